// Round 6
// baseline (2665.398 us; speedup 1.0000x reference)
//
#include <hip/hip_runtime.h>
#include <math.h>

// ---- problem constants ----
#define BB    64
#define NN_   128
#define NH    6
#define DM    600     // d_model
#define RHID  300     // rnn hidden
#define DKH   100     // per-head dim
#define INDIM 360
#define G4    1200    // 4*RHID
#define WXROW 1206    // NH + 2*DM
#define DMP   608     // DM padded to mult of 32
#define INP   384     // INDIM padded

// ---- LSTM cluster config ----
#define S_CL  25
#define NSU   12
#define NSR   48
#define KPAD  320
#define HSLOT (BB*KPAD)          // 20480 bf16 per history slot
#define DSTR  (129*HSLOT)        // per-dir history stride (bf16)

// ---- workspace layout (float offsets). Peak ~ 25.9M fl = 103.7 MB ----
#define OFF_GINB   0ull                 // bf16 [8192][608] = 2,490,368 fl
#define OFF_ASPECT 2490368ull
#define OFF_ABUF   2528768ull
#define OFF_AWB    2535168ull
#define OFF_ASCB   2573568ull
#define OFF_W1SUM  2622720ull
#define OFF_W2SUM  2623360ull
#define OFF_SWX    2624000ull
#define OFF_SBX    2624016ull
#define OFF_SG1    2624032ull
#define OFF_SG2    2632224ull
#define OFF_WHS    2640416ull           // fp32 [64][128][128]
#define OFF_WQKP   3688992ull           // bf16 [1200][608]
#define OFF_BQK    4053792ull
#define OFF_WWP    4054992ull           // bf16 [600][608]
#define OFF_WXXP   4237392ull           // bf16 [300][608]
#define OFF_WIHPF  4328592ull           // bf16 [1200][384]
#define OFF_WIHPB  4558992ull
#define OFF_BPF    4789392ull
#define OFF_BPB    4790592ull
#define OFF_WTB    4791792ull           // bf16 [2][1200][320]
#define OFF_EMBS   5216768ull           // bf16 [8192][384]
#define ARENA      6789632ull
#define OFF_XGF    (ARENA)                      // bf16 [8192][1200] = 4,915,200 fl
#define OFF_XGB    (ARENA + 4915200ull)         // bf16, 4,915,200 fl
#define OFF_HIST   (ARENA + 9830400ull)         // bf16 [2][129][64][320] = 2,641,920 fl
#define OFF_FLAGS  (ARENA + 12472320ull)        // 2048 fl (50 flags, 128B apart)
// post-lstm reuse (hist/flags dead after reshape; xg dead after lstm):
#define OFF_QKB    (ARENA)                      // fp32 [8192][1200]
#define OFF_ADJ    (ARENA + 9830400ull)         // fp32 [64][6][128][128] (over hist)
#define OFF_ADJS   (ARENA + 16121856ull)        // bf16 [64][128][128]
#define OFF_GINT   (ARENA + 16646144ull)        // bf16 [64][608][128]
#define OFF_AXB    (ARENA)                      // bf16 (over qkb, dead after attn)
#define OFF_G1B    (ARENA + 2490368ull)
#define OFF_G1T    (OFF_GINT)
#define OFF_AX2B   (ARENA + 4980736ull)
#define OFF_G2B    (ARENA + 7471104ull)
#define OFF_HNB    (ARENA + 9961472ull)         // fp32 [8192][300] (over adjb, dead)

typedef __bf16 bf16x8 __attribute__((ext_vector_type(8)));
typedef __bf16 bf16x4 __attribute__((ext_vector_type(4)));
typedef __bf16 bf16x2 __attribute__((ext_vector_type(2)));
typedef float  f32x4  __attribute__((ext_vector_type(4)));

__device__ __forceinline__ float sigm(float x){ return 1.f/(1.f+__expf(-x)); }
__device__ __forceinline__ float selu_f(float x){
  const float sc=1.0507009873554805f, al=1.6732632423543772f;
  return x>0.f ? sc*x : sc*al*(__expf(x)-1.f);
}
__device__ __forceinline__ bf16x8 bzero8(){
  bf16x8 z;
#pragma unroll
  for (int j=0;j<8;++j) z[j]=(__bf16)0.f;
  return z;
}

// ---------------- embedding concat -> bf16 [8192][384], pads written zero ----------------
__global__ __launch_bounds__(384) void embed_k(
    const int* __restrict__ tok, const int* __restrict__ pos_ids, const int* __restrict__ post_ids,
    const float* __restrict__ emb_w, const float* __restrict__ pos_w, const float* __restrict__ post_w,
    __bf16* __restrict__ embs)
{
  int bn = blockIdx.x, t = threadIdx.x;
  float v = 0.f;
  if      (t < 300) v = emb_w [(size_t)tok     [bn]*300 + t];
  else if (t < 330) v = pos_w [(size_t)pos_ids [bn]*30  + (t-300)];
  else if (t < 360) v = post_w[(size_t)post_ids[bn]*30  + (t-330)];
  embs[(size_t)bn*INP + t] = (__bf16)v;
}

// ---------------- Wx folded constants ----------------
__global__ __launch_bounds__(640) void consts_k(
    const float* __restrict__ Wx, const float* __restrict__ bx,
    float* __restrict__ w1sum, float* __restrict__ w2sum,
    float* __restrict__ swx, float* __restrict__ sbx)
{
  int t = threadIdx.x;
  if (t < DM){
    float s1=0.f, s2=0.f;
    for (int k=0;k<NH;++k){ s1 += Wx[k*WXROW + NH + t]; s2 += Wx[k*WXROW + NH + DM + t]; }
    w1sum[t]=s1; w2sum[t]=s2;
  } else if (t < DM+NH){
    int h=t-DM; float s=0.f;
    for (int k=0;k<NH;++k) s += Wx[k*WXROW + h];
    swx[h]=s;
  } else if (t == DM+NH){
    float s=0.f; for (int k=0;k<NH;++k) s += bx[k];
    sbx[0]=s;
  }
}

// ---------------- pack Wih (gate-interleaved rows p=4u+g) -> bf16 [1200][384] ----------------
__global__ __launch_bounds__(256) void wihp_k(
    const float* __restrict__ Wih, const float* __restrict__ b,
    __bf16* __restrict__ wp, float* __restrict__ bp)
{
  int idx = blockIdx.x*256 + threadIdx.x;
  if (idx < G4*INP){
    int p = idx / INP, k = idx - p*INP;
    int srow = (p&3)*RHID + (p>>2);
    wp[idx] = (k<INDIM) ? (__bf16)Wih[(size_t)srow*INDIM + k] : (__bf16)0.f;
  } else if (idx < G4*INP + G4){
    int p = idx - G4*INP;
    bp[p] = b[(p&3)*RHID + (p>>2)];
  }
}

// ---------------- pack Wq||Wk -> bf16 [1200][608], bias ----------------
__global__ __launch_bounds__(256) void wqkp_k(
    const float* __restrict__ Wq, const float* __restrict__ bq,
    const float* __restrict__ Wk, const float* __restrict__ bk,
    __bf16* __restrict__ wp, float* __restrict__ bp)
{
  int idx = blockIdx.x*256 + threadIdx.x;
  if (idx < G4*DMP){
    int n = idx / DMP, k = idx - n*DMP;
    float v = 0.f;
    if (k < DM) v = (n < DM) ? Wq[(size_t)n*DM + k] : Wk[(size_t)(n-DM)*DM + k];
    wp[idx] = (__bf16)v;
  } else if (idx < G4*DMP + G4){
    int n = idx - G4*DMP;
    bp[n] = (n < DM) ? bq[n] : bk[n-DM];
  }
}

// ---------------- generic weight pack fp32[n][ksrc] -> bf16[n][kp] (k-pads zero) ----------------
__global__ __launch_bounds__(256) void wpk_k(
    const float* __restrict__ W, __bf16* __restrict__ wp, int nrows, int ksrc, int kp)
{
  int idx = blockIdx.x*256 + threadIdx.x;
  if (idx >= nrows*kp) return;
  int n = idx / kp, k = idx - n*kp;
  wp[idx] = (k < ksrc) ? (__bf16)W[(size_t)n*ksrc + k] : (__bf16)0.f;
}

// ---------------- pack Whh -> bf16 [p=4u+g][KPAD] ----------------
__global__ __launch_bounds__(256) void whhp_k(
    const float* __restrict__ Whh, __bf16* __restrict__ outW)
{
  int idx = blockIdx.x*256 + threadIdx.x;
  if (idx >= G4*KPAD) return;
  int p = idx / KPAD, k = idx - p*KPAD;
  outW[idx] = (k < RHID) ? (__bf16)Whh[((size_t)((p&3)*RHID + (p>>2)))*RHID + k] : (__bf16)0.f;
}

// ---------------- zero hist slot0 (both dirs) + flags ----------------
__global__ __launch_bounds__(256) void init_k(float* __restrict__ ws)
{
  int idx = blockIdx.x*256 + threadIdx.x;
  if (idx < 10240)       ws[OFF_HIST + idx] = 0.f;                       // dir0 slot0
  else if (idx < 20480)  ws[OFF_HIST + 1320960ull + (idx-10240)] = 0.f;  // dir1 slot0
  else if (idx < 22528)  ws[OFF_FLAGS + (idx-20480)] = 0.f;              // flags
}

// ---------------- LDS-free bf16 MFMA GEMM: C = act(A @ B^T + bias) ----------------
template<int KT, int ACT, int OBF>
__global__ __launch_bounds__(256) void wgemm_k(
    const __bf16* __restrict__ A, const __bf16* __restrict__ B,
    const float* __restrict__ bias, void* __restrict__ Cout,
    int Nn, int Npad, int ldc,
    long long sA, long long sB, long long sC)
{
  const int tid = threadIdx.x, lane = tid & 63, wave = tid >> 6;
  const int fn = lane & 15, fq = lane >> 4;
  const int K = KT*32;
  const __bf16* Ab = A + (size_t)blockIdx.z * (size_t)sA;
  const __bf16* Bb = B + (size_t)blockIdx.z * (size_t)sB;
  float*  Cf = (float*) Cout + (size_t)blockIdx.z * (size_t)sC;
  __bf16* Ch = (__bf16*)Cout + (size_t)blockIdx.z * (size_t)sC;

  const int m0 = (blockIdx.x*4 + wave)*16;

  bf16x8 Af[KT];
#pragma unroll
  for (int kt=0; kt<KT; ++kt)
    Af[kt] = *(const bf16x8*)(Ab + (size_t)(m0 + fn)*K + kt*32 + fq*8);

  for (int n0 = blockIdx.y*16; n0 < Nn; n0 += 16*gridDim.y){
    const int gn = n0 + fn;
    const int gnc = (gn < Nn) ? gn : 0;
    f32x4 acc = {0.f,0.f,0.f,0.f};
#pragma unroll
    for (int kt=0; kt<KT; ++kt){
      bf16x8 Bf = *(const bf16x8*)(Bb + (size_t)gnc*K + kt*32 + fq*8);
      if (gn >= Nn) Bf = bzero8();
      acc = __builtin_amdgcn_mfma_f32_16x16x32_bf16(Af[kt], Bf, acc, 0, 0, 0);
    }
    float bv = (bias && gn < Nn) ? bias[gn] : 0.f;
#pragma unroll
    for (int r=0; r<4; ++r){
      int gm = m0 + fq*4 + r;
      float v = acc[r] + bv;
      if (ACT==1) v = selu_f(v);
      else if (ACT==2) v = fmaxf(v, 0.f);
      if (gn < Nn){
        if (OBF) Ch[(size_t)gm*ldc + gn] = (__bf16)v;
        else     Cf[(size_t)gm*ldc + gn] = v;
      } else if (gn < Npad){
        if (OBF) Ch[(size_t)gm*ldc + gn] = (__bf16)0.f;
        else     Cf[(size_t)gm*ldc + gn] = 0.f;
      }
    }
  }
}

// ---------------- legacy fp32 GEMM (only for tiny aspect@Wd) ----------------
template<bool TRANSB, int ACT>
__global__ __launch_bounds__(256) void gemm_k(
    const float* __restrict__ A, const float* __restrict__ Bm,
    const float* __restrict__ bias, float* __restrict__ C,
    int M, int Nn, int K, long long sA, long long sB, long long sC)
{
  __shared__ __align__(16) float As[16][132];
  __shared__ __align__(16) float Bs[16][132];
  const float* Ab = A  + (size_t)blockIdx.z * (size_t)sA;
  const float* Bb = Bm + (size_t)blockIdx.z * (size_t)sB;
  float*       Cb = C  + (size_t)blockIdx.z * (size_t)sC;
  const int m0 = blockIdx.y * 128, n0 = blockIdx.x * 128;
  const int lin = threadIdx.x;
  const int tx = lin & 15, ty = lin >> 4;
  float acc[8][8];
#pragma unroll
  for (int i=0;i<8;i++)
#pragma unroll
    for (int j=0;j<8;j++) acc[i][j]=0.f;
  for (int k0=0; k0<K; k0+=16) {
#pragma unroll
    for (int r=0;r<2;++r){
      int e = lin*2+r;
      int row = e>>2, kq=(e&3)*4;
      float4 v = make_float4(0.f,0.f,0.f,0.f);
      int gm=m0+row, gk=k0+kq;
      if (gm<M && gk<K) v = *(const float4*)(Ab + (size_t)gm*K + gk);
      As[kq+0][row]=v.x; As[kq+1][row]=v.y; As[kq+2][row]=v.z; As[kq+3][row]=v.w;
    }
#pragma unroll
    for (int r=0;r<2;++r){
      int e = lin*2+r;
      int col = e>>2, kq=(e&3)*4;
      float4 v = make_float4(0.f,0.f,0.f,0.f);
      int gn=n0+col, gk=k0+kq;
      if (gn<Nn && gk<K) v = *(const float4*)(Bb + (size_t)gn*K + gk);
      Bs[kq+0][col]=v.x; Bs[kq+1][col]=v.y; Bs[kq+2][col]=v.z; Bs[kq+3][col]=v.w;
    }
    __syncthreads();
#pragma unroll
    for (int kk=0;kk<16;++kk){
      float a[8], bv[8];
      *(float4*)&a[0]  = *(const float4*)&As[kk][ty*8];
      *(float4*)&a[4]  = *(const float4*)&As[kk][ty*8+4];
      *(float4*)&bv[0] = *(const float4*)&Bs[kk][tx*8];
      *(float4*)&bv[4] = *(const float4*)&Bs[kk][tx*8+4];
#pragma unroll
      for (int i=0;i<8;i++)
#pragma unroll
        for (int j=0;j<8;j++) acc[i][j] = fmaf(a[i], bv[j], acc[i][j]);
    }
    __syncthreads();
  }
#pragma unroll
  for (int i=0;i<8;i++){
    int gm = m0 + ty*8 + i;
    if (gm>=M) continue;
#pragma unroll
    for (int j=0;j<8;j+=4){
      int gn = n0 + tx*8 + j;
      if (gn>=Nn) continue;
      float t0=acc[i][j+0], t1=acc[i][j+1], t2=acc[i][j+2], t3=acc[i][j+3];
      if (bias){ t0+=bias[gn]; t1+=bias[gn+1]; t2+=bias[gn+2]; t3+=bias[gn+3]; }
      float4 v; v.x=t0; v.y=t1; v.z=t2; v.w=t3;
      *(float4*)(Cb + (size_t)gm*Nn + gn) = v;
    }
  }
}

// ---------------- bf16 per-batch transpose [64][128][608] -> [64][608][128] ----------------
__global__ __launch_bounds__(256) void tr_k(
    const __bf16* __restrict__ in, __bf16* __restrict__ out)
{
  const int b = blockIdx.z, m0 = blockIdx.y*64, d0 = blockIdx.x*64;
  const int tid = threadIdx.x;
  __shared__ __align__(16) __bf16 T[64][72];
  const __bf16* ib = in + (size_t)b*NN_*DMP;
  __bf16* ob = out + (size_t)b*DMP*NN_;
#pragma unroll
  for (int r=0;r<2;++r){
    int idx = tid + 256*r;
    int mi = idx>>3, ch = idx&7;
    int d = d0 + ch*8;
    bf16x8 v = bzero8();
    if (d < DMP) v = *(const bf16x8*)(ib + (size_t)(m0+mi)*DMP + d);
    *(bf16x8*)&T[mi][ch*8] = v;
  }
  __syncthreads();
#pragma unroll
  for (int r=0;r<2;++r){
    int idx = tid + 256*r;
    int di = idx>>3, mch = idx&7;
    int d = d0 + di;
    if (d >= DMP) continue;
    bf16x8 v;
#pragma unroll
    for (int j=0;j<8;++j) v[j] = T[mch*8+j][di];
    *(bf16x8*)(ob + (size_t)d*NN_ + m0 + mch*8) = v;
  }
}

// ---------------- cooperative-cluster MFMA LSTM, flag-array sync + h history ----------------
// Producer: threadfence + per-block RELEASE flag (own 128B line). Consumer: wave0 lanes 0..24
// poll all flags in parallel with RELAXED agent loads (no per-poll cache inv), then one
// threadfence (single inv) before reading the new h slot. History buffer: slot s+1 = h(s).
__global__ __launch_bounds__(256, 1) void lstm_mfma_k(
    const __bf16* __restrict__ xgf, const __bf16* __restrict__ xgb,
    const __bf16* __restrict__ wtb,
    __bf16* hist, int* flags)
{
  const int blk = blockIdx.x;
  const int dir = blk / S_CL, sl = blk - dir*S_CL;
  const int tid = threadIdx.x, lane = tid & 63, wave = tid >> 6;
  const int p0 = sl * NSR;
  const __bf16* xg = dir ? xgb : xgf;
  const __bf16* W = wtb + (size_t)dir * G4 * KPAD;
  __bf16* hb = hist + (size_t)dir * DSTR;

  __shared__ __align__(16) float accS[NSR][68];

  const int fn = lane & 15;
  const int fk = (lane >> 4) * 8;
  const int m0 = wave * 16;

  bf16x8 Bf[3][10];
#pragma unroll
  for (int nt = 0; nt < 3; ++nt)
#pragma unroll
    for (int kt = 0; kt < 10; ++kt)
      Bf[nt][kt] = *(const bf16x8*)(W + (size_t)(p0 + nt*16 + fn)*KPAD + kt*32 + fk);

  int ib[3], iu[3]; float cst[3];
  const __bf16* xp[3];
#pragma unroll
  for (int j = 0; j < 3; ++j){
    int item = tid + 256*j;
    iu[j] = item % NSU; ib[j] = item / NSU;
    cst[j] = 0.f;
    xp[j] = xg + ((size_t)ib[j]*NN_)*G4 + p0 + iu[j]*4;
  }

  for (int s = 0; s < NN_; ++s){
    const int n_t = dir ? (NN_-1-s) : s;
    const __bf16* hbr = hb + (size_t)s*HSLOT;        // h(s-1)
    __bf16*       hbw = hb + (size_t)(s+1)*HSLOT;    // h(s)

    // prefetch xg (independent of h)
    bf16x4 xv0 = *(const bf16x4*)(xp[0] + (size_t)n_t*G4);
    bf16x4 xv1 = *(const bf16x4*)(xp[1] + (size_t)n_t*G4);
    bf16x4 xv2 = *(const bf16x4*)(xp[2] + (size_t)n_t*G4);

    bf16x8 Af[10];
#pragma unroll
    for (int kt = 0; kt < 10; ++kt)
      Af[kt] = *(const bf16x8*)(hbr + (size_t)(m0 + fn)*KPAD + kt*32 + fk);

    f32x4 acc[3] = { {0.f,0.f,0.f,0.f}, {0.f,0.f,0.f,0.f}, {0.f,0.f,0.f,0.f} };
#pragma unroll
    for (int kt = 0; kt < 10; ++kt)
#pragma unroll
      for (int nt = 0; nt < 3; ++nt)
        acc[nt] = __builtin_amdgcn_mfma_f32_16x16x32_bf16(Af[kt], Bf[nt][kt], acc[nt], 0, 0, 0);

#pragma unroll
    for (int nt = 0; nt < 3; ++nt)
      *(f32x4*)&accS[nt*16 + fn][m0 + (lane>>4)*4] = acc[nt];
    __syncthreads();

    bf16x4 xv[3] = {xv0, xv1, xv2};
#pragma unroll
    for (int j = 0; j < 3; ++j){
      int u = iu[j], b = ib[j];
      float p_i = accS[u*4+0][b] + (float)xv[j][0];
      float p_f = accS[u*4+1][b] + (float)xv[j][1];
      float p_g = accS[u*4+2][b] + (float)xv[j][2];
      float p_o = accS[u*4+3][b] + (float)xv[j][3];
      float ig = sigm(p_i), fg = sigm(p_f), gg = tanhf(p_g), og = sigm(p_o);
      float c = fg*cst[j] + ig*gg; cst[j] = c;
      float h = og * tanhf(c);
      hbw[(size_t)b*KPAD + sl*NSU + u] = (__bf16)h;
    }
    // ---- publish: fence + release flag ----
    __threadfence();
    __syncthreads();
    if (tid == 0)
      __hip_atomic_store(&flags[(dir*S_CL + sl)*32], s+1, __ATOMIC_RELEASE, __HIP_MEMORY_SCOPE_AGENT);
    // ---- wait: parallel relaxed poll, one fence ----
    if (wave == 0 && lane < S_CL){
      int* fp = &flags[(dir*S_CL + lane)*32];
      while (__hip_atomic_load(fp, __ATOMIC_RELAXED, __HIP_MEMORY_SCOPE_AGENT) < s+1)
        __builtin_amdgcn_s_sleep(1);
    }
    __syncthreads();
    __threadfence();   // acquire side: invalidate stale h lines before next step's reads
  }
}

// ---------------- hist -> ginb [8192][608] (pads zeroed) ----------------
__global__ __launch_bounds__(320) void reshape_k(
    const __bf16* __restrict__ hist, __bf16* __restrict__ ginb)
{
  int row = blockIdx.x;                 // b*128 + n
  int b = row >> 7, n = row & 127;
  int t = threadIdx.x;
  if (t < 150){
    int u = 2*t;
    bf16x2 v = *(const bf16x2*)(hist + (size_t)(n+1)*HSLOT + (size_t)b*KPAD + u);
    *(bf16x2*)(ginb + (size_t)row*DMP + u) = v;
  } else if (t >= 160 && t < 310){
    int u = 2*(t-160);
    bf16x2 v = *(const bf16x2*)(hist + (size_t)DSTR + (size_t)(NN_-n)*HSLOT + (size_t)b*KPAD + u);
    *(bf16x2*)(ginb + (size_t)row*DMP + RHID + u) = v;
  } else if (t >= 312 && t < 316){
    int c = DM + 2*(t-312);
    bf16x2 z; z[0]=(__bf16)0.f; z[1]=(__bf16)0.f;
    *(bf16x2*)(ginb + (size_t)row*DMP + c) = z;
  }
}

// ---------------- masked mean over sequence -> aspect[B,DM] (bf16 in) ----------------
__global__ __launch_bounds__(640) void aspect_k(
    const __bf16* __restrict__ ginb, const float* __restrict__ mask, float* __restrict__ aspect)
{
  int b = blockIdx.x, t = threadIdx.x;
  __shared__ float msk[NN_];
  __shared__ float wn;
  if (t < NN_) msk[t] = mask[b*NN_+t];
  __syncthreads();
  if (t==0){ float s=0.f; for (int n=0;n<NN_;++n) s+=msk[n]; wn=s; }
  __syncthreads();
  if (t < DM){
    float s=0.f;
    for (int n=0;n<NN_;++n) s += (float)ginb[((size_t)(b*NN_+n))*DMP + t]*msk[n];
    aspect[b*DM+t] = s/wn;
  }
}

// ---------------- aw[b,h,e] = sum_d a[b,d] * weight_m[h,d,e] ----------------
__global__ __launch_bounds__(128) void aw_k(
    const float* __restrict__ a, const float* __restrict__ wm, float* __restrict__ aw)
{
  int b=blockIdx.x, h=blockIdx.y, e=threadIdx.x;
  if (e>=DKH) return;
  float s=0.f;
  for (int d=0; d<DKH; ++d) s += a[b*DKH+d]*wm[(h*DKH+d)*DKH+e];
  aw[(b*NH+h)*DKH+e]=s;
}

// ---------------- asc[b,h,m] = tanh(aw . k[b,h,m,:] + bias_m) ----------------
__global__ __launch_bounds__(128) void asc_k(
    const float* __restrict__ aw, const float* __restrict__ qkb,
    const float* __restrict__ bias_m, float* __restrict__ asc)
{
  int b=blockIdx.x, h=blockIdx.y, m=threadIdx.x;
  __shared__ __align__(16) float awl[DKH];
  if (m<DKH) awl[m]=aw[(b*NH+h)*DKH+m];
  __syncthreads();
  const float* kr = qkb + ((size_t)(b*NN_+m))*G4 + DM + h*DKH;
  const float4* a4=(const float4*)awl; const float4* k4=(const float4*)kr;
  float s=0.f;
#pragma unroll
  for (int e=0;e<DKH/4;e++){ float4 x=a4[e], y=k4[e]; s += x.x*y.x+x.y*y.y+x.z*y.z+x.w*y.w; }
  asc[(b*NH+h)*NN_+m] = tanhf(s + bias_m[0]);
}

// ---------------- scores + mask + short + softmax -> adj[B,H,N,N] ----------------
__global__ __launch_bounds__(128) void attn_k(
    const float* __restrict__ qkb, const float* __restrict__ asc,
    const float* __restrict__ shortm, const int* __restrict__ tok, float* __restrict__ adj)
{
  int n=blockIdx.x, h=blockIdx.y, b=blockIdx.z, m=threadIdx.x;
  __shared__ __align__(16) float qrow[DKH];
  __shared__ float red[NN_];
  if (m < DKH) qrow[m] = qkb[((size_t)(b*NN_+n))*G4 + h*DKH + m];
  __syncthreads();
  const float* kr = qkb + ((size_t)(b*NN_+m))*G4 + DM + h*DKH;
  const float4* q4=(const float4*)qrow; const float4* k4=(const float4*)kr;
  float s=0.f;
#pragma unroll
  for (int e=0;e<DKH/4;e++){ float4 x=q4[e], y=k4[e]; s += x.x*y.x+x.y*y.y+x.z*y.z+x.w*y.w; }
  s = s*0.1f + asc[(b*NH+h)*NN_+m];
  if (tok[b*NN_+m]==0) s = -1e9f;
  s += shortm[((size_t)(b*NN_+n))*NN_+m];
  red[m]=s; __syncthreads();
  for (int o=64;o;o>>=1){ if (m<o) red[m]=fmaxf(red[m],red[m+o]); __syncthreads(); }
  float mx = red[0]; __syncthreads();
  float e = __expf(s-mx);
  red[m]=e; __syncthreads();
  for (int o=64;o;o>>=1){ if (m<o) red[m]+=red[m+o]; __syncthreads(); }
  adj[(((size_t)b*NH+h)*NN_+n)*NN_+m] = e/red[0];
}

// ---------------- adjsum -> bf16 adjs (/H) + fp32 whs ----------------
__global__ __launch_bounds__(256) void adjsum_k(
    const float* __restrict__ adj, const float* __restrict__ swx,
    __bf16* __restrict__ adjs, float* __restrict__ whs)
{
  int idx = blockIdx.x*256 + threadIdx.x;
  int b = idx >> 14, rem = idx & 16383;
  float s=0.f, w=0.f;
  for (int h=0;h<NH;++h){
    float v = adj[(((size_t)b*NH+h)<<14) + rem];
    s += v; w += v*swx[h];
  }
  adjs[idx] = (__bf16)(s*(1.f/NH));
  whs [idx] = w*(1.f/NH);
}

// ---------------- sg1/sg2 from g1 (bf16) ----------------
__global__ __launch_bounds__(128) void sg_k(
    const __bf16* __restrict__ g1, const float* __restrict__ w1sum, const float* __restrict__ w2sum,
    float* __restrict__ sg1, float* __restrict__ sg2)
{
  int row = blockIdx.x*128 + threadIdx.x;
  const __bf16* gr = g1 + (size_t)row*DMP;
  float s1=0.f,s2=0.f;
  for (int d=0;d<DM;++d){ float g=(float)gr[d]; s1+=g*w1sum[d]; s2+=g*w2sum[d]; }
  sg1[row]=s1; sg2[row]=s2;
}

// ---------------- adjs2[b,i,j] = whs + (sg1[b,j]+sg2[b,i]+sbx)/H -> bf16 ----------------
__global__ __launch_bounds__(256) void adjsum2_k(
    const float* __restrict__ whs, const float* __restrict__ sg1, const float* __restrict__ sg2,
    const float* __restrict__ sbx, __bf16* __restrict__ adjs)
{
  int idx = blockIdx.x*256 + threadIdx.x;
  int b = idx >> 14, rem = idx & 16383;
  int i = rem >> 7, j = rem & 127;
  adjs[idx] = (__bf16)(whs[idx] + (sg1[b*NN_+j] + sg2[b*NN_+i] + sbx[0])*(1.f/NH));
}

// ---------------- pooled mean + logits ----------------
__global__ __launch_bounds__(320) void pooled_k(
    const float* __restrict__ hn, const float* __restrict__ mask,
    const float* __restrict__ Wc, const float* __restrict__ bc, float* __restrict__ out)
{
  int b=blockIdx.x, t=threadIdx.x;
  __shared__ float msk[NN_];
  __shared__ float pl[RHID];
  __shared__ float wn;
  if (t<NN_) msk[t]=mask[b*NN_+t];
  __syncthreads();
  if (t==0){ float s=0.f; for (int n=0;n<NN_;++n) s+=msk[n]; wn=s; }
  __syncthreads();
  if (t<RHID){
    float s=0.f;
    for (int n=0;n<NN_;++n) s += hn[((size_t)(b*NN_+n))*RHID+t]*msk[n];
    pl[t]=s/wn;
  }
  __syncthreads();
  if (t<3){
    float s=bc[t];
    for (int d=0;d<RHID;++d) s += pl[d]*Wc[t*RHID+d];
    out[b*3+t]=s;
  }
}

extern "C" void kernel_launch(void* const* d_in, const int* in_sizes, int n_in,
                              void* d_out, int out_size, void* d_ws, size_t ws_size,
                              hipStream_t stream)
{
  (void)in_sizes; (void)n_in; (void)out_size; (void)ws_size;
  const int*   tok      = (const int*)  d_in[0];
  const int*   pos_ids  = (const int*)  d_in[2];
  const int*   post_ids = (const int*)  d_in[5];
  const float* mask     = (const float*)d_in[6];
  const float* shortm   = (const float*)d_in[8];
  const float* emb_w    = (const float*)d_in[9];
  const float* pos_w    = (const float*)d_in[10];
  const float* post_w   = (const float*)d_in[11];
  const float* Wih_f    = (const float*)d_in[12];
  const float* Whh_f    = (const float*)d_in[13];
  const float* b_f      = (const float*)d_in[14];
  const float* Wih_b    = (const float*)d_in[15];
  const float* Whh_b    = (const float*)d_in[16];
  const float* b_b      = (const float*)d_in[17];
  const float* Wq       = (const float*)d_in[18];
  const float* bq       = (const float*)d_in[19];
  const float* Wk       = (const float*)d_in[20];
  const float* bk       = (const float*)d_in[21];
  const float* Wd       = (const float*)d_in[22];
  const float* bd       = (const float*)d_in[23];
  const float* weight_m = (const float*)d_in[24];
  const float* bias_m   = (const float*)d_in[25];
  const float* Ww       = (const float*)d_in[26];
  const float* bw       = (const float*)d_in[27];
  const float* Wx       = (const float*)d_in[28];
  const float* bx       = (const float*)d_in[29];
  const float* Wxx      = (const float*)d_in[30];
  const float* bxx      = (const float*)d_in[31];
  const float* Wc       = (const float*)d_in[32];
  const float* bc       = (const float*)d_in[33];

  float* ws  = (float*)d_ws;
  float* out = (float*)d_out;

  __bf16* ginb  = (__bf16*)(ws + OFF_GINB);
  float* aspect = ws + OFF_ASPECT;
  float* abuf   = ws + OFF_ABUF;
  float* awb    = ws + OFF_AWB;
  float* ascb   = ws + OFF_ASCB;
  float* w1sum  = ws + OFF_W1SUM;
  float* w2sum  = ws + OFF_W2SUM;
  float* swx    = ws + OFF_SWX;
  float* sbx    = ws + OFF_SBX;
  float* sg1    = ws + OFF_SG1;
  float* sg2    = ws + OFF_SG2;
  float* whs    = ws + OFF_WHS;
  __bf16* wqkp  = (__bf16*)(ws + OFF_WQKP);
  float* bqk    = ws + OFF_BQK;
  __bf16* wwp   = (__bf16*)(ws + OFF_WWP);
  __bf16* wxxp  = (__bf16*)(ws + OFF_WXXP);
  __bf16* wihpF = (__bf16*)(ws + OFF_WIHPF);
  __bf16* wihpB = (__bf16*)(ws + OFF_WIHPB);
  float* bpF    = ws + OFF_BPF;
  float* bpB    = ws + OFF_BPB;
  __bf16* wtb   = (__bf16*)(ws + OFF_WTB);
  __bf16* embs  = (__bf16*)(ws + OFF_EMBS);
  __bf16* xgf   = (__bf16*)(ws + OFF_XGF);
  __bf16* xgb   = (__bf16*)(ws + OFF_XGB);
  __bf16* hist  = (__bf16*)(ws + OFF_HIST);
  int*   flags  = (int*)(ws + OFF_FLAGS);
  float* qkb    = ws + OFF_QKB;
  float* adjb   = ws + OFF_ADJ;
  __bf16* adjs  = (__bf16*)(ws + OFF_ADJS);
  __bf16* gint  = (__bf16*)(ws + OFF_GINT);
  __bf16* axb   = (__bf16*)(ws + OFF_AXB);
  __bf16* g1b   = (__bf16*)(ws + OFF_G1B);
  __bf16* g1t   = (__bf16*)(ws + OFF_G1T);
  __bf16* ax2b  = (__bf16*)(ws + OFF_AX2B);
  __bf16* g2b   = (__bf16*)(ws + OFF_G2B);
  float* hnb    = ws + OFF_HNB;

  // 1. embeddings, constants, weight packing, init
  embed_k<<<dim3(BB*NN_),384,0,stream>>>(tok,pos_ids,post_ids,emb_w,pos_w,post_w,embs);
  consts_k<<<1,640,0,stream>>>(Wx,bx,w1sum,w2sum,swx,sbx);
  wihp_k<<<dim3((G4*INP+G4+255)/256),256,0,stream>>>(Wih_f,b_f,wihpF,bpF);
  wihp_k<<<dim3((G4*INP+G4+255)/256),256,0,stream>>>(Wih_b,b_b,wihpB,bpB);
  wqkp_k<<<dim3((G4*DMP+G4+255)/256),256,0,stream>>>(Wq,bq,Wk,bk,wqkp,bqk);
  wpk_k<<<dim3((DM*DMP+255)/256),256,0,stream>>>(Ww,wwp,DM,DM,DMP);
  wpk_k<<<dim3((RHID*DMP+255)/256),256,0,stream>>>(Wxx,wxxp,RHID,DM,DMP);
  whhp_k<<<dim3((G4*KPAD+255)/256),256,0,stream>>>(Whh_f, wtb);
  whhp_k<<<dim3((G4*KPAD+255)/256),256,0,stream>>>(Whh_b, wtb + (size_t)G4*KPAD);
  init_k<<<dim3((22528+255)/256),256,0,stream>>>(ws);
  // 2. LSTM input projections (bf16 MFMA, LDS-free), bf16 out
  wgemm_k<12,0,1><<<dim3(128,4,1),256,0,stream>>>(embs,wihpF,bpF,xgf, G4,G4,G4, 0,0,0);
  wgemm_k<12,0,1><<<dim3(128,4,1),256,0,stream>>>(embs,wihpB,bpB,xgb, G4,G4,G4, 0,0,0);
  // 3. recurrence (flag-array cluster sync, h history)
  lstm_mfma_k<<<dim3(2*S_CL),256,0,stream>>>(xgf,xgb,wtb,hist,flags);
  reshape_k<<<dim3(BB*NN_),320,0,stream>>>(hist,ginb);
  // 4. fused Q||K projection, aspect path
  wgemm_k<19,0,0><<<dim3(128,4,1),256,0,stream>>>(ginb,wqkp,bqk,qkb, G4,G4,G4, 0,0,0);
  aspect_k<<<BB,640,0,stream>>>(ginb,mask,aspect);
  gemm_k<false,0><<<dim3(1,1,1),256,0,stream>>>(aspect,Wd,bd,abuf, BB,DKH,DM, 0,0,0);
  aw_k <<<dim3(BB,NH),128,0,stream>>>(abuf,weight_m,awb);
  asc_k<<<dim3(BB,NH),128,0,stream>>>(awb,qkb,bias_m,ascb);
  // 5. scores + softmax
  attn_k<<<dim3(NN_,NH,BB),128,0,stream>>>(qkb,ascb,shortm,tok,adjb);
  // 6. GCN layer 1 (bf16 MFMA)
  adjsum_k<<<4096,256,0,stream>>>(adjb,swx,adjs,whs);
  tr_k<<<dim3(10,2,BB),256,0,stream>>>(ginb,gint);
  wgemm_k<4,0,1><<<dim3(2,4,BB),256,0,stream>>>(adjs,gint,nullptr,axb, DM,DMP,DMP, 16384,(long long)DMP*NN_,(long long)NN_*DMP);
  wgemm_k<19,1,1><<<dim3(128,4,1),256,0,stream>>>(axb,wwp,bw,g1b, DM,DMP,DMP, 0,0,0);
  // 7. layer-2 adjacency collapsed
  sg_k<<<64,128,0,stream>>>(g1b,w1sum,w2sum,sg1,sg2);
  adjsum2_k<<<4096,256,0,stream>>>(whs,sg1,sg2,sbx,adjs);
  // 8. GCN layer 2
  tr_k<<<dim3(10,2,BB),256,0,stream>>>(g1b,g1t);
  wgemm_k<4,0,1><<<dim3(2,4,BB),256,0,stream>>>(adjs,g1t,nullptr,ax2b, DM,DMP,DMP, 16384,(long long)DMP*NN_,(long long)NN_*DMP);
  wgemm_k<19,1,1><<<dim3(128,4,1),256,0,stream>>>(ax2b,wwp,bw,g2b, DM,DMP,DMP, 0,0,0);
  // 9. head
  wgemm_k<19,2,0><<<dim3(128,4,1),256,0,stream>>>(g2b,wxxp,bxx,hnb, RHID,RHID,RHID, 0,0,0);
  pooled_k<<<BB,320,0,stream>>>(hnb,mask,Wc,bc,out);
}

// Round 7
// 1743.329 us; speedup vs baseline: 1.5289x; 1.5289x over previous
//
#include <hip/hip_runtime.h>
#include <math.h>

// ---- problem constants ----
#define BB    64
#define NN_   128
#define NH    6
#define DM    600     // d_model
#define RHID  300     // rnn hidden
#define DKH   100     // per-head dim
#define INDIM 360
#define G4    1200    // 4*RHID
#define WXROW 1206    // NH + 2*DM
#define DMP   608     // DM padded to mult of 32
#define INP   384     // INDIM padded

// ---- LSTM cluster config ----
#define S_CL  25
#define NSU   12
#define NSR   48
#define KPAD  320
#define HSLOT (BB*KPAD)          // 20480 bf16 per history slot
#define DSTR  (129*HSLOT)        // per-dir history stride (bf16)

// ---- workspace layout (float offsets). Peak ~ 25.9M fl = 103.7 MB ----
#define OFF_GINB   0ull                 // bf16 [8192][608] = 2,490,368 fl
#define OFF_ASPECT 2490368ull
#define OFF_ABUF   2528768ull
#define OFF_AWB    2535168ull
#define OFF_ASCB   2573568ull
#define OFF_W1SUM  2622720ull
#define OFF_W2SUM  2623360ull
#define OFF_SWX    2624000ull
#define OFF_SBX    2624016ull
#define OFF_SG1    2624032ull
#define OFF_SG2    2632224ull
#define OFF_WHS    2640416ull           // fp32 [64][128][128]
#define OFF_WQKP   3688992ull           // bf16 [1200][608]
#define OFF_BQK    4053792ull
#define OFF_WWP    4054992ull           // bf16 [600][608]
#define OFF_WXXP   4237392ull           // bf16 [300][608]
#define OFF_WIHPF  4328592ull           // bf16 [1200][384]
#define OFF_WIHPB  4558992ull
#define OFF_BPF    4789392ull
#define OFF_BPB    4790592ull
#define OFF_WTB    4791792ull           // bf16 [2][1200][320]
#define OFF_EMBS   5216768ull           // bf16 [8192][384]
#define ARENA      6789632ull
#define OFF_XGF    (ARENA)                      // bf16 [8192][1200] = 4,915,200 fl
#define OFF_XGB    (ARENA + 4915200ull)         // bf16, 4,915,200 fl
#define OFF_HIST   (ARENA + 9830400ull)         // bf16 [2][129][64][320] = 2,641,920 fl
#define OFF_FLAGS  (ARENA + 12472320ull)        // 2048 fl (50 flags, 128B apart)
// post-lstm reuse (hist/flags dead after reshape; xg dead after lstm):
#define OFF_QKB    (ARENA)                      // fp32 [8192][1200]
#define OFF_ADJ    (ARENA + 9830400ull)         // fp32 [64][6][128][128] (over hist)
#define OFF_ADJS   (ARENA + 16121856ull)        // bf16 [64][128][128]
#define OFF_GINT   (ARENA + 16646144ull)        // bf16 [64][608][128]
#define OFF_AXB    (ARENA)                      // bf16 (over qkb, dead after attn)
#define OFF_G1B    (ARENA + 2490368ull)
#define OFF_G1T    (OFF_GINT)
#define OFF_AX2B   (ARENA + 4980736ull)
#define OFF_G2B    (ARENA + 7471104ull)
#define OFF_HNB    (ARENA + 9961472ull)         // fp32 [8192][300] (over adjb, dead)

typedef __bf16 bf16x8 __attribute__((ext_vector_type(8)));
typedef __bf16 bf16x4 __attribute__((ext_vector_type(4)));
typedef __bf16 bf16x2 __attribute__((ext_vector_type(2)));
typedef float  f32x4  __attribute__((ext_vector_type(4)));

__device__ __forceinline__ float sigm(float x){ return 1.f/(1.f+__expf(-x)); }
__device__ __forceinline__ float selu_f(float x){
  const float sc=1.0507009873554805f, al=1.6732632423543772f;
  return x>0.f ? sc*x : sc*al*(__expf(x)-1.f);
}
__device__ __forceinline__ bf16x8 bzero8(){
  bf16x8 z;
#pragma unroll
  for (int j=0;j<8;++j) z[j]=(__bf16)0.f;
  return z;
}

// ---------------- embedding concat -> bf16 [8192][384], pads written zero ----------------
__global__ __launch_bounds__(384) void embed_k(
    const int* __restrict__ tok, const int* __restrict__ pos_ids, const int* __restrict__ post_ids,
    const float* __restrict__ emb_w, const float* __restrict__ pos_w, const float* __restrict__ post_w,
    __bf16* __restrict__ embs)
{
  int bn = blockIdx.x, t = threadIdx.x;
  float v = 0.f;
  if      (t < 300) v = emb_w [(size_t)tok     [bn]*300 + t];
  else if (t < 330) v = pos_w [(size_t)pos_ids [bn]*30  + (t-300)];
  else if (t < 360) v = post_w[(size_t)post_ids[bn]*30  + (t-330)];
  embs[(size_t)bn*INP + t] = (__bf16)v;
}

// ---------------- Wx folded constants ----------------
__global__ __launch_bounds__(640) void consts_k(
    const float* __restrict__ Wx, const float* __restrict__ bx,
    float* __restrict__ w1sum, float* __restrict__ w2sum,
    float* __restrict__ swx, float* __restrict__ sbx)
{
  int t = threadIdx.x;
  if (t < DM){
    float s1=0.f, s2=0.f;
    for (int k=0;k<NH;++k){ s1 += Wx[k*WXROW + NH + t]; s2 += Wx[k*WXROW + NH + DM + t]; }
    w1sum[t]=s1; w2sum[t]=s2;
  } else if (t < DM+NH){
    int h=t-DM; float s=0.f;
    for (int k=0;k<NH;++k) s += Wx[k*WXROW + h];
    swx[h]=s;
  } else if (t == DM+NH){
    float s=0.f; for (int k=0;k<NH;++k) s += bx[k];
    sbx[0]=s;
  }
}

// ---------------- pack Wih (gate-interleaved rows p=4u+g) -> bf16 [1200][384] ----------------
__global__ __launch_bounds__(256) void wihp_k(
    const float* __restrict__ Wih, const float* __restrict__ b,
    __bf16* __restrict__ wp, float* __restrict__ bp)
{
  int idx = blockIdx.x*256 + threadIdx.x;
  if (idx < G4*INP){
    int p = idx / INP, k = idx - p*INP;
    int srow = (p&3)*RHID + (p>>2);
    wp[idx] = (k<INDIM) ? (__bf16)Wih[(size_t)srow*INDIM + k] : (__bf16)0.f;
  } else if (idx < G4*INP + G4){
    int p = idx - G4*INP;
    bp[p] = b[(p&3)*RHID + (p>>2)];
  }
}

// ---------------- pack Wq||Wk -> bf16 [1200][608], bias ----------------
__global__ __launch_bounds__(256) void wqkp_k(
    const float* __restrict__ Wq, const float* __restrict__ bq,
    const float* __restrict__ Wk, const float* __restrict__ bk,
    __bf16* __restrict__ wp, float* __restrict__ bp)
{
  int idx = blockIdx.x*256 + threadIdx.x;
  if (idx < G4*DMP){
    int n = idx / DMP, k = idx - n*DMP;
    float v = 0.f;
    if (k < DM) v = (n < DM) ? Wq[(size_t)n*DM + k] : Wk[(size_t)(n-DM)*DM + k];
    wp[idx] = (__bf16)v;
  } else if (idx < G4*DMP + G4){
    int n = idx - G4*DMP;
    bp[n] = (n < DM) ? bq[n] : bk[n-DM];
  }
}

// ---------------- generic weight pack fp32[n][ksrc] -> bf16[n][kp] (k-pads zero) ----------------
__global__ __launch_bounds__(256) void wpk_k(
    const float* __restrict__ W, __bf16* __restrict__ wp, int nrows, int ksrc, int kp)
{
  int idx = blockIdx.x*256 + threadIdx.x;
  if (idx >= nrows*kp) return;
  int n = idx / kp, k = idx - n*kp;
  wp[idx] = (k < ksrc) ? (__bf16)W[(size_t)n*ksrc + k] : (__bf16)0.f;
}

// ---------------- pack Whh -> bf16 [p=4u+g][KPAD] ----------------
__global__ __launch_bounds__(256) void whhp_k(
    const float* __restrict__ Whh, __bf16* __restrict__ outW)
{
  int idx = blockIdx.x*256 + threadIdx.x;
  if (idx >= G4*KPAD) return;
  int p = idx / KPAD, k = idx - p*KPAD;
  outW[idx] = (k < RHID) ? (__bf16)Whh[((size_t)((p&3)*RHID + (p>>2)))*RHID + k] : (__bf16)0.f;
}

// ---------------- zero hist slot0 (both dirs) + flags ----------------
__global__ __launch_bounds__(256) void init_k(float* __restrict__ ws)
{
  int idx = blockIdx.x*256 + threadIdx.x;
  if (idx < 10240)       ws[OFF_HIST + idx] = 0.f;                       // dir0 slot0
  else if (idx < 20480)  ws[OFF_HIST + 1320960ull + (idx-10240)] = 0.f;  // dir1 slot0
  else if (idx < 22528)  ws[OFF_FLAGS + (idx-20480)] = 0.f;              // flags
}

// ---------------- LDS-free bf16 MFMA GEMM: C = act(A @ B^T + bias) ----------------
template<int KT, int ACT, int OBF>
__global__ __launch_bounds__(256) void wgemm_k(
    const __bf16* __restrict__ A, const __bf16* __restrict__ B,
    const float* __restrict__ bias, void* __restrict__ Cout,
    int Nn, int Npad, int ldc,
    long long sA, long long sB, long long sC)
{
  const int tid = threadIdx.x, lane = tid & 63, wave = tid >> 6;
  const int fn = lane & 15, fq = lane >> 4;
  const int K = KT*32;
  const __bf16* Ab = A + (size_t)blockIdx.z * (size_t)sA;
  const __bf16* Bb = B + (size_t)blockIdx.z * (size_t)sB;
  float*  Cf = (float*) Cout + (size_t)blockIdx.z * (size_t)sC;
  __bf16* Ch = (__bf16*)Cout + (size_t)blockIdx.z * (size_t)sC;

  const int m0 = (blockIdx.x*4 + wave)*16;

  bf16x8 Af[KT];
#pragma unroll
  for (int kt=0; kt<KT; ++kt)
    Af[kt] = *(const bf16x8*)(Ab + (size_t)(m0 + fn)*K + kt*32 + fq*8);

  for (int n0 = blockIdx.y*16; n0 < Nn; n0 += 16*gridDim.y){
    const int gn = n0 + fn;
    const int gnc = (gn < Nn) ? gn : 0;
    f32x4 acc = {0.f,0.f,0.f,0.f};
#pragma unroll
    for (int kt=0; kt<KT; ++kt){
      bf16x8 Bf = *(const bf16x8*)(Bb + (size_t)gnc*K + kt*32 + fq*8);
      if (gn >= Nn) Bf = bzero8();
      acc = __builtin_amdgcn_mfma_f32_16x16x32_bf16(Af[kt], Bf, acc, 0, 0, 0);
    }
    float bv = (bias && gn < Nn) ? bias[gn] : 0.f;
#pragma unroll
    for (int r=0; r<4; ++r){
      int gm = m0 + fq*4 + r;
      float v = acc[r] + bv;
      if (ACT==1) v = selu_f(v);
      else if (ACT==2) v = fmaxf(v, 0.f);
      if (gn < Nn){
        if (OBF) Ch[(size_t)gm*ldc + gn] = (__bf16)v;
        else     Cf[(size_t)gm*ldc + gn] = v;
      } else if (gn < Npad){
        if (OBF) Ch[(size_t)gm*ldc + gn] = (__bf16)0.f;
        else     Cf[(size_t)gm*ldc + gn] = 0.f;
      }
    }
  }
}

// ---------------- legacy fp32 GEMM (only for tiny aspect@Wd) ----------------
template<bool TRANSB, int ACT>
__global__ __launch_bounds__(256) void gemm_k(
    const float* __restrict__ A, const float* __restrict__ Bm,
    const float* __restrict__ bias, float* __restrict__ C,
    int M, int Nn, int K, long long sA, long long sB, long long sC)
{
  __shared__ __align__(16) float As[16][132];
  __shared__ __align__(16) float Bs[16][132];
  const float* Ab = A  + (size_t)blockIdx.z * (size_t)sA;
  const float* Bb = Bm + (size_t)blockIdx.z * (size_t)sB;
  float*       Cb = C  + (size_t)blockIdx.z * (size_t)sC;
  const int m0 = blockIdx.y * 128, n0 = blockIdx.x * 128;
  const int lin = threadIdx.x;
  const int tx = lin & 15, ty = lin >> 4;
  float acc[8][8];
#pragma unroll
  for (int i=0;i<8;i++)
#pragma unroll
    for (int j=0;j<8;j++) acc[i][j]=0.f;
  for (int k0=0; k0<K; k0+=16) {
#pragma unroll
    for (int r=0;r<2;++r){
      int e = lin*2+r;
      int row = e>>2, kq=(e&3)*4;
      float4 v = make_float4(0.f,0.f,0.f,0.f);
      int gm=m0+row, gk=k0+kq;
      if (gm<M && gk<K) v = *(const float4*)(Ab + (size_t)gm*K + gk);
      As[kq+0][row]=v.x; As[kq+1][row]=v.y; As[kq+2][row]=v.z; As[kq+3][row]=v.w;
    }
#pragma unroll
    for (int r=0;r<2;++r){
      int e = lin*2+r;
      int col = e>>2, kq=(e&3)*4;
      float4 v = make_float4(0.f,0.f,0.f,0.f);
      int gn=n0+col, gk=k0+kq;
      if (gn<Nn && gk<K) v = *(const float4*)(Bb + (size_t)gn*K + gk);
      Bs[kq+0][col]=v.x; Bs[kq+1][col]=v.y; Bs[kq+2][col]=v.z; Bs[kq+3][col]=v.w;
    }
    __syncthreads();
#pragma unroll
    for (int kk=0;kk<16;++kk){
      float a[8], bv[8];
      *(float4*)&a[0]  = *(const float4*)&As[kk][ty*8];
      *(float4*)&a[4]  = *(const float4*)&As[kk][ty*8+4];
      *(float4*)&bv[0] = *(const float4*)&Bs[kk][tx*8];
      *(float4*)&bv[4] = *(const float4*)&Bs[kk][tx*8+4];
#pragma unroll
      for (int i=0;i<8;i++)
#pragma unroll
        for (int j=0;j<8;j++) acc[i][j] = fmaf(a[i], bv[j], acc[i][j]);
    }
    __syncthreads();
  }
#pragma unroll
  for (int i=0;i<8;i++){
    int gm = m0 + ty*8 + i;
    if (gm>=M) continue;
#pragma unroll
    for (int j=0;j<8;j+=4){
      int gn = n0 + tx*8 + j;
      if (gn>=Nn) continue;
      float t0=acc[i][j+0], t1=acc[i][j+1], t2=acc[i][j+2], t3=acc[i][j+3];
      if (bias){ t0+=bias[gn]; t1+=bias[gn+1]; t2+=bias[gn+2]; t3+=bias[gn+3]; }
      float4 v; v.x=t0; v.y=t1; v.z=t2; v.w=t3;
      *(float4*)(Cb + (size_t)gm*Nn + gn) = v;
    }
  }
}

// ---------------- bf16 per-batch transpose [64][128][608] -> [64][608][128] ----------------
__global__ __launch_bounds__(256) void tr_k(
    const __bf16* __restrict__ in, __bf16* __restrict__ out)
{
  const int b = blockIdx.z, m0 = blockIdx.y*64, d0 = blockIdx.x*64;
  const int tid = threadIdx.x;
  __shared__ __align__(16) __bf16 T[64][72];
  const __bf16* ib = in + (size_t)b*NN_*DMP;
  __bf16* ob = out + (size_t)b*DMP*NN_;
#pragma unroll
  for (int r=0;r<2;++r){
    int idx = tid + 256*r;
    int mi = idx>>3, ch = idx&7;
    int d = d0 + ch*8;
    bf16x8 v = bzero8();
    if (d < DMP) v = *(const bf16x8*)(ib + (size_t)(m0+mi)*DMP + d);
    *(bf16x8*)&T[mi][ch*8] = v;
  }
  __syncthreads();
#pragma unroll
  for (int r=0;r<2;++r){
    int idx = tid + 256*r;
    int di = idx>>3, mch = idx&7;
    int d = d0 + di;
    if (d >= DMP) continue;
    bf16x8 v;
#pragma unroll
    for (int j=0;j<8;++j) v[j] = T[mch*8+j][di];
    *(bf16x8*)(ob + (size_t)d*NN_ + m0 + mch*8) = v;
  }
}

// ---------------- cooperative-cluster MFMA LSTM — FENCE-FREE system-coherent sync ----------------
// h published via system-scope RELAXED atomic stores (sc0 sc1: write-through at L3, no dirty
// L2); flag RELAXED store after __syncthreads (vmcnt drain orders data before flag at L3).
// Consumer polls flags RELAXED SYSTEM, reads h via system-scope atomic loads (bypass stale
// L1/L2, always L3-fresh). No __threadfence (no buffer_wbl2/buffer_inv) anywhere in the loop.
__global__ __launch_bounds__(256, 1) void lstm_mfma_k(
    const __bf16* __restrict__ xgf, const __bf16* __restrict__ xgb,
    const __bf16* __restrict__ wtb,
    __bf16* hist, int* flags)
{
  const int blk = blockIdx.x;
  const int dir = blk / S_CL, sl = blk - dir*S_CL;
  const int tid = threadIdx.x, lane = tid & 63, wave = tid >> 6;
  const int p0 = sl * NSR;
  const __bf16* xg = dir ? xgb : xgf;
  const __bf16* W = wtb + (size_t)dir * G4 * KPAD;
  __bf16* hb = hist + (size_t)dir * DSTR;

  __shared__ __align__(16) float accS[NSR][68];

  const int fn = lane & 15;
  const int fk = (lane >> 4) * 8;
  const int m0 = wave * 16;

  bf16x8 Bf[3][10];
#pragma unroll
  for (int nt = 0; nt < 3; ++nt)
#pragma unroll
    for (int kt = 0; kt < 10; ++kt)
      Bf[nt][kt] = *(const bf16x8*)(W + (size_t)(p0 + nt*16 + fn)*KPAD + kt*32 + fk);

  // epilogue ownership: threads 0..191 own 4 consecutive units of one batch
  const int b_ep = tid / 3;
  const int q_ep = tid - b_ep*3;
  const int u0 = q_ep*4;
  const bool ep = (tid < 192);
  float cst[4] = {0.f,0.f,0.f,0.f};
  const __bf16* xp = xg + ((size_t)b_ep*NN_)*G4 + p0 + u0*4;  // 16 consecutive gates

  for (int s = 0; s < NN_; ++s){
    const int n_t = dir ? (NN_-1-s) : s;
    const __bf16* hbr = hb + (size_t)s*HSLOT;        // h(s-1)
    __bf16*       hbw = hb + (size_t)(s+1)*HSLOT;    // h(s)

    // prefetch xg (independent of h): 16 bf16 = gates of 4 units
    bf16x8 xv0, xv1;
    if (ep){
      xv0 = *(const bf16x8*)(xp + (size_t)n_t*G4);
      xv1 = *(const bf16x8*)(xp + (size_t)n_t*G4 + 8);
    }

    // A fragments: system-coherent loads (L3-fresh, bypass L1/L2)
    bf16x8 Af[10];
#pragma unroll
    for (int kt = 0; kt < 10; ++kt){
      const unsigned long long* hp =
          (const unsigned long long*)(hbr + (size_t)(m0 + fn)*KPAD + kt*32 + fk);
      union { unsigned long long u[2]; bf16x8 v; } cv;
      cv.u[0] = __hip_atomic_load(hp,   __ATOMIC_RELAXED, __HIP_MEMORY_SCOPE_SYSTEM);
      cv.u[1] = __hip_atomic_load(hp+1, __ATOMIC_RELAXED, __HIP_MEMORY_SCOPE_SYSTEM);
      Af[kt] = cv.v;
    }

    f32x4 acc[3] = { {0.f,0.f,0.f,0.f}, {0.f,0.f,0.f,0.f}, {0.f,0.f,0.f,0.f} };
#pragma unroll
    for (int kt = 0; kt < 10; ++kt)
#pragma unroll
      for (int nt = 0; nt < 3; ++nt)
        acc[nt] = __builtin_amdgcn_mfma_f32_16x16x32_bf16(Af[kt], Bf[nt][kt], acc[nt], 0, 0, 0);

#pragma unroll
    for (int nt = 0; nt < 3; ++nt)
      *(f32x4*)&accS[nt*16 + fn][m0 + (lane>>4)*4] = acc[nt];
    __syncthreads();

    if (ep){
      union { unsigned long long u; __bf16 h[4]; } pk;
      float xgv[16];
#pragma unroll
      for (int j=0;j<8;++j){ xgv[j]=(float)xv0[j]; xgv[8+j]=(float)xv1[j]; }
#pragma unroll
      for (int du = 0; du < 4; ++du){
        int u = u0 + du;
        float p_i = accS[u*4+0][b_ep] + xgv[du*4+0];
        float p_f = accS[u*4+1][b_ep] + xgv[du*4+1];
        float p_g = accS[u*4+2][b_ep] + xgv[du*4+2];
        float p_o = accS[u*4+3][b_ep] + xgv[du*4+3];
        float ig = sigm(p_i), fg = sigm(p_f), gg = tanhf(p_g), og = sigm(p_o);
        float c = fg*cst[du] + ig*gg; cst[du] = c;
        pk.h[du] = (__bf16)(og * tanhf(c));
      }
      __hip_atomic_store(
          (unsigned long long*)(hbw + (size_t)b_ep*KPAD + sl*NSU + u0),
          pk.u, __ATOMIC_RELAXED, __HIP_MEMORY_SCOPE_SYSTEM);
    }
    // ---- publish: barrier drains vmcnt (stores acked at L3), then flag ----
    __syncthreads();
    if (tid == 0)
      __hip_atomic_store(&flags[(dir*S_CL + sl)*32], s+1, __ATOMIC_RELAXED, __HIP_MEMORY_SCOPE_SYSTEM);
    // ---- wait: parallel relaxed system poll ----
    if (wave == 0 && lane < S_CL){
      int* fp = &flags[(dir*S_CL + lane)*32];
      while (__hip_atomic_load(fp, __ATOMIC_RELAXED, __HIP_MEMORY_SCOPE_SYSTEM) < s+1)
        __builtin_amdgcn_s_sleep(1);
    }
    __syncthreads();
  }
}

// ---------------- hist -> ginb [8192][608] (pads zeroed) ----------------
__global__ __launch_bounds__(320) void reshape_k(
    const __bf16* __restrict__ hist, __bf16* __restrict__ ginb)
{
  int row = blockIdx.x;                 // b*128 + n
  int b = row >> 7, n = row & 127;
  int t = threadIdx.x;
  if (t < 150){
    int u = 2*t;
    bf16x2 v = *(const bf16x2*)(hist + (size_t)(n+1)*HSLOT + (size_t)b*KPAD + u);
    *(bf16x2*)(ginb + (size_t)row*DMP + u) = v;
  } else if (t >= 160 && t < 310){
    int u = 2*(t-160);
    bf16x2 v = *(const bf16x2*)(hist + (size_t)DSTR + (size_t)(NN_-n)*HSLOT + (size_t)b*KPAD + u);
    *(bf16x2*)(ginb + (size_t)row*DMP + RHID + u) = v;
  } else if (t >= 312 && t < 316){
    int c = DM + 2*(t-312);
    bf16x2 z; z[0]=(__bf16)0.f; z[1]=(__bf16)0.f;
    *(bf16x2*)(ginb + (size_t)row*DMP + c) = z;
  }
}

// ---------------- masked mean over sequence -> aspect[B,DM] (bf16 in) ----------------
__global__ __launch_bounds__(640) void aspect_k(
    const __bf16* __restrict__ ginb, const float* __restrict__ mask, float* __restrict__ aspect)
{
  int b = blockIdx.x, t = threadIdx.x;
  __shared__ float msk[NN_];
  __shared__ float wn;
  if (t < NN_) msk[t] = mask[b*NN_+t];
  __syncthreads();
  if (t==0){ float s=0.f; for (int n=0;n<NN_;++n) s+=msk[n]; wn=s; }
  __syncthreads();
  if (t < DM){
    float s=0.f;
    for (int n=0;n<NN_;++n) s += (float)ginb[((size_t)(b*NN_+n))*DMP + t]*msk[n];
    aspect[b*DM+t] = s/wn;
  }
}

// ---------------- aw[b,h,e] = sum_d a[b,d] * weight_m[h,d,e] ----------------
__global__ __launch_bounds__(128) void aw_k(
    const float* __restrict__ a, const float* __restrict__ wm, float* __restrict__ aw)
{
  int b=blockIdx.x, h=blockIdx.y, e=threadIdx.x;
  if (e>=DKH) return;
  float s=0.f;
  for (int d=0; d<DKH; ++d) s += a[b*DKH+d]*wm[(h*DKH+d)*DKH+e];
  aw[(b*NH+h)*DKH+e]=s;
}

// ---------------- asc[b,h,m] = tanh(aw . k[b,h,m,:] + bias_m) ----------------
__global__ __launch_bounds__(128) void asc_k(
    const float* __restrict__ aw, const float* __restrict__ qkb,
    const float* __restrict__ bias_m, float* __restrict__ asc)
{
  int b=blockIdx.x, h=blockIdx.y, m=threadIdx.x;
  __shared__ __align__(16) float awl[DKH];
  if (m<DKH) awl[m]=aw[(b*NH+h)*DKH+m];
  __syncthreads();
  const float* kr = qkb + ((size_t)(b*NN_+m))*G4 + DM + h*DKH;
  const float4* a4=(const float4*)awl; const float4* k4=(const float4*)kr;
  float s=0.f;
#pragma unroll
  for (int e=0;e<DKH/4;e++){ float4 x=a4[e], y=k4[e]; s += x.x*y.x+x.y*y.y+x.z*y.z+x.w*y.w; }
  asc[(b*NH+h)*NN_+m] = tanhf(s + bias_m[0]);
}

// ---------------- scores + mask + short + softmax -> adj[B,H,N,N] ----------------
__global__ __launch_bounds__(128) void attn_k(
    const float* __restrict__ qkb, const float* __restrict__ asc,
    const float* __restrict__ shortm, const int* __restrict__ tok, float* __restrict__ adj)
{
  int n=blockIdx.x, h=blockIdx.y, b=blockIdx.z, m=threadIdx.x;
  __shared__ __align__(16) float qrow[DKH];
  __shared__ float red[NN_];
  if (m < DKH) qrow[m] = qkb[((size_t)(b*NN_+n))*G4 + h*DKH + m];
  __syncthreads();
  const float* kr = qkb + ((size_t)(b*NN_+m))*G4 + DM + h*DKH;
  const float4* q4=(const float4*)qrow; const float4* k4=(const float4*)kr;
  float s=0.f;
#pragma unroll
  for (int e=0;e<DKH/4;e++){ float4 x=q4[e], y=k4[e]; s += x.x*y.x+x.y*y.y+x.z*y.z+x.w*y.w; }
  s = s*0.1f + asc[(b*NH+h)*NN_+m];
  if (tok[b*NN_+m]==0) s = -1e9f;
  s += shortm[((size_t)(b*NN_+n))*NN_+m];
  red[m]=s; __syncthreads();
  for (int o=64;o;o>>=1){ if (m<o) red[m]=fmaxf(red[m],red[m+o]); __syncthreads(); }
  float mx = red[0]; __syncthreads();
  float e = __expf(s-mx);
  red[m]=e; __syncthreads();
  for (int o=64;o;o>>=1){ if (m<o) red[m]+=red[m+o]; __syncthreads(); }
  adj[(((size_t)b*NH+h)*NN_+n)*NN_+m] = e/red[0];
}

// ---------------- adjsum -> bf16 adjs (/H) + fp32 whs ----------------
__global__ __launch_bounds__(256) void adjsum_k(
    const float* __restrict__ adj, const float* __restrict__ swx,
    __bf16* __restrict__ adjs, float* __restrict__ whs)
{
  int idx = blockIdx.x*256 + threadIdx.x;
  int b = idx >> 14, rem = idx & 16383;
  float s=0.f, w=0.f;
  for (int h=0;h<NH;++h){
    float v = adj[(((size_t)b*NH+h)<<14) + rem];
    s += v; w += v*swx[h];
  }
  adjs[idx] = (__bf16)(s*(1.f/NH));
  whs [idx] = w*(1.f/NH);
}

// ---------------- sg1/sg2 from g1 (bf16) ----------------
__global__ __launch_bounds__(128) void sg_k(
    const __bf16* __restrict__ g1, const float* __restrict__ w1sum, const float* __restrict__ w2sum,
    float* __restrict__ sg1, float* __restrict__ sg2)
{
  int row = blockIdx.x*128 + threadIdx.x;
  const __bf16* gr = g1 + (size_t)row*DMP;
  float s1=0.f,s2=0.f;
  for (int d=0;d<DM;++d){ float g=(float)gr[d]; s1+=g*w1sum[d]; s2+=g*w2sum[d]; }
  sg1[row]=s1; sg2[row]=s2;
}

// ---------------- adjs2[b,i,j] = whs + (sg1[b,j]+sg2[b,i]+sbx)/H -> bf16 ----------------
__global__ __launch_bounds__(256) void adjsum2_k(
    const float* __restrict__ whs, const float* __restrict__ sg1, const float* __restrict__ sg2,
    const float* __restrict__ sbx, __bf16* __restrict__ adjs)
{
  int idx = blockIdx.x*256 + threadIdx.x;
  int b = idx >> 14, rem = idx & 16383;
  int i = rem >> 7, j = rem & 127;
  adjs[idx] = (__bf16)(whs[idx] + (sg1[b*NN_+j] + sg2[b*NN_+i] + sbx[0])*(1.f/NH));
}

// ---------------- pooled mean + logits ----------------
__global__ __launch_bounds__(320) void pooled_k(
    const float* __restrict__ hn, const float* __restrict__ mask,
    const float* __restrict__ Wc, const float* __restrict__ bc, float* __restrict__ out)
{
  int b=blockIdx.x, t=threadIdx.x;
  __shared__ float msk[NN_];
  __shared__ float pl[RHID];
  __shared__ float wn;
  if (t<NN_) msk[t]=mask[b*NN_+t];
  __syncthreads();
  if (t==0){ float s=0.f; for (int n=0;n<NN_;++n) s+=msk[n]; wn=s; }
  __syncthreads();
  if (t<RHID){
    float s=0.f;
    for (int n=0;n<NN_;++n) s += hn[((size_t)(b*NN_+n))*RHID+t]*msk[n];
    pl[t]=s/wn;
  }
  __syncthreads();
  if (t<3){
    float s=bc[t];
    for (int d=0;d<RHID;++d) s += pl[d]*Wc[t*RHID+d];
    out[b*3+t]=s;
  }
}

extern "C" void kernel_launch(void* const* d_in, const int* in_sizes, int n_in,
                              void* d_out, int out_size, void* d_ws, size_t ws_size,
                              hipStream_t stream)
{
  (void)in_sizes; (void)n_in; (void)out_size; (void)ws_size;
  const int*   tok      = (const int*)  d_in[0];
  const int*   pos_ids  = (const int*)  d_in[2];
  const int*   post_ids = (const int*)  d_in[5];
  const float* mask     = (const float*)d_in[6];
  const float* shortm   = (const float*)d_in[8];
  const float* emb_w    = (const float*)d_in[9];
  const float* pos_w    = (const float*)d_in[10];
  const float* post_w   = (const float*)d_in[11];
  const float* Wih_f    = (const float*)d_in[12];
  const float* Whh_f    = (const float*)d_in[13];
  const float* b_f      = (const float*)d_in[14];
  const float* Wih_b    = (const float*)d_in[15];
  const float* Whh_b    = (const float*)d_in[16];
  const float* b_b      = (const float*)d_in[17];
  const float* Wq       = (const float*)d_in[18];
  const float* bq       = (const float*)d_in[19];
  const float* Wk       = (const float*)d_in[20];
  const float* bk       = (const float*)d_in[21];
  const float* Wd       = (const float*)d_in[22];
  const float* bd       = (const float*)d_in[23];
  const float* weight_m = (const float*)d_in[24];
  const float* bias_m   = (const float*)d_in[25];
  const float* Ww       = (const float*)d_in[26];
  const float* bw       = (const float*)d_in[27];
  const float* Wx       = (const float*)d_in[28];
  const float* bx       = (const float*)d_in[29];
  const float* Wxx      = (const float*)d_in[30];
  const float* bxx      = (const float*)d_in[31];
  const float* Wc       = (const float*)d_in[32];
  const float* bc       = (const float*)d_in[33];

  float* ws  = (float*)d_ws;
  float* out = (float*)d_out;

  __bf16* ginb  = (__bf16*)(ws + OFF_GINB);
  float* aspect = ws + OFF_ASPECT;
  float* abuf   = ws + OFF_ABUF;
  float* awb    = ws + OFF_AWB;
  float* ascb   = ws + OFF_ASCB;
  float* w1sum  = ws + OFF_W1SUM;
  float* w2sum  = ws + OFF_W2SUM;
  float* swx    = ws + OFF_SWX;
  float* sbx    = ws + OFF_SBX;
  float* sg1    = ws + OFF_SG1;
  float* sg2    = ws + OFF_SG2;
  float* whs    = ws + OFF_WHS;
  __bf16* wqkp  = (__bf16*)(ws + OFF_WQKP);
  float* bqk    = ws + OFF_BQK;
  __bf16* wwp   = (__bf16*)(ws + OFF_WWP);
  __bf16* wxxp  = (__bf16*)(ws + OFF_WXXP);
  __bf16* wihpF = (__bf16*)(ws + OFF_WIHPF);
  __bf16* wihpB = (__bf16*)(ws + OFF_WIHPB);
  float* bpF    = ws + OFF_BPF;
  float* bpB    = ws + OFF_BPB;
  __bf16* wtb   = (__bf16*)(ws + OFF_WTB);
  __bf16* embs  = (__bf16*)(ws + OFF_EMBS);
  __bf16* xgf   = (__bf16*)(ws + OFF_XGF);
  __bf16* xgb   = (__bf16*)(ws + OFF_XGB);
  __bf16* hist  = (__bf16*)(ws + OFF_HIST);
  int*   flags  = (int*)(ws + OFF_FLAGS);
  float* qkb    = ws + OFF_QKB;
  float* adjb   = ws + OFF_ADJ;
  __bf16* adjs  = (__bf16*)(ws + OFF_ADJS);
  __bf16* gint  = (__bf16*)(ws + OFF_GINT);
  __bf16* axb   = (__bf16*)(ws + OFF_AXB);
  __bf16* g1b   = (__bf16*)(ws + OFF_G1B);
  __bf16* g1t   = (__bf16*)(ws + OFF_G1T);
  __bf16* ax2b  = (__bf16*)(ws + OFF_AX2B);
  __bf16* g2b   = (__bf16*)(ws + OFF_G2B);
  float* hnb    = ws + OFF_HNB;

  // 1. embeddings, constants, weight packing, init
  embed_k<<<dim3(BB*NN_),384,0,stream>>>(tok,pos_ids,post_ids,emb_w,pos_w,post_w,embs);
  consts_k<<<1,640,0,stream>>>(Wx,bx,w1sum,w2sum,swx,sbx);
  wihp_k<<<dim3((G4*INP+G4+255)/256),256,0,stream>>>(Wih_f,b_f,wihpF,bpF);
  wihp_k<<<dim3((G4*INP+G4+255)/256),256,0,stream>>>(Wih_b,b_b,wihpB,bpB);
  wqkp_k<<<dim3((G4*DMP+G4+255)/256),256,0,stream>>>(Wq,bq,Wk,bk,wqkp,bqk);
  wpk_k<<<dim3((DM*DMP+255)/256),256,0,stream>>>(Ww,wwp,DM,DM,DMP);
  wpk_k<<<dim3((RHID*DMP+255)/256),256,0,stream>>>(Wxx,wxxp,RHID,DM,DMP);
  whhp_k<<<dim3((G4*KPAD+255)/256),256,0,stream>>>(Whh_f, wtb);
  whhp_k<<<dim3((G4*KPAD+255)/256),256,0,stream>>>(Whh_b, wtb + (size_t)G4*KPAD);
  init_k<<<dim3((22528+255)/256),256,0,stream>>>(ws);
  // 2. LSTM input projections (bf16 MFMA, LDS-free), bf16 out
  wgemm_k<12,0,1><<<dim3(128,4,1),256,0,stream>>>(embs,wihpF,bpF,xgf, G4,G4,G4, 0,0,0);
  wgemm_k<12,0,1><<<dim3(128,4,1),256,0,stream>>>(embs,wihpB,bpB,xgb, G4,G4,G4, 0,0,0);
  // 3. recurrence (fence-free system-coherent cluster sync)
  lstm_mfma_k<<<dim3(2*S_CL),256,0,stream>>>(xgf,xgb,wtb,hist,flags);
  reshape_k<<<dim3(BB*NN_),320,0,stream>>>(hist,ginb);
  // 4. fused Q||K projection, aspect path
  wgemm_k<19,0,0><<<dim3(128,4,1),256,0,stream>>>(ginb,wqkp,bqk,qkb, G4,G4,G4, 0,0,0);
  aspect_k<<<BB,640,0,stream>>>(ginb,mask,aspect);
  gemm_k<false,0><<<dim3(1,1,1),256,0,stream>>>(aspect,Wd,bd,abuf, BB,DKH,DM, 0,0,0);
  aw_k <<<dim3(BB,NH),128,0,stream>>>(abuf,weight_m,awb);
  asc_k<<<dim3(BB,NH),128,0,stream>>>(awb,qkb,bias_m,ascb);
  // 5. scores + softmax
  attn_k<<<dim3(NN_,NH,BB),128,0,stream>>>(qkb,ascb,shortm,tok,adjb);
  // 6. GCN layer 1 (bf16 MFMA)
  adjsum_k<<<4096,256,0,stream>>>(adjb,swx,adjs,whs);
  tr_k<<<dim3(10,2,BB),256,0,stream>>>(ginb,gint);
  wgemm_k<4,0,1><<<dim3(2,4,BB),256,0,stream>>>(adjs,gint,nullptr,axb, DM,DMP,DMP, 16384,(long long)DMP*NN_,(long long)NN_*DMP);
  wgemm_k<19,1,1><<<dim3(128,4,1),256,0,stream>>>(axb,wwp,bw,g1b, DM,DMP,DMP, 0,0,0);
  // 7. layer-2 adjacency collapsed
  sg_k<<<64,128,0,stream>>>(g1b,w1sum,w2sum,sg1,sg2);
  adjsum2_k<<<4096,256,0,stream>>>(whs,sg1,sg2,sbx,adjs);
  // 8. GCN layer 2
  tr_k<<<dim3(10,2,BB),256,0,stream>>>(g1b,g1t);
  wgemm_k<4,0,1><<<dim3(2,4,BB),256,0,stream>>>(adjs,g1t,nullptr,ax2b, DM,DMP,DMP, 16384,(long long)DMP*NN_,(long long)NN_*DMP);
  wgemm_k<19,1,1><<<dim3(128,4,1),256,0,stream>>>(ax2b,wwp,bw,g2b, DM,DMP,DMP, 0,0,0);
  // 9. head
  wgemm_k<19,2,0><<<dim3(128,4,1),256,0,stream>>>(g2b,wxxp,bxx,hnb, RHID,RHID,RHID, 0,0,0);
  pooled_k<<<BB,320,0,stream>>>(hnb,mask,Wc,bc,out);
}

// Round 8
// 1491.033 us; speedup vs baseline: 1.7876x; 1.1692x over previous
//
#include <hip/hip_runtime.h>
#include <math.h>

// ---- problem constants ----
#define BB    64
#define NN_   128
#define NH    6
#define DM    600     // d_model
#define RHID  300     // rnn hidden
#define DKH   100     // per-head dim
#define INDIM 360
#define G4    1200    // 4*RHID
#define WXROW 1206    // NH + 2*DM
#define DMP   608     // DM padded to mult of 32
#define INP   384     // INDIM padded
#define QKL   1536    // 2 * NH * 128 (head-padded q||k row length)

// ---- LSTM cluster config ----
#define S_CL  25
#define NSU   12
#define NSR   48
#define KPAD  320
#define HSLOT (BB*KPAD)          // 20480 bf16 per history slot
#define DSTR  (129*HSLOT)        // per-dir history stride (bf16)

// ---- workspace layout (float offsets). Peak ~ 25.94M fl = 103.8 MB ----
#define OFF_GINB   0ull                 // bf16 [8192][608] = 2,490,368 fl
#define OFF_ASPECT 2490368ull
#define OFF_ABUF   2528768ull
#define OFF_AWB    2535168ull
#define OFF_ASCB   2573568ull
#define OFF_W1SUM  2622720ull
#define OFF_W2SUM  2623360ull
#define OFF_SWX    2624000ull
#define OFF_SBX    2624016ull
#define OFF_SGI    2624032ull           // fp32 [8192][2] interleaved (sg1,sg2)
#define OFF_WHS    2640416ull           // fp32 [64][128][128]
#define OFF_WQKP   3688992ull           // bf16 [1536][608] = 466,944 fl
#define OFF_BQK    4155936ull           // fp32 1536
#define OFF_WWP    4157472ull           // bf16 [600][608] = 182,400 fl
#define OFF_WXXP   4339872ull           // bf16 [300][608] = 91,200 fl
#define OFF_WIHPF  4431072ull           // bf16 [1200][384] = 230,400 fl
#define OFF_WIHPB  4661472ull
#define OFF_BPF    4891872ull
#define OFF_BPB    4893072ull
#define OFF_WTB    4894272ull           // bf16 [2][1200][320] = 384,000 fl
#define OFF_EMBS   5278272ull           // bf16 [8192][384] = 1,572,864 fl
#define ARENA      6851136ull
#define OFF_XGF    (ARENA)                      // bf16 [8192][1200] = 4,915,200 fl
#define OFF_XGB    (ARENA + 4915200ull)         // bf16, 4,915,200 fl
#define OFF_HIST   (ARENA + 9830400ull)         // bf16 [2][129][64][320] = 2,641,920 fl
#define OFF_FLAGS  (ARENA + 12472320ull)        // flags (50, 128B apart)
// post-lstm reuse (xg dead after lstm; hist/flags dead after reshape):
#define OFF_QKH    (ARENA)                      // bf16 [8192][1536] = 6,291,456 fl (over xg)
#define OFF_ADJ    (ARENA + 6291456ull)         // bf16 [64][6][128][128] = 3,145,728 fl
#define OFF_ADJS   (ARENA + 16121856ull)        // bf16 [64][128][128] = 524,288 fl
#define OFF_GINT   (ARENA + 16646144ull)        // bf16 [64][608][128] = 2,490,368 fl
#define OFF_W12    (ARENA + 19136512ull)        // bf16 [2][608] = 608 fl
#define OFF_AXB    (ARENA)                      // bf16 (over qkh, dead after attn2/asc)
#define OFF_G1B    (ARENA + 2490368ull)
#define OFF_G1T    (OFF_GINT)
#define OFF_AX2B   (ARENA + 4980736ull)
#define OFF_G2B    (ARENA + 7471104ull)         // over adj (dead after adjsum)
#define OFF_HNB    (ARENA + 9961472ull)         // fp32 [8192][300] (over hist, dead)

typedef __bf16 bf16x8 __attribute__((ext_vector_type(8)));
typedef __bf16 bf16x4 __attribute__((ext_vector_type(4)));
typedef __bf16 bf16x2 __attribute__((ext_vector_type(2)));
typedef float  f32x4  __attribute__((ext_vector_type(4)));

__device__ __forceinline__ float sigm(float x){ return 1.f/(1.f+__expf(-x)); }
__device__ __forceinline__ float selu_f(float x){
  const float sc=1.0507009873554805f, al=1.6732632423543772f;
  return x>0.f ? sc*x : sc*al*(__expf(x)-1.f);
}
__device__ __forceinline__ bf16x8 bzero8(){
  bf16x8 z;
#pragma unroll
  for (int j=0;j<8;++j) z[j]=(__bf16)0.f;
  return z;
}

// ---------------- embedding concat -> bf16 [8192][384], pads written zero ----------------
__global__ __launch_bounds__(384) void embed_k(
    const int* __restrict__ tok, const int* __restrict__ pos_ids, const int* __restrict__ post_ids,
    const float* __restrict__ emb_w, const float* __restrict__ pos_w, const float* __restrict__ post_w,
    __bf16* __restrict__ embs)
{
  int bn = blockIdx.x, t = threadIdx.x;
  float v = 0.f;
  if      (t < 300) v = emb_w [(size_t)tok     [bn]*300 + t];
  else if (t < 330) v = pos_w [(size_t)pos_ids [bn]*30  + (t-300)];
  else if (t < 360) v = post_w[(size_t)post_ids[bn]*30  + (t-330)];
  embs[(size_t)bn*INP + t] = (__bf16)v;
}

// ---------------- Wx folded constants (+ bf16 w12 for the sg GEMV) ----------------
__global__ __launch_bounds__(640) void consts_k(
    const float* __restrict__ Wx, const float* __restrict__ bx,
    float* __restrict__ w1sum, float* __restrict__ w2sum,
    float* __restrict__ swx, float* __restrict__ sbx, __bf16* __restrict__ w12)
{
  int t = threadIdx.x;
  if (t < DM){
    float s1=0.f, s2=0.f;
    for (int k=0;k<NH;++k){ s1 += Wx[k*WXROW + NH + t]; s2 += Wx[k*WXROW + NH + DM + t]; }
    w1sum[t]=s1; w2sum[t]=s2;
    w12[t]=(__bf16)s1; w12[DMP+t]=(__bf16)s2;
  } else if (t < DM+NH){
    int h=t-DM; float s=0.f;
    for (int k=0;k<NH;++k) s += Wx[k*WXROW + h];
    swx[h]=s;
  } else if (t == DM+NH){
    float s=0.f; for (int k=0;k<NH;++k) s += bx[k];
    sbx[0]=s;
  }
  if (t >= DM && t < DMP){ w12[t]=(__bf16)0.f; w12[DMP+t]=(__bf16)0.f; }
}

// ---------------- pack Wih (gate-interleaved rows p=4u+g) -> bf16 [1200][384] ----------------
__global__ __launch_bounds__(256) void wihp_k(
    const float* __restrict__ Wih, const float* __restrict__ b,
    __bf16* __restrict__ wp, float* __restrict__ bp)
{
  int idx = blockIdx.x*256 + threadIdx.x;
  if (idx < G4*INP){
    int p = idx / INP, k = idx - p*INP;
    int srow = (p&3)*RHID + (p>>2);
    wp[idx] = (k<INDIM) ? (__bf16)Wih[(size_t)srow*INDIM + k] : (__bf16)0.f;
  } else if (idx < G4*INP + G4){
    int p = idx - G4*INP;
    bp[p] = b[(p&3)*RHID + (p>>2)];
  }
}

// ---------------- pack Wq||Wk head-padded -> bf16 [1536][608], bias [1536] ----------------
// output row n: n<768 -> q head h=n>>7, e=n&127; else k head. e>=100 rows are ZERO
// (=> qkh pad cols are exactly 0: score dots over K=128 are correct).
__global__ __launch_bounds__(256) void wqkhp_k(
    const float* __restrict__ Wq, const float* __restrict__ bq,
    const float* __restrict__ Wk, const float* __restrict__ bk,
    __bf16* __restrict__ wp, float* __restrict__ bp)
{
  int idx = blockIdx.x*256 + threadIdx.x;
  if (idx < QKL*DMP){
    int n = idx / DMP, k = idx - n*DMP;
    int nl = (n < 768) ? n : n - 768;
    int h = nl >> 7, e = nl & 127;
    float v = 0.f;
    if (k < DM && e < DKH)
      v = (n < 768) ? Wq[(size_t)(h*DKH+e)*DM + k] : Wk[(size_t)(h*DKH+e)*DM + k];
    wp[idx] = (__bf16)v;
  } else if (idx < QKL*DMP + QKL){
    int n = idx - QKL*DMP;
    int nl = (n < 768) ? n : n - 768;
    int h = nl >> 7, e = nl & 127;
    bp[n] = (e < DKH) ? ((n < 768) ? bq[h*DKH+e] : bk[h*DKH+e]) : 0.f;
  }
}

// ---------------- generic weight pack fp32[n][ksrc] -> bf16[n][kp] (k-pads zero) ----------------
__global__ __launch_bounds__(256) void wpk_k(
    const float* __restrict__ W, __bf16* __restrict__ wp, int nrows, int ksrc, int kp)
{
  int idx = blockIdx.x*256 + threadIdx.x;
  if (idx >= nrows*kp) return;
  int n = idx / kp, k = idx - n*kp;
  wp[idx] = (k < ksrc) ? (__bf16)W[(size_t)n*ksrc + k] : (__bf16)0.f;
}

// ---------------- pack Whh -> bf16 [p=4u+g][KPAD] ----------------
__global__ __launch_bounds__(256) void whhp_k(
    const float* __restrict__ Whh, __bf16* __restrict__ outW)
{
  int idx = blockIdx.x*256 + threadIdx.x;
  if (idx >= G4*KPAD) return;
  int p = idx / KPAD, k = idx - p*KPAD;
  outW[idx] = (k < RHID) ? (__bf16)Whh[((size_t)((p&3)*RHID + (p>>2)))*RHID + k] : (__bf16)0.f;
}

// ---------------- zero hist slot0 (both dirs) + flags ----------------
__global__ __launch_bounds__(256) void init_k(float* __restrict__ ws)
{
  int idx = blockIdx.x*256 + threadIdx.x;
  if (idx < 10240)       ws[OFF_HIST + idx] = 0.f;                       // dir0 slot0
  else if (idx < 20480)  ws[OFF_HIST + 1320960ull + (idx-10240)] = 0.f;  // dir1 slot0
  else if (idx < 22528)  ws[OFF_FLAGS + (idx-20480)] = 0.f;              // flags
}

// ---------------- LDS-free bf16 MFMA GEMM: C = act(A @ B^T + bias) ----------------
template<int KT, int ACT, int OBF>
__global__ __launch_bounds__(256) void wgemm_k(
    const __bf16* __restrict__ A, const __bf16* __restrict__ B,
    const float* __restrict__ bias, void* __restrict__ Cout,
    int Nn, int Npad, int ldc,
    long long sA, long long sB, long long sC)
{
  const int tid = threadIdx.x, lane = tid & 63, wave = tid >> 6;
  const int fn = lane & 15, fq = lane >> 4;
  const int K = KT*32;
  const __bf16* Ab = A + (size_t)blockIdx.z * (size_t)sA;
  const __bf16* Bb = B + (size_t)blockIdx.z * (size_t)sB;
  float*  Cf = (float*) Cout + (size_t)blockIdx.z * (size_t)sC;
  __bf16* Ch = (__bf16*)Cout + (size_t)blockIdx.z * (size_t)sC;

  const int m0 = (blockIdx.x*4 + wave)*16;

  bf16x8 Af[KT];
#pragma unroll
  for (int kt=0; kt<KT; ++kt)
    Af[kt] = *(const bf16x8*)(Ab + (size_t)(m0 + fn)*K + kt*32 + fq*8);

  for (int n0 = blockIdx.y*16; n0 < Nn; n0 += 16*gridDim.y){
    const int gn = n0 + fn;
    const int gnc = (gn < Nn) ? gn : 0;
    f32x4 acc = {0.f,0.f,0.f,0.f};
#pragma unroll
    for (int kt=0; kt<KT; ++kt){
      bf16x8 Bf = *(const bf16x8*)(Bb + (size_t)gnc*K + kt*32 + fq*8);
      if (gn >= Nn) Bf = bzero8();
      acc = __builtin_amdgcn_mfma_f32_16x16x32_bf16(Af[kt], Bf, acc, 0, 0, 0);
    }
    float bv = (bias && gn < Nn) ? bias[gn] : 0.f;
#pragma unroll
    for (int r=0; r<4; ++r){
      int gm = m0 + fq*4 + r;
      float v = acc[r] + bv;
      if (ACT==1) v = selu_f(v);
      else if (ACT==2) v = fmaxf(v, 0.f);
      if (gn < Nn){
        if (OBF) Ch[(size_t)gm*ldc + gn] = (__bf16)v;
        else     Cf[(size_t)gm*ldc + gn] = v;
      } else if (gn < Npad){
        if (OBF) Ch[(size_t)gm*ldc + gn] = (__bf16)0.f;
        else     Cf[(size_t)gm*ldc + gn] = 0.f;
      }
    }
  }
}

// ---------------- legacy fp32 GEMM (only for tiny aspect@Wd) ----------------
template<bool TRANSB, int ACT>
__global__ __launch_bounds__(256) void gemm_k(
    const float* __restrict__ A, const float* __restrict__ Bm,
    const float* __restrict__ bias, float* __restrict__ C,
    int M, int Nn, int K, long long sA, long long sB, long long sC)
{
  __shared__ __align__(16) float As[16][132];
  __shared__ __align__(16) float Bs[16][132];
  const float* Ab = A  + (size_t)blockIdx.z * (size_t)sA;
  const float* Bb = Bm + (size_t)blockIdx.z * (size_t)sB;
  float*       Cb = C  + (size_t)blockIdx.z * (size_t)sC;
  const int m0 = blockIdx.y * 128, n0 = blockIdx.x * 128;
  const int lin = threadIdx.x;
  const int tx = lin & 15, ty = lin >> 4;
  float acc[8][8];
#pragma unroll
  for (int i=0;i<8;i++)
#pragma unroll
    for (int j=0;j<8;j++) acc[i][j]=0.f;
  for (int k0=0; k0<K; k0+=16) {
#pragma unroll
    for (int r=0;r<2;++r){
      int e = lin*2+r;
      int row = e>>2, kq=(e&3)*4;
      float4 v = make_float4(0.f,0.f,0.f,0.f);
      int gm=m0+row, gk=k0+kq;
      if (gm<M && gk<K) v = *(const float4*)(Ab + (size_t)gm*K + gk);
      As[kq+0][row]=v.x; As[kq+1][row]=v.y; As[kq+2][row]=v.z; As[kq+3][row]=v.w;
    }
#pragma unroll
    for (int r=0;r<2;++r){
      int e = lin*2+r;
      int col = e>>2, kq=(e&3)*4;
      float4 v = make_float4(0.f,0.f,0.f,0.f);
      int gn=n0+col, gk=k0+kq;
      if (gn<Nn && gk<K) v = *(const float4*)(Bb + (size_t)gn*K + gk);
      Bs[kq+0][col]=v.x; Bs[kq+1][col]=v.y; Bs[kq+2][col]=v.z; Bs[kq+3][col]=v.w;
    }
    __syncthreads();
#pragma unroll
    for (int kk=0;kk<16;++kk){
      float a[8], bv[8];
      *(float4*)&a[0]  = *(const float4*)&As[kk][ty*8];
      *(float4*)&a[4]  = *(const float4*)&As[kk][ty*8+4];
      *(float4*)&bv[0] = *(const float4*)&Bs[kk][tx*8];
      *(float4*)&bv[4] = *(const float4*)&Bs[kk][tx*8+4];
#pragma unroll
      for (int i=0;i<8;i++)
#pragma unroll
        for (int j=0;j<8;j++) acc[i][j] = fmaf(a[i], bv[j], acc[i][j]);
    }
    __syncthreads();
  }
#pragma unroll
  for (int i=0;i<8;i++){
    int gm = m0 + ty*8 + i;
    if (gm>=M) continue;
#pragma unroll
    for (int j=0;j<8;j+=4){
      int gn = n0 + tx*8 + j;
      if (gn>=Nn) continue;
      float t0=acc[i][j+0], t1=acc[i][j+1], t2=acc[i][j+2], t3=acc[i][j+3];
      if (bias){ t0+=bias[gn]; t1+=bias[gn+1]; t2+=bias[gn+2]; t3+=bias[gn+3]; }
      float4 v; v.x=t0; v.y=t1; v.z=t2; v.w=t3;
      *(float4*)(Cb + (size_t)gm*Nn + gn) = v;
    }
  }
}

// ---------------- bf16 per-batch transpose [64][128][608] -> [64][608][128] ----------------
__global__ __launch_bounds__(256) void tr_k(
    const __bf16* __restrict__ in, __bf16* __restrict__ out)
{
  const int b = blockIdx.z, m0 = blockIdx.y*64, d0 = blockIdx.x*64;
  const int tid = threadIdx.x;
  __shared__ __align__(16) __bf16 T[64][72];
  const __bf16* ib = in + (size_t)b*NN_*DMP;
  __bf16* ob = out + (size_t)b*DMP*NN_;
#pragma unroll
  for (int r=0;r<2;++r){
    int idx = tid + 256*r;
    int mi = idx>>3, ch = idx&7;
    int d = d0 + ch*8;
    bf16x8 v = bzero8();
    if (d < DMP) v = *(const bf16x8*)(ib + (size_t)(m0+mi)*DMP + d);
    *(bf16x8*)&T[mi][ch*8] = v;
  }
  __syncthreads();
#pragma unroll
  for (int r=0;r<2;++r){
    int idx = tid + 256*r;
    int di = idx>>3, mch = idx&7;
    int d = d0 + di;
    if (d >= DMP) continue;
    bf16x8 v;
#pragma unroll
    for (int j=0;j<8;++j) v[j] = T[mch*8+j][di];
    *(bf16x8*)(ob + (size_t)d*NN_ + m0 + mch*8) = v;
  }
}

// ---------------- cooperative-cluster MFMA LSTM — fence-free system-coherent sync ----------------
__global__ __launch_bounds__(256, 1) void lstm_mfma_k(
    const __bf16* __restrict__ xgf, const __bf16* __restrict__ xgb,
    const __bf16* __restrict__ wtb,
    __bf16* hist, int* flags)
{
  const int blk = blockIdx.x;
  const int dir = blk / S_CL, sl = blk - dir*S_CL;
  const int tid = threadIdx.x, lane = tid & 63, wave = tid >> 6;
  const int p0 = sl * NSR;
  const __bf16* xg = dir ? xgb : xgf;
  const __bf16* W = wtb + (size_t)dir * G4 * KPAD;
  __bf16* hb = hist + (size_t)dir * DSTR;

  __shared__ __align__(16) float accS[NSR][68];

  const int fn = lane & 15;
  const int fk = (lane >> 4) * 8;
  const int m0 = wave * 16;

  bf16x8 Bf[3][10];
#pragma unroll
  for (int nt = 0; nt < 3; ++nt)
#pragma unroll
    for (int kt = 0; kt < 10; ++kt)
      Bf[nt][kt] = *(const bf16x8*)(W + (size_t)(p0 + nt*16 + fn)*KPAD + kt*32 + fk);

  const int b_ep = tid / 3;
  const int q_ep = tid - b_ep*3;
  const int u0 = q_ep*4;
  const bool ep = (tid < 192);
  float cst[4] = {0.f,0.f,0.f,0.f};
  const __bf16* xp = xg + ((size_t)b_ep*NN_)*G4 + p0 + u0*4;

  for (int s = 0; s < NN_; ++s){
    const int n_t = dir ? (NN_-1-s) : s;
    const __bf16* hbr = hb + (size_t)s*HSLOT;
    __bf16*       hbw = hb + (size_t)(s+1)*HSLOT;

    bf16x8 xv0, xv1;
    if (ep){
      xv0 = *(const bf16x8*)(xp + (size_t)n_t*G4);
      xv1 = *(const bf16x8*)(xp + (size_t)n_t*G4 + 8);
    }

    bf16x8 Af[10];
#pragma unroll
    for (int kt = 0; kt < 10; ++kt){
      const unsigned long long* hp =
          (const unsigned long long*)(hbr + (size_t)(m0 + fn)*KPAD + kt*32 + fk);
      union { unsigned long long u[2]; bf16x8 v; } cv;
      cv.u[0] = __hip_atomic_load(hp,   __ATOMIC_RELAXED, __HIP_MEMORY_SCOPE_SYSTEM);
      cv.u[1] = __hip_atomic_load(hp+1, __ATOMIC_RELAXED, __HIP_MEMORY_SCOPE_SYSTEM);
      Af[kt] = cv.v;
    }

    f32x4 acc[3] = { {0.f,0.f,0.f,0.f}, {0.f,0.f,0.f,0.f}, {0.f,0.f,0.f,0.f} };
#pragma unroll
    for (int kt = 0; kt < 10; ++kt)
#pragma unroll
      for (int nt = 0; nt < 3; ++nt)
        acc[nt] = __builtin_amdgcn_mfma_f32_16x16x32_bf16(Af[kt], Bf[nt][kt], acc[nt], 0, 0, 0);

#pragma unroll
    for (int nt = 0; nt < 3; ++nt)
      *(f32x4*)&accS[nt*16 + fn][m0 + (lane>>4)*4] = acc[nt];
    __syncthreads();

    if (ep){
      union { unsigned long long u; __bf16 h[4]; } pk;
      float xgv[16];
#pragma unroll
      for (int j=0;j<8;++j){ xgv[j]=(float)xv0[j]; xgv[8+j]=(float)xv1[j]; }
#pragma unroll
      for (int du = 0; du < 4; ++du){
        int u = u0 + du;
        float p_i = accS[u*4+0][b_ep] + xgv[du*4+0];
        float p_f = accS[u*4+1][b_ep] + xgv[du*4+1];
        float p_g = accS[u*4+2][b_ep] + xgv[du*4+2];
        float p_o = accS[u*4+3][b_ep] + xgv[du*4+3];
        float ig = sigm(p_i), fg = sigm(p_f), gg = tanhf(p_g), og = sigm(p_o);
        float c = fg*cst[du] + ig*gg; cst[du] = c;
        pk.h[du] = (__bf16)(og * tanhf(c));
      }
      __hip_atomic_store(
          (unsigned long long*)(hbw + (size_t)b_ep*KPAD + sl*NSU + u0),
          pk.u, __ATOMIC_RELAXED, __HIP_MEMORY_SCOPE_SYSTEM);
    }
    __syncthreads();
    if (tid == 0)
      __hip_atomic_store(&flags[(dir*S_CL + sl)*32], s+1, __ATOMIC_RELAXED, __HIP_MEMORY_SCOPE_SYSTEM);
    if (wave == 0 && lane < S_CL){
      int* fp = &flags[(dir*S_CL + lane)*32];
      while (__hip_atomic_load(fp, __ATOMIC_RELAXED, __HIP_MEMORY_SCOPE_SYSTEM) < s+1)
        __builtin_amdgcn_s_sleep(1);
    }
    __syncthreads();
  }
}

// ---------------- hist -> ginb [8192][608] (pads zeroed) ----------------
__global__ __launch_bounds__(320) void reshape_k(
    const __bf16* __restrict__ hist, __bf16* __restrict__ ginb)
{
  int row = blockIdx.x;                 // b*128 + n
  int b = row >> 7, n = row & 127;
  int t = threadIdx.x;
  if (t < 150){
    int u = 2*t;
    bf16x2 v = *(const bf16x2*)(hist + (size_t)(n+1)*HSLOT + (size_t)b*KPAD + u);
    *(bf16x2*)(ginb + (size_t)row*DMP + u) = v;
  } else if (t >= 160 && t < 310){
    int u = 2*(t-160);
    bf16x2 v = *(const bf16x2*)(hist + (size_t)DSTR + (size_t)(NN_-n)*HSLOT + (size_t)b*KPAD + u);
    *(bf16x2*)(ginb + (size_t)row*DMP + RHID + u) = v;
  } else if (t >= 312 && t < 316){
    int c = DM + 2*(t-312);
    bf16x2 z; z[0]=(__bf16)0.f; z[1]=(__bf16)0.f;
    *(bf16x2*)(ginb + (size_t)row*DMP + c) = z;
  }
}

// ---------------- masked mean over sequence -> aspect[B,DM] (bf16 in) ----------------
__global__ __launch_bounds__(640) void aspect_k(
    const __bf16* __restrict__ ginb, const float* __restrict__ mask, float* __restrict__ aspect)
{
  int b = blockIdx.x, t = threadIdx.x;
  __shared__ float msk[NN_];
  __shared__ float wn;
  if (t < NN_) msk[t] = mask[b*NN_+t];
  __syncthreads();
  if (t==0){ float s=0.f; for (int n=0;n<NN_;++n) s+=msk[n]; wn=s; }
  __syncthreads();
  if (t < DM){
    float s=0.f;
    for (int n=0;n<NN_;++n) s += (float)ginb[((size_t)(b*NN_+n))*DMP + t]*msk[n];
    aspect[b*DM+t] = s/wn;
  }
}

// ---------------- aw[b,h,e] = sum_d a[b,d] * weight_m[h,d,e] ----------------
__global__ __launch_bounds__(128) void aw_k(
    const float* __restrict__ a, const float* __restrict__ wm, float* __restrict__ aw)
{
  int b=blockIdx.x, h=blockIdx.y, e=threadIdx.x;
  if (e>=DKH) return;
  float s=0.f;
  for (int d=0; d<DKH; ++d) s += a[b*DKH+d]*wm[(h*DKH+d)*DKH+e];
  aw[(b*NH+h)*DKH+e]=s;
}

// ---------------- asc[b,h,m] = tanh(aw . k[b,h,m,:] + bias_m) (k from bf16 qkh) ----------------
__global__ __launch_bounds__(128) void asc_k(
    const float* __restrict__ aw, const __bf16* __restrict__ qkh,
    const float* __restrict__ bias_m, float* __restrict__ asc)
{
  int b=blockIdx.x, h=blockIdx.y, m=threadIdx.x;
  __shared__ __align__(16) float awl[DKH];
  if (m<DKH) awl[m]=aw[(b*NH+h)*DKH+m];
  __syncthreads();
  const __bf16* kr = qkh + (size_t)(b*NN_+m)*QKL + 768 + h*128;
  float s=0.f;
#pragma unroll
  for (int e=0;e<DKH;e+=2){
    bf16x2 kv = *(const bf16x2*)(kr + e);
    s += awl[e]*(float)kv[0] + awl[e+1]*(float)kv[1];
  }
  asc[(b*NH+h)*NN_+m] = tanhf(s + bias_m[0]);
}

// ---------------- MFMA attention: scores + mask + short + softmax -> adj bf16 ----------------
// One block per (b,h). 128x128 scores via mfma 16x16x32 (K=128, head-padded, pads zero).
// Softmax per row entirely in registers (shfl_xor across the 16 fn lanes).
__global__ __launch_bounds__(256) void attn2_k(
    const __bf16* __restrict__ qkh, const float* __restrict__ asc,
    const float* __restrict__ shortm, const int* __restrict__ tok,
    __bf16* __restrict__ adj)
{
  const int bh = blockIdx.x, b = bh / NH, h = bh - b*NH;
  const int tid = threadIdx.x, lane = tid & 63, wave = tid >> 6;
  const int fn = lane & 15, fq = lane >> 4;
  const __bf16* qb = qkh + (size_t)(b*NN_)*QKL + h*128;
  const __bf16* kb = qkh + (size_t)(b*NN_)*QKL + 768 + h*128;

  bf16x8 Af[2][4];
#pragma unroll
  for (int t=0;t<2;++t){
    int m0 = t*64 + wave*16;
#pragma unroll
    for (int kt=0;kt<4;++kt)
      Af[t][kt] = *(const bf16x8*)(qb + (size_t)(m0+fn)*QKL + kt*32 + fq*8);
  }

  f32x4 acc[2][8];
#pragma unroll
  for (int t=0;t<2;++t)
#pragma unroll
    for (int j=0;j<8;++j) acc[t][j] = (f32x4){0.f,0.f,0.f,0.f};

#pragma unroll
  for (int j=0;j<8;++j){
    bf16x8 Bf[4];
#pragma unroll
    for (int kt=0;kt<4;++kt)
      Bf[kt] = *(const bf16x8*)(kb + (size_t)(j*16+fn)*QKL + kt*32 + fq*8);
#pragma unroll
    for (int t=0;t<2;++t)
#pragma unroll
      for (int kt=0;kt<4;++kt)
        acc[t][j] = __builtin_amdgcn_mfma_f32_16x16x32_bf16(Af[t][kt], Bf[kt], acc[t][j], 0,0,0);
  }

  // per-column constants for this lane's 8 columns
  float ascv[8]; int msk[8];
#pragma unroll
  for (int j=0;j<8;++j){
    int c = j*16 + fn;
    ascv[j] = asc[(b*NH+h)*NN_ + c];
    msk [j] = tok[b*NN_ + c];
  }

#pragma unroll
  for (int t=0;t<2;++t){
#pragma unroll
    for (int r=0;r<4;++r){
      int m = t*64 + wave*16 + fq*4 + r;   // query row
      float sv[8];
#pragma unroll
      for (int j=0;j<8;++j){
        int c = j*16 + fn;
        float s = acc[t][j][r]*0.1f + ascv[j];
        if (msk[j]==0) s = -1e9f;
        s += shortm[((size_t)(b*NN_+m))*NN_ + c];
        sv[j]=s;
      }
      float mx = sv[0];
#pragma unroll
      for (int j=1;j<8;++j) mx = fmaxf(mx, sv[j]);
#pragma unroll
      for (int o=1;o<16;o<<=1) mx = fmaxf(mx, __shfl_xor(mx, o, 64));
      float sum = 0.f, ev[8];
#pragma unroll
      for (int j=0;j<8;++j){ ev[j]=__expf(sv[j]-mx); sum+=ev[j]; }
#pragma unroll
      for (int o=1;o<16;o<<=1) sum += __shfl_xor(sum, o, 64);
      float inv = 1.f/sum;
#pragma unroll
      for (int j=0;j<8;++j)
        adj[(((size_t)(b*NH+h))*NN_ + m)*NN_ + j*16 + fn] = (__bf16)(ev[j]*inv);
    }
  }
}

// ---------------- adjsum (bf16 in) -> bf16 adjs (/H) + fp32 whs ----------------
__global__ __launch_bounds__(256) void adjsum_k(
    const __bf16* __restrict__ adj, const float* __restrict__ swx,
    __bf16* __restrict__ adjs, float* __restrict__ whs)
{
  int idx = blockIdx.x*256 + threadIdx.x;
  int b = idx >> 14, rem = idx & 16383;
  float s=0.f, w=0.f;
  for (int h=0;h<NH;++h){
    float v = (float)adj[(((size_t)b*NH+h)<<14) + rem];
    s += v; w += v*swx[h];
  }
  adjs[idx] = (__bf16)(s*(1.f/NH));
  whs [idx] = w*(1.f/NH);
}

// ---------------- adjs2[b,i,j] = whs + (sg1[b,j]+sg2[b,i]+sbx)/H -> bf16 ----------------
// sgi: [8192][2] interleaved (col0 = g1.w1sum, col1 = g1.w2sum), from the sg wgemm
__global__ __launch_bounds__(256) void adjsum2_k(
    const float* __restrict__ whs, const float* __restrict__ sgi,
    const float* __restrict__ sbx, __bf16* __restrict__ adjs)
{
  int idx = blockIdx.x*256 + threadIdx.x;
  int b = idx >> 14, rem = idx & 16383;
  int i = rem >> 7, j = rem & 127;
  adjs[idx] = (__bf16)(whs[idx] + (sgi[(b*NN_+j)*2] + sgi[(b*NN_+i)*2+1] + sbx[0])*(1.f/NH));
}

// ---------------- pooled mean + logits ----------------
__global__ __launch_bounds__(320) void pooled_k(
    const float* __restrict__ hn, const float* __restrict__ mask,
    const float* __restrict__ Wc, const float* __restrict__ bc, float* __restrict__ out)
{
  int b=blockIdx.x, t=threadIdx.x;
  __shared__ float msk[NN_];
  __shared__ float pl[RHID];
  __shared__ float wn;
  if (t<NN_) msk[t]=mask[b*NN_+t];
  __syncthreads();
  if (t==0){ float s=0.f; for (int n=0;n<NN_;++n) s+=msk[n]; wn=s; }
  __syncthreads();
  if (t<RHID){
    float s=0.f;
    for (int n=0;n<NN_;++n) s += hn[((size_t)(b*NN_+n))*RHID+t]*msk[n];
    pl[t]=s/wn;
  }
  __syncthreads();
  if (t<3){
    float s=bc[t];
    for (int d=0;d<RHID;++d) s += pl[d]*Wc[t*RHID+d];
    out[b*3+t]=s;
  }
}

extern "C" void kernel_launch(void* const* d_in, const int* in_sizes, int n_in,
                              void* d_out, int out_size, void* d_ws, size_t ws_size,
                              hipStream_t stream)
{
  (void)in_sizes; (void)n_in; (void)out_size; (void)ws_size;
  const int*   tok      = (const int*)  d_in[0];
  const int*   pos_ids  = (const int*)  d_in[2];
  const int*   post_ids = (const int*)  d_in[5];
  const float* mask     = (const float*)d_in[6];
  const float* shortm   = (const float*)d_in[8];
  const float* emb_w    = (const float*)d_in[9];
  const float* pos_w    = (const float*)d_in[10];
  const float* post_w   = (const float*)d_in[11];
  const float* Wih_f    = (const float*)d_in[12];
  const float* Whh_f    = (const float*)d_in[13];
  const float* b_f      = (const float*)d_in[14];
  const float* Wih_b    = (const float*)d_in[15];
  const float* Whh_b    = (const float*)d_in[16];
  const float* b_b      = (const float*)d_in[17];
  const float* Wq       = (const float*)d_in[18];
  const float* bq       = (const float*)d_in[19];
  const float* Wk       = (const float*)d_in[20];
  const float* bk       = (const float*)d_in[21];
  const float* Wd       = (const float*)d_in[22];
  const float* bd       = (const float*)d_in[23];
  const float* weight_m = (const float*)d_in[24];
  const float* bias_m   = (const float*)d_in[25];
  const float* Ww       = (const float*)d_in[26];
  const float* bw       = (const float*)d_in[27];
  const float* Wx       = (const float*)d_in[28];
  const float* bx       = (const float*)d_in[29];
  const float* Wxx      = (const float*)d_in[30];
  const float* bxx      = (const float*)d_in[31];
  const float* Wc       = (const float*)d_in[32];
  const float* bc       = (const float*)d_in[33];

  float* ws  = (float*)d_ws;
  float* out = (float*)d_out;

  __bf16* ginb  = (__bf16*)(ws + OFF_GINB);
  float* aspect = ws + OFF_ASPECT;
  float* abuf   = ws + OFF_ABUF;
  float* awb    = ws + OFF_AWB;
  float* ascb   = ws + OFF_ASCB;
  float* w1sum  = ws + OFF_W1SUM;
  float* w2sum  = ws + OFF_W2SUM;
  float* swx    = ws + OFF_SWX;
  float* sbx    = ws + OFF_SBX;
  float* sgi    = ws + OFF_SGI;
  float* whs    = ws + OFF_WHS;
  __bf16* wqkp  = (__bf16*)(ws + OFF_WQKP);
  float* bqk    = ws + OFF_BQK;
  __bf16* wwp   = (__bf16*)(ws + OFF_WWP);
  __bf16* wxxp  = (__bf16*)(ws + OFF_WXXP);
  __bf16* wihpF = (__bf16*)(ws + OFF_WIHPF);
  __bf16* wihpB = (__bf16*)(ws + OFF_WIHPB);
  float* bpF    = ws + OFF_BPF;
  float* bpB    = ws + OFF_BPB;
  __bf16* wtb   = (__bf16*)(ws + OFF_WTB);
  __bf16* embs  = (__bf16*)(ws + OFF_EMBS);
  __bf16* xgf   = (__bf16*)(ws + OFF_XGF);
  __bf16* xgb   = (__bf16*)(ws + OFF_XGB);
  __bf16* hist  = (__bf16*)(ws + OFF_HIST);
  int*   flags  = (int*)(ws + OFF_FLAGS);
  __bf16* qkh   = (__bf16*)(ws + OFF_QKH);
  __bf16* adjb  = (__bf16*)(ws + OFF_ADJ);
  __bf16* adjs  = (__bf16*)(ws + OFF_ADJS);
  __bf16* gint  = (__bf16*)(ws + OFF_GINT);
  __bf16* w12   = (__bf16*)(ws + OFF_W12);
  __bf16* axb   = (__bf16*)(ws + OFF_AXB);
  __bf16* g1b   = (__bf16*)(ws + OFF_G1B);
  __bf16* g1t   = (__bf16*)(ws + OFF_G1T);
  __bf16* ax2b  = (__bf16*)(ws + OFF_AX2B);
  __bf16* g2b   = (__bf16*)(ws + OFF_G2B);
  float* hnb    = ws + OFF_HNB;

  // 1. embeddings, constants, weight packing, init
  embed_k<<<dim3(BB*NN_),384,0,stream>>>(tok,pos_ids,post_ids,emb_w,pos_w,post_w,embs);
  consts_k<<<1,640,0,stream>>>(Wx,bx,w1sum,w2sum,swx,sbx,w12);
  wihp_k<<<dim3((G4*INP+G4+255)/256),256,0,stream>>>(Wih_f,b_f,wihpF,bpF);
  wihp_k<<<dim3((G4*INP+G4+255)/256),256,0,stream>>>(Wih_b,b_b,wihpB,bpB);
  wqkhp_k<<<dim3((QKL*DMP+QKL+255)/256),256,0,stream>>>(Wq,bq,Wk,bk,wqkp,bqk);
  wpk_k<<<dim3((DM*DMP+255)/256),256,0,stream>>>(Ww,wwp,DM,DM,DMP);
  wpk_k<<<dim3((RHID*DMP+255)/256),256,0,stream>>>(Wxx,wxxp,RHID,DM,DMP);
  whhp_k<<<dim3((G4*KPAD+255)/256),256,0,stream>>>(Whh_f, wtb);
  whhp_k<<<dim3((G4*KPAD+255)/256),256,0,stream>>>(Whh_b, wtb + (size_t)G4*KPAD);
  init_k<<<dim3((22528+255)/256),256,0,stream>>>(ws);
  // 2. LSTM input projections (bf16 MFMA, LDS-free), bf16 out
  wgemm_k<12,0,1><<<dim3(128,4,1),256,0,stream>>>(embs,wihpF,bpF,xgf, G4,G4,G4, 0,0,0);
  wgemm_k<12,0,1><<<dim3(128,4,1),256,0,stream>>>(embs,wihpB,bpB,xgb, G4,G4,G4, 0,0,0);
  // 3. recurrence (fence-free system-coherent cluster sync)
  lstm_mfma_k<<<dim3(2*S_CL),256,0,stream>>>(xgf,xgb,wtb,hist,flags);
  reshape_k<<<dim3(BB*NN_),320,0,stream>>>(hist,ginb);
  // 4. fused Q||K projection (bf16 head-padded), aspect path
  wgemm_k<19,0,1><<<dim3(128,4,1),256,0,stream>>>(ginb,wqkp,bqk,qkh, QKL,QKL,QKL, 0,0,0);
  aspect_k<<<BB,640,0,stream>>>(ginb,mask,aspect);
  gemm_k<false,0><<<dim3(1,1,1),256,0,stream>>>(aspect,Wd,bd,abuf, BB,DKH,DM, 0,0,0);
  aw_k <<<dim3(BB,NH),128,0,stream>>>(abuf,weight_m,awb);
  asc_k<<<dim3(BB,NH),128,0,stream>>>(awb,qkh,bias_m,ascb);
  // 5. MFMA scores + softmax -> adj bf16
  attn2_k<<<dim3(BB*NH),256,0,stream>>>(qkh,ascb,shortm,tok,adjb);
  // 6. GCN layer 1 (bf16 MFMA)
  adjsum_k<<<4096,256,0,stream>>>(adjb,swx,adjs,whs);
  tr_k<<<dim3(10,2,BB),256,0,stream>>>(ginb,gint);
  wgemm_k<4,0,1><<<dim3(2,4,BB),256,0,stream>>>(adjs,gint,nullptr,axb, DM,DMP,DMP, 16384,(long long)DMP*NN_,(long long)NN_*DMP);
  wgemm_k<19,1,1><<<dim3(128,4,1),256,0,stream>>>(axb,wwp,bw,g1b, DM,DMP,DMP, 0,0,0);
  // 7. layer-2 adjacency collapsed (sg via coalesced MFMA GEMV, N=2)
  wgemm_k<19,0,0><<<dim3(128,1,1),256,0,stream>>>(g1b,w12,nullptr,sgi, 2,2,2, 0,0,0);
  adjsum2_k<<<4096,256,0,stream>>>(whs,sgi,sbx,adjs);
  // 8. GCN layer 2
  tr_k<<<dim3(10,2,BB),256,0,stream>>>(g1b,g1t);
  wgemm_k<4,0,1><<<dim3(2,4,BB),256,0,stream>>>(adjs,g1t,nullptr,ax2b, DM,DMP,DMP, 16384,(long long)DMP*NN_,(long long)NN_*DMP);
  wgemm_k<19,1,1><<<dim3(128,4,1),256,0,stream>>>(ax2b,wwp,bw,g2b, DM,DMP,DMP, 0,0,0);
  // 9. head
  wgemm_k<19,2,0><<<dim3(128,4,1),256,0,stream>>>(g2b,wxxp,bxx,hnb, RHID,RHID,RHID, 0,0,0);
  pooled_k<<<BB,320,0,stream>>>(hnb,mask,Wc,bc,out);
}

// Round 9
// 1283.632 us; speedup vs baseline: 2.0765x; 1.1616x over previous
//
#include <hip/hip_runtime.h>
#include <math.h>

// ---- problem constants ----
#define BB    64
#define NN_   128
#define NH    6
#define DM    600     // d_model
#define RHID  300     // rnn hidden
#define DKH   100     // per-head dim
#define INDIM 360
#define G4    1200    // 4*RHID
#define WXROW 1206    // NH + 2*DM
#define DMP   608     // DM padded to mult of 32
#define INP   384     // INDIM padded
#define QKL   1536    // 2 * NH * 128 (head-padded q||k row length)

// ---- LSTM cluster config ----
#define S_CL  25
#define NSU   12
#define NSR   48
#define KPAD  320
#define HSLOT (BB*KPAD)          // 20480 bf16 per history slot
#define DSTR  (129*HSLOT)        // per-dir history stride (bf16)

// ---- workspace layout (float offsets). Peak ~ 26.35M fl = 105.4 MB ----
#define OFF_GINB   0ull                 // bf16 [8192][608] = 2,490,368 fl
#define OFF_ASPECT 2490368ull
#define OFF_ASCB   2573568ull
#define OFF_W1SUM  2622720ull
#define OFF_W2SUM  2623360ull
#define OFF_SWX    2624000ull
#define OFF_SBX    2624016ull
#define OFF_SGI    2624032ull           // fp32 [8192][2] interleaved (sg1,sg2)
#define OFF_WHS    2640416ull           // fp32 [64][128][128]
#define OFF_WQKP   3688992ull           // bf16 [1536][608] = 466,944 fl
#define OFF_BQK    4155936ull           // fp32 1536
#define OFF_WWP    4157472ull           // bf16 [600][608] = 182,400 fl
#define OFF_WXXP   4339872ull           // bf16 [300][608] = 91,200 fl
#define OFF_WIHPF  4431072ull           // bf16 [1200][384] = 230,400 fl
#define OFF_WIHPB  4661472ull
#define OFF_BPF    4891872ull
#define OFF_BPB    4893072ull
#define OFF_WTB    4894272ull           // bf16 [2][1200][320] = 384,000 fl
#define OFF_EMBS   5278272ull           // bf16 [8192][384] = 1,572,864 fl
#define ARENA      6851136ull
#define OFF_XGF    (ARENA)                      // bf16 [8192][1200] = 4,915,200 fl
#define OFF_XGB    (ARENA + 4915200ull)         // bf16, 4,915,200 fl
#define OFF_HIST   (ARENA + 9830400ull)         // bf16 [2][129][64][320] = 2,641,920 fl
#define OFF_FLAGS  (ARENA + 12472320ull)        // flags (50, 128B apart)
// post-lstm reuse (xg dead after lstm; hist/flags dead after reshape):
#define OFF_QKH    (ARENA)                      // bf16 [8192][1536] = 6,291,456 fl (over xg)
#define OFF_ADJ    (ARENA + 6291456ull)         // bf16 [64][6][128][128] = 3,145,728 fl
#define OFF_ADJS   (ARENA + 16121856ull)        // bf16 [64][128][128] = 524,288 fl
#define OFF_GINT   (ARENA + 16646144ull)        // bf16 [64][608][128] = 2,490,368 fl
#define OFF_W12    (ARENA + 19136512ull)        // bf16 [2][608] = 608 fl
#define OFF_WDM    (ARENA + 19137152ull)        // fp32 [6][600][100] = 360,000 fl
#define OFF_BDM    (ARENA + 19497152ull)        // fp32 600
#define OFF_AXB    (ARENA)                      // bf16 (over qkh, dead after attn2/ascf)
#define OFF_G1B    (ARENA + 2490368ull)
#define OFF_G1T    (OFF_GINT)
#define OFF_AX2B   (ARENA + 4980736ull)
#define OFF_G2B    (ARENA + 7471104ull)         // over adj (dead after adjsum)
#define OFF_HNB    (ARENA + 9961472ull)         // fp32 [8192][300] (over hist, dead)

typedef __bf16 bf16x8 __attribute__((ext_vector_type(8)));
typedef __bf16 bf16x4 __attribute__((ext_vector_type(4)));
typedef __bf16 bf16x2 __attribute__((ext_vector_type(2)));
typedef float  f32x4  __attribute__((ext_vector_type(4)));

__device__ __forceinline__ float sigm(float x){ return 1.f/(1.f+__expf(-x)); }
__device__ __forceinline__ float selu_f(float x){
  const float sc=1.0507009873554805f, al=1.6732632423543772f;
  return x>0.f ? sc*x : sc*al*(__expf(x)-1.f);
}
__device__ __forceinline__ bf16x8 bzero8(){
  bf16x8 z;
#pragma unroll
  for (int j=0;j<8;++j) z[j]=(__bf16)0.f;
  return z;
}

// ---------------- embedding concat -> bf16 [8192][384], pads written zero ----------------
__global__ __launch_bounds__(384) void embed_k(
    const int* __restrict__ tok, const int* __restrict__ pos_ids, const int* __restrict__ post_ids,
    const float* __restrict__ emb_w, const float* __restrict__ pos_w, const float* __restrict__ post_w,
    __bf16* __restrict__ embs)
{
  int bn = blockIdx.x, t = threadIdx.x;
  float v = 0.f;
  if      (t < 300) v = emb_w [(size_t)tok     [bn]*300 + t];
  else if (t < 330) v = pos_w [(size_t)pos_ids [bn]*30  + (t-300)];
  else if (t < 360) v = post_w[(size_t)post_ids[bn]*30  + (t-330)];
  embs[(size_t)bn*INP + t] = (__bf16)v;
}

// ---------------- Wx folded constants (+ bf16 w12 for the sg GEMV) ----------------
__global__ __launch_bounds__(640) void consts_k(
    const float* __restrict__ Wx, const float* __restrict__ bx,
    float* __restrict__ w1sum, float* __restrict__ w2sum,
    float* __restrict__ swx, float* __restrict__ sbx, __bf16* __restrict__ w12)
{
  int t = threadIdx.x;
  if (t < DM){
    float s1=0.f, s2=0.f;
    for (int k=0;k<NH;++k){ s1 += Wx[k*WXROW + NH + t]; s2 += Wx[k*WXROW + NH + DM + t]; }
    w1sum[t]=s1; w2sum[t]=s2;
    w12[t]=(__bf16)s1; w12[DMP+t]=(__bf16)s2;
  } else if (t < DM+NH){
    int h=t-DM; float s=0.f;
    for (int k=0;k<NH;++k) s += Wx[k*WXROW + h];
    swx[h]=s;
  } else if (t == DM+NH){
    float s=0.f; for (int k=0;k<NH;++k) s += bx[k];
    sbx[0]=s;
  }
  if (t >= DM && t < DMP){ w12[t]=(__bf16)0.f; w12[DMP+t]=(__bf16)0.f; }
}

// ---------------- WdM[h][D][e] = sum_d Wd[d][D]*wm[h][d][e]; bdM[h][e] = bd·wm[h][:,e] ----------------
__global__ __launch_bounds__(128) void wdm_k(
    const float* __restrict__ Wd, const float* __restrict__ bd, const float* __restrict__ wm,
    float* __restrict__ WdM, float* __restrict__ bdM)
{
  int D = blockIdx.x, h = blockIdx.y, e = threadIdx.x;
  if (e >= DKH) return;
  float s = 0.f;
  for (int d=0; d<DKH; ++d)
    s += Wd[d*DM + D] * wm[(h*DKH+d)*DKH + e];
  WdM[((size_t)h*DM + D)*DKH + e] = s;
  if (D == 0){
    float sb = 0.f;
    for (int d=0; d<DKH; ++d) sb += bd[d]*wm[(h*DKH+d)*DKH + e];
    bdM[h*DKH + e] = sb;
  }
}

// ---------------- pack Wih both dirs (gate-interleaved rows p=4u+g) -> bf16 [1200][384] ----------------
__global__ __launch_bounds__(256) void wihp_k(
    const float* __restrict__ WihF, const float* __restrict__ bF,
    const float* __restrict__ WihB, const float* __restrict__ bB,
    __bf16* __restrict__ wpF, float* __restrict__ bpF,
    __bf16* __restrict__ wpB, float* __restrict__ bpB)
{
  const float* Wih = blockIdx.y ? WihB : WihF;
  const float* b   = blockIdx.y ? bB   : bF;
  __bf16* wp       = blockIdx.y ? wpB  : wpF;
  float* bp        = blockIdx.y ? bpB  : bpF;
  int idx = blockIdx.x*256 + threadIdx.x;
  if (idx < G4*INP){
    int p = idx / INP, k = idx - p*INP;
    int srow = (p&3)*RHID + (p>>2);
    wp[idx] = (k<INDIM) ? (__bf16)Wih[(size_t)srow*INDIM + k] : (__bf16)0.f;
  } else if (idx < G4*INP + G4){
    int p = idx - G4*INP;
    bp[p] = b[(p&3)*RHID + (p>>2)];
  }
}

// ---------------- pack Wq||Wk head-padded -> bf16 [1536][608], bias [1536] ----------------
__global__ __launch_bounds__(256) void wqkhp_k(
    const float* __restrict__ Wq, const float* __restrict__ bq,
    const float* __restrict__ Wk, const float* __restrict__ bk,
    __bf16* __restrict__ wp, float* __restrict__ bp)
{
  int idx = blockIdx.x*256 + threadIdx.x;
  if (idx < QKL*DMP){
    int n = idx / DMP, k = idx - n*DMP;
    int nl = (n < 768) ? n : n - 768;
    int h = nl >> 7, e = nl & 127;
    float v = 0.f;
    if (k < DM && e < DKH)
      v = (n < 768) ? Wq[(size_t)(h*DKH+e)*DM + k] : Wk[(size_t)(h*DKH+e)*DM + k];
    wp[idx] = (__bf16)v;
  } else if (idx < QKL*DMP + QKL){
    int n = idx - QKL*DMP;
    int nl = (n < 768) ? n : n - 768;
    int h = nl >> 7, e = nl & 127;
    bp[n] = (e < DKH) ? ((n < 768) ? bq[h*DKH+e] : bk[h*DKH+e]) : 0.f;
  }
}

// ---------------- generic weight pack fp32[n][ksrc] -> bf16[n][kp] (k-pads zero) ----------------
__global__ __launch_bounds__(256) void wpk_k(
    const float* __restrict__ W, __bf16* __restrict__ wp, int nrows, int ksrc, int kp)
{
  int idx = blockIdx.x*256 + threadIdx.x;
  if (idx >= nrows*kp) return;
  int n = idx / kp, k = idx - n*kp;
  wp[idx] = (k < ksrc) ? (__bf16)W[(size_t)n*ksrc + k] : (__bf16)0.f;
}

// ---------------- pack Whh both dirs -> bf16 [p=4u+g][KPAD] ----------------
__global__ __launch_bounds__(256) void whhp_k(
    const float* __restrict__ WhhF, const float* __restrict__ WhhB, __bf16* __restrict__ outW)
{
  const float* Whh = blockIdx.y ? WhhB : WhhF;
  __bf16* wp = outW + (size_t)blockIdx.y * G4 * KPAD;
  int idx = blockIdx.x*256 + threadIdx.x;
  if (idx >= G4*KPAD) return;
  int p = idx / KPAD, k = idx - p*KPAD;
  wp[idx] = (k < RHID) ? (__bf16)Whh[((size_t)((p&3)*RHID + (p>>2)))*RHID + k] : (__bf16)0.f;
}

// ---------------- zero hist slot0 (both dirs) + flags ----------------
__global__ __launch_bounds__(256) void init_k(float* __restrict__ ws)
{
  int idx = blockIdx.x*256 + threadIdx.x;
  if (idx < 10240)       ws[OFF_HIST + idx] = 0.f;                       // dir0 slot0
  else if (idx < 20480)  ws[OFF_HIST + 1320960ull + (idx-10240)] = 0.f;  // dir1 slot0
  else if (idx < 22528)  ws[OFF_FLAGS + (idx-20480)] = 0.f;              // flags
}

// ---------------- LDS-free bf16 MFMA GEMM: C = act(A @ B^T + bias) ----------------
// Dual accumulator chains (even/odd kt) double per-wave MFMA ILP.
template<int KT, int ACT, int OBF>
__global__ __launch_bounds__(256) void wgemm_k(
    const __bf16* __restrict__ A, const __bf16* __restrict__ B,
    const float* __restrict__ bias, void* __restrict__ Cout,
    int Nn, int Npad, int ldc,
    long long sA, long long sB, long long sC)
{
  const int tid = threadIdx.x, lane = tid & 63, wave = tid >> 6;
  const int fn = lane & 15, fq = lane >> 4;
  const int K = KT*32;
  const __bf16* Ab = A + (size_t)blockIdx.z * (size_t)sA;
  const __bf16* Bb = B + (size_t)blockIdx.z * (size_t)sB;
  float*  Cf = (float*) Cout + (size_t)blockIdx.z * (size_t)sC;
  __bf16* Ch = (__bf16*)Cout + (size_t)blockIdx.z * (size_t)sC;

  const int m0 = (blockIdx.x*4 + wave)*16;

  bf16x8 Af[KT];
#pragma unroll
  for (int kt=0; kt<KT; ++kt)
    Af[kt] = *(const bf16x8*)(Ab + (size_t)(m0 + fn)*K + kt*32 + fq*8);

  for (int n0 = blockIdx.y*16; n0 < Nn; n0 += 16*gridDim.y){
    const int gn = n0 + fn;
    const int gnc = (gn < Nn) ? gn : 0;
    f32x4 acc0 = {0.f,0.f,0.f,0.f};
    f32x4 acc1 = {0.f,0.f,0.f,0.f};
#pragma unroll
    for (int kt=0; kt<KT; ++kt){
      bf16x8 Bf = *(const bf16x8*)(Bb + (size_t)gnc*K + kt*32 + fq*8);
      if (gn >= Nn) Bf = bzero8();
      if (kt & 1) acc1 = __builtin_amdgcn_mfma_f32_16x16x32_bf16(Af[kt], Bf, acc1, 0, 0, 0);
      else        acc0 = __builtin_amdgcn_mfma_f32_16x16x32_bf16(Af[kt], Bf, acc0, 0, 0, 0);
    }
    float bv = (bias && gn < Nn) ? bias[gn] : 0.f;
#pragma unroll
    for (int r=0; r<4; ++r){
      int gm = m0 + fq*4 + r;
      float v = acc0[r] + acc1[r] + bv;
      if (ACT==1) v = selu_f(v);
      else if (ACT==2) v = fmaxf(v, 0.f);
      if (gn < Nn){
        if (OBF) Ch[(size_t)gm*ldc + gn] = (__bf16)v;
        else     Cf[(size_t)gm*ldc + gn] = v;
      } else if (gn < Npad){
        if (OBF) Ch[(size_t)gm*ldc + gn] = (__bf16)0.f;
        else     Cf[(size_t)gm*ldc + gn] = 0.f;
      }
    }
  }
}

// ---------------- bf16 per-batch transpose [64][128][608] -> [64][608][128] ----------------
__global__ __launch_bounds__(256) void tr_k(
    const __bf16* __restrict__ in, __bf16* __restrict__ out)
{
  const int b = blockIdx.z, m0 = blockIdx.y*64, d0 = blockIdx.x*64;
  const int tid = threadIdx.x;
  __shared__ __align__(16) __bf16 T[64][72];
  const __bf16* ib = in + (size_t)b*NN_*DMP;
  __bf16* ob = out + (size_t)b*DMP*NN_;
#pragma unroll
  for (int r=0;r<2;++r){
    int idx = tid + 256*r;
    int mi = idx>>3, ch = idx&7;
    int d = d0 + ch*8;
    bf16x8 v = bzero8();
    if (d < DMP) v = *(const bf16x8*)(ib + (size_t)(m0+mi)*DMP + d);
    *(bf16x8*)&T[mi][ch*8] = v;
  }
  __syncthreads();
#pragma unroll
  for (int r=0;r<2;++r){
    int idx = tid + 256*r;
    int di = idx>>3, mch = idx&7;
    int d = d0 + di;
    if (d >= DMP) continue;
    bf16x8 v;
#pragma unroll
    for (int j=0;j<8;++j) v[j] = T[mch*8+j][di];
    *(bf16x8*)(ob + (size_t)d*NN_ + m0 + mch*8) = v;
  }
}

// ---------------- cooperative-cluster MFMA LSTM — fence-free system-coherent sync ----------------
__global__ __launch_bounds__(256, 1) void lstm_mfma_k(
    const __bf16* __restrict__ xgf, const __bf16* __restrict__ xgb,
    const __bf16* __restrict__ wtb,
    __bf16* hist, int* flags)
{
  const int blk = blockIdx.x;
  const int dir = blk / S_CL, sl = blk - dir*S_CL;
  const int tid = threadIdx.x, lane = tid & 63, wave = tid >> 6;
  const int p0 = sl * NSR;
  const __bf16* xg = dir ? xgb : xgf;
  const __bf16* W = wtb + (size_t)dir * G4 * KPAD;
  __bf16* hb = hist + (size_t)dir * DSTR;

  __shared__ __align__(16) float accS[NSR][68];

  const int fn = lane & 15;
  const int fk = (lane >> 4) * 8;
  const int m0 = wave * 16;

  bf16x8 Bf[3][10];
#pragma unroll
  for (int nt = 0; nt < 3; ++nt)
#pragma unroll
    for (int kt = 0; kt < 10; ++kt)
      Bf[nt][kt] = *(const bf16x8*)(W + (size_t)(p0 + nt*16 + fn)*KPAD + kt*32 + fk);

  const int b_ep = tid / 3;
  const int q_ep = tid - b_ep*3;
  const int u0 = q_ep*4;
  const bool ep = (tid < 192);
  float cst[4] = {0.f,0.f,0.f,0.f};
  const __bf16* xp = xg + ((size_t)b_ep*NN_)*G4 + p0 + u0*4;

  for (int s = 0; s < NN_; ++s){
    const int n_t = dir ? (NN_-1-s) : s;
    const __bf16* hbr = hb + (size_t)s*HSLOT;
    __bf16*       hbw = hb + (size_t)(s+1)*HSLOT;

    bf16x8 xv0, xv1;
    if (ep){
      xv0 = *(const bf16x8*)(xp + (size_t)n_t*G4);
      xv1 = *(const bf16x8*)(xp + (size_t)n_t*G4 + 8);
    }

    bf16x8 Af[10];
#pragma unroll
    for (int kt = 0; kt < 10; ++kt){
      const unsigned long long* hp =
          (const unsigned long long*)(hbr + (size_t)(m0 + fn)*KPAD + kt*32 + fk);
      union { unsigned long long u[2]; bf16x8 v; } cv;
      cv.u[0] = __hip_atomic_load(hp,   __ATOMIC_RELAXED, __HIP_MEMORY_SCOPE_SYSTEM);
      cv.u[1] = __hip_atomic_load(hp+1, __ATOMIC_RELAXED, __HIP_MEMORY_SCOPE_SYSTEM);
      Af[kt] = cv.v;
    }

    f32x4 acc[3] = { {0.f,0.f,0.f,0.f}, {0.f,0.f,0.f,0.f}, {0.f,0.f,0.f,0.f} };
#pragma unroll
    for (int kt = 0; kt < 10; ++kt)
#pragma unroll
      for (int nt = 0; nt < 3; ++nt)
        acc[nt] = __builtin_amdgcn_mfma_f32_16x16x32_bf16(Af[kt], Bf[nt][kt], acc[nt], 0, 0, 0);

#pragma unroll
    for (int nt = 0; nt < 3; ++nt)
      *(f32x4*)&accS[nt*16 + fn][m0 + (lane>>4)*4] = acc[nt];
    __syncthreads();

    if (ep){
      union { unsigned long long u; __bf16 h[4]; } pk;
      float xgv[16];
#pragma unroll
      for (int j=0;j<8;++j){ xgv[j]=(float)xv0[j]; xgv[8+j]=(float)xv1[j]; }
#pragma unroll
      for (int du = 0; du < 4; ++du){
        int u = u0 + du;
        float p_i = accS[u*4+0][b_ep] + xgv[du*4+0];
        float p_f = accS[u*4+1][b_ep] + xgv[du*4+1];
        float p_g = accS[u*4+2][b_ep] + xgv[du*4+2];
        float p_o = accS[u*4+3][b_ep] + xgv[du*4+3];
        float ig = sigm(p_i), fg = sigm(p_f), gg = tanhf(p_g), og = sigm(p_o);
        float c = fg*cst[du] + ig*gg; cst[du] = c;
        pk.h[du] = (__bf16)(og * tanhf(c));
      }
      __hip_atomic_store(
          (unsigned long long*)(hbw + (size_t)b_ep*KPAD + sl*NSU + u0),
          pk.u, __ATOMIC_RELAXED, __HIP_MEMORY_SCOPE_SYSTEM);
    }
    __syncthreads();
    if (tid == 0)
      __hip_atomic_store(&flags[(dir*S_CL + sl)*32], s+1, __ATOMIC_RELAXED, __HIP_MEMORY_SCOPE_SYSTEM);
    if (wave == 0 && lane < S_CL){
      int* fp = &flags[(dir*S_CL + lane)*32];
      while (__hip_atomic_load(fp, __ATOMIC_RELAXED, __HIP_MEMORY_SCOPE_SYSTEM) < s+1) { }
    }
    __syncthreads();
  }
}

// ---------------- hist -> ginb [8192][608] (pads zeroed) ----------------
__global__ __launch_bounds__(320) void reshape_k(
    const __bf16* __restrict__ hist, __bf16* __restrict__ ginb)
{
  int row = blockIdx.x;                 // b*128 + n
  int b = row >> 7, n = row & 127;
  int t = threadIdx.x;
  if (t < 150){
    int u = 2*t;
    bf16x2 v = *(const bf16x2*)(hist + (size_t)(n+1)*HSLOT + (size_t)b*KPAD + u);
    *(bf16x2*)(ginb + (size_t)row*DMP + u) = v;
  } else if (t >= 160 && t < 310){
    int u = 2*(t-160);
    bf16x2 v = *(const bf16x2*)(hist + (size_t)DSTR + (size_t)(NN_-n)*HSLOT + (size_t)b*KPAD + u);
    *(bf16x2*)(ginb + (size_t)row*DMP + RHID + u) = v;
  } else if (t >= 312 && t < 316){
    int c = DM + 2*(t-312);
    bf16x2 z; z[0]=(__bf16)0.f; z[1]=(__bf16)0.f;
    *(bf16x2*)(ginb + (size_t)row*DMP + c) = z;
  }
}

// ---------------- masked mean over sequence -> aspect[B,DM] (bf16 in, 2 col-halves) ----------------
__global__ __launch_bounds__(320) void aspect_k(
    const __bf16* __restrict__ ginb, const float* __restrict__ mask, float* __restrict__ aspect)
{
  int b = blockIdx.x, t = threadIdx.x;
  int col = blockIdx.y*300 + t;
  __shared__ float msk[NN_];
  __shared__ float wn;
  if (t < NN_) msk[t] = mask[b*NN_+t];
  __syncthreads();
  if (t==0){ float s=0.f; for (int n=0;n<NN_;++n) s+=msk[n]; wn=s; }
  __syncthreads();
  if (t < 300){
    float s=0.f;
    for (int n=0;n<NN_;++n) s += (float)ginb[((size_t)(b*NN_+n))*DMP + col]*msk[n];
    aspect[b*DM+col] = s/wn;
  }
}

// ---------------- fused: aw = aspect@WdM + bdM ; asc = tanh(aw·k + bias_m) ----------------
__global__ __launch_bounds__(128) void ascf_k(
    const float* __restrict__ aspect, const float* __restrict__ WdM, const float* __restrict__ bdM,
    const __bf16* __restrict__ qkh, const float* __restrict__ bias_m, float* __restrict__ asc)
{
  int b = blockIdx.x, h = blockIdx.y, t = threadIdx.x;
  __shared__ __align__(16) float asp[DM];
  __shared__ __align__(16) float awl[DKH];
  for (int i = t; i < DM; i += 128) asp[i] = aspect[b*DM + i];
  __syncthreads();
  if (t < DKH){
    const float* wrow = WdM + (size_t)h*DM*DKH + t;
    float s0=0.f,s1=0.f,s2=0.f,s3=0.f;
    for (int D=0; D<DM; D+=4){
      s0 += asp[D+0]*wrow[(size_t)(D+0)*DKH];
      s1 += asp[D+1]*wrow[(size_t)(D+1)*DKH];
      s2 += asp[D+2]*wrow[(size_t)(D+2)*DKH];
      s3 += asp[D+3]*wrow[(size_t)(D+3)*DKH];
    }
    awl[t] = s0+s1+s2+s3 + bdM[h*DKH + t];
  }
  __syncthreads();
  const __bf16* kr = qkh + (size_t)(b*NN_ + t)*QKL + 768 + h*128;
  float s=0.f;
#pragma unroll
  for (int e=0;e<DKH;e+=2){
    bf16x2 kv = *(const bf16x2*)(kr + e);
    s += awl[e]*(float)kv[0] + awl[e+1]*(float)kv[1];
  }
  asc[(b*NH+h)*NN_ + t] = tanhf(s + bias_m[0]);
}

// ---------------- MFMA attention: scores + mask + short + softmax -> adj bf16 ----------------
__global__ __launch_bounds__(256) void attn2_k(
    const __bf16* __restrict__ qkh, const float* __restrict__ asc,
    const float* __restrict__ shortm, const int* __restrict__ tok,
    __bf16* __restrict__ adj)
{
  const int bh = blockIdx.x, b = bh / NH, h = bh - b*NH;
  const int tid = threadIdx.x, lane = tid & 63, wave = tid >> 6;
  const int fn = lane & 15, fq = lane >> 4;
  const __bf16* qb = qkh + (size_t)(b*NN_)*QKL + h*128;
  const __bf16* kb = qkh + (size_t)(b*NN_)*QKL + 768 + h*128;

  bf16x8 Af[2][4];
#pragma unroll
  for (int t=0;t<2;++t){
    int m0 = t*64 + wave*16;
#pragma unroll
    for (int kt=0;kt<4;++kt)
      Af[t][kt] = *(const bf16x8*)(qb + (size_t)(m0+fn)*QKL + kt*32 + fq*8);
  }

  f32x4 acc[2][8];
#pragma unroll
  for (int t=0;t<2;++t)
#pragma unroll
    for (int j=0;j<8;++j) acc[t][j] = (f32x4){0.f,0.f,0.f,0.f};

#pragma unroll
  for (int j=0;j<8;++j){
    bf16x8 Bf[4];
#pragma unroll
    for (int kt=0;kt<4;++kt)
      Bf[kt] = *(const bf16x8*)(kb + (size_t)(j*16+fn)*QKL + kt*32 + fq*8);
#pragma unroll
    for (int t=0;t<2;++t)
#pragma unroll
      for (int kt=0;kt<4;++kt)
        acc[t][j] = __builtin_amdgcn_mfma_f32_16x16x32_bf16(Af[t][kt], Bf[kt], acc[t][j], 0,0,0);
  }

  float ascv[8]; int msk[8];
#pragma unroll
  for (int j=0;j<8;++j){
    int c = j*16 + fn;
    ascv[j] = asc[(b*NH+h)*NN_ + c];
    msk [j] = tok[b*NN_ + c];
  }

#pragma unroll
  for (int t=0;t<2;++t){
#pragma unroll
    for (int r=0;r<4;++r){
      int m = t*64 + wave*16 + fq*4 + r;
      float sv[8];
#pragma unroll
      for (int j=0;j<8;++j){
        int c = j*16 + fn;
        float s = acc[t][j][r]*0.1f + ascv[j];
        if (msk[j]==0) s = -1e9f;
        s += shortm[((size_t)(b*NN_+m))*NN_ + c];
        sv[j]=s;
      }
      float mx = sv[0];
#pragma unroll
      for (int j=1;j<8;++j) mx = fmaxf(mx, sv[j]);
#pragma unroll
      for (int o=1;o<16;o<<=1) mx = fmaxf(mx, __shfl_xor(mx, o, 64));
      float sum = 0.f, ev[8];
#pragma unroll
      for (int j=0;j<8;++j){ ev[j]=__expf(sv[j]-mx); sum+=ev[j]; }
#pragma unroll
      for (int o=1;o<16;o<<=1) sum += __shfl_xor(sum, o, 64);
      float inv = 1.f/sum;
#pragma unroll
      for (int j=0;j<8;++j)
        adj[(((size_t)(b*NH+h))*NN_ + m)*NN_ + j*16 + fn] = (__bf16)(ev[j]*inv);
    }
  }
}

// ---------------- adjsum (bf16 in) -> bf16 adjs (/H) + fp32 whs ----------------
__global__ __launch_bounds__(256) void adjsum_k(
    const __bf16* __restrict__ adj, const float* __restrict__ swx,
    __bf16* __restrict__ adjs, float* __restrict__ whs)
{
  int idx = blockIdx.x*256 + threadIdx.x;
  int b = idx >> 14, rem = idx & 16383;
  float s=0.f, w=0.f;
  for (int h=0;h<NH;++h){
    float v = (float)adj[(((size_t)b*NH+h)<<14) + rem];
    s += v; w += v*swx[h];
  }
  adjs[idx] = (__bf16)(s*(1.f/NH));
  whs [idx] = w*(1.f/NH);
}

// ---------------- adjs2[b,i,j] = whs + (sg1[b,j]+sg2[b,i]+sbx)/H -> bf16 ----------------
__global__ __launch_bounds__(256) void adjsum2_k(
    const float* __restrict__ whs, const float* __restrict__ sgi,
    const float* __restrict__ sbx, __bf16* __restrict__ adjs)
{
  int idx = blockIdx.x*256 + threadIdx.x;
  int b = idx >> 14, rem = idx & 16383;
  int i = rem >> 7, j = rem & 127;
  adjs[idx] = (__bf16)(whs[idx] + (sgi[(b*NN_+j)*2] + sgi[(b*NN_+i)*2+1] + sbx[0])*(1.f/NH));
}

// ---------------- pooled mean + logits ----------------
__global__ __launch_bounds__(320) void pooled_k(
    const float* __restrict__ hn, const float* __restrict__ mask,
    const float* __restrict__ Wc, const float* __restrict__ bc, float* __restrict__ out)
{
  int b=blockIdx.x, t=threadIdx.x;
  __shared__ float msk[NN_];
  __shared__ float pl[RHID];
  __shared__ float wn;
  if (t<NN_) msk[t]=mask[b*NN_+t];
  __syncthreads();
  if (t==0){ float s=0.f; for (int n=0;n<NN_;++n) s+=msk[n]; wn=s; }
  __syncthreads();
  if (t<RHID){
    float s=0.f;
    for (int n=0;n<NN_;++n) s += hn[((size_t)(b*NN_+n))*RHID+t]*msk[n];
    pl[t]=s/wn;
  }
  __syncthreads();
  if (t<3){
    float s=bc[t];
    for (int d=0;d<RHID;++d) s += pl[d]*Wc[t*RHID+d];
    out[b*3+t]=s;
  }
}

extern "C" void kernel_launch(void* const* d_in, const int* in_sizes, int n_in,
                              void* d_out, int out_size, void* d_ws, size_t ws_size,
                              hipStream_t stream)
{
  (void)in_sizes; (void)n_in; (void)out_size; (void)ws_size;
  const int*   tok      = (const int*)  d_in[0];
  const int*   pos_ids  = (const int*)  d_in[2];
  const int*   post_ids = (const int*)  d_in[5];
  const float* mask     = (const float*)d_in[6];
  const float* shortm   = (const float*)d_in[8];
  const float* emb_w    = (const float*)d_in[9];
  const float* pos_w    = (const float*)d_in[10];
  const float* post_w   = (const float*)d_in[11];
  const float* Wih_f    = (const float*)d_in[12];
  const float* Whh_f    = (const float*)d_in[13];
  const float* b_f      = (const float*)d_in[14];
  const float* Wih_b    = (const float*)d_in[15];
  const float* Whh_b    = (const float*)d_in[16];
  const float* b_b      = (const float*)d_in[17];
  const float* Wq       = (const float*)d_in[18];
  const float* bq       = (const float*)d_in[19];
  const float* Wk       = (const float*)d_in[20];
  const float* bk       = (const float*)d_in[21];
  const float* Wd       = (const float*)d_in[22];
  const float* bd       = (const float*)d_in[23];
  const float* weight_m = (const float*)d_in[24];
  const float* bias_m   = (const float*)d_in[25];
  const float* Ww       = (const float*)d_in[26];
  const float* bw       = (const float*)d_in[27];
  const float* Wx       = (const float*)d_in[28];
  const float* bx       = (const float*)d_in[29];
  const float* Wxx      = (const float*)d_in[30];
  const float* bxx      = (const float*)d_in[31];
  const float* Wc       = (const float*)d_in[32];
  const float* bc       = (const float*)d_in[33];

  float* ws  = (float*)d_ws;
  float* out = (float*)d_out;

  __bf16* ginb  = (__bf16*)(ws + OFF_GINB);
  float* aspect = ws + OFF_ASPECT;
  float* ascb   = ws + OFF_ASCB;
  float* w1sum  = ws + OFF_W1SUM;
  float* w2sum  = ws + OFF_W2SUM;
  float* swx    = ws + OFF_SWX;
  float* sbx    = ws + OFF_SBX;
  float* sgi    = ws + OFF_SGI;
  float* whs    = ws + OFF_WHS;
  __bf16* wqkp  = (__bf16*)(ws + OFF_WQKP);
  float* bqk    = ws + OFF_BQK;
  __bf16* wwp   = (__bf16*)(ws + OFF_WWP);
  __bf16* wxxp  = (__bf16*)(ws + OFF_WXXP);
  __bf16* wihpF = (__bf16*)(ws + OFF_WIHPF);
  __bf16* wihpB = (__bf16*)(ws + OFF_WIHPB);
  float* bpF    = ws + OFF_BPF;
  float* bpB    = ws + OFF_BPB;
  __bf16* wtb   = (__bf16*)(ws + OFF_WTB);
  __bf16* embs  = (__bf16*)(ws + OFF_EMBS);
  __bf16* xgf   = (__bf16*)(ws + OFF_XGF);
  __bf16* xgb   = (__bf16*)(ws + OFF_XGB);
  __bf16* hist  = (__bf16*)(ws + OFF_HIST);
  int*   flags  = (int*)(ws + OFF_FLAGS);
  __bf16* qkh   = (__bf16*)(ws + OFF_QKH);
  __bf16* adjb  = (__bf16*)(ws + OFF_ADJ);
  __bf16* adjs  = (__bf16*)(ws + OFF_ADJS);
  __bf16* gint  = (__bf16*)(ws + OFF_GINT);
  __bf16* w12   = (__bf16*)(ws + OFF_W12);
  float* wdm    = ws + OFF_WDM;
  float* bdm    = ws + OFF_BDM;
  __bf16* axb   = (__bf16*)(ws + OFF_AXB);
  __bf16* g1b   = (__bf16*)(ws + OFF_G1B);
  __bf16* g1t   = (__bf16*)(ws + OFF_G1T);
  __bf16* ax2b  = (__bf16*)(ws + OFF_AX2B);
  __bf16* g2b   = (__bf16*)(ws + OFF_G2B);
  float* hnb    = ws + OFF_HNB;

  // 1. embeddings, constants, weight packing, init
  embed_k<<<dim3(BB*NN_),384,0,stream>>>(tok,pos_ids,post_ids,emb_w,pos_w,post_w,embs);
  consts_k<<<1,640,0,stream>>>(Wx,bx,w1sum,w2sum,swx,sbx,w12);
  wdm_k<<<dim3(DM,NH),128,0,stream>>>(Wd,bd,weight_m,wdm,bdm);
  wihp_k<<<dim3((G4*INP+G4+255)/256,2),256,0,stream>>>(Wih_f,b_f,Wih_b,b_b,wihpF,bpF,wihpB,bpB);
  wqkhp_k<<<dim3((QKL*DMP+QKL+255)/256),256,0,stream>>>(Wq,bq,Wk,bk,wqkp,bqk);
  wpk_k<<<dim3((DM*DMP+255)/256),256,0,stream>>>(Ww,wwp,DM,DM,DMP);
  wpk_k<<<dim3((RHID*DMP+255)/256),256,0,stream>>>(Wxx,wxxp,RHID,DM,DMP);
  whhp_k<<<dim3((G4*KPAD+255)/256,2),256,0,stream>>>(Whh_f,Whh_b,wtb);
  init_k<<<dim3((22528+255)/256),256,0,stream>>>(ws);
  // 2. LSTM input projections (bf16 MFMA, LDS-free), bf16 out
  wgemm_k<12,0,1><<<dim3(128,8,1),256,0,stream>>>(embs,wihpF,bpF,xgf, G4,G4,G4, 0,0,0);
  wgemm_k<12,0,1><<<dim3(128,8,1),256,0,stream>>>(embs,wihpB,bpB,xgb, G4,G4,G4, 0,0,0);
  // 3. recurrence (fence-free system-coherent cluster sync)
  lstm_mfma_k<<<dim3(2*S_CL),256,0,stream>>>(xgf,xgb,wtb,hist,flags);
  reshape_k<<<dim3(BB*NN_),320,0,stream>>>(hist,ginb);
  // 4. fused Q||K projection (bf16 head-padded), aspect path
  wgemm_k<19,0,1><<<dim3(128,8,1),256,0,stream>>>(ginb,wqkp,bqk,qkh, QKL,QKL,QKL, 0,0,0);
  aspect_k<<<dim3(BB,2),320,0,stream>>>(ginb,mask,aspect);
  ascf_k<<<dim3(BB,NH),128,0,stream>>>(aspect,wdm,bdm,qkh,bias_m,ascb);
  // 5. MFMA scores + softmax -> adj bf16
  attn2_k<<<dim3(BB*NH),256,0,stream>>>(qkh,ascb,shortm,tok,adjb);
  // 6. GCN layer 1 (bf16 MFMA)
  adjsum_k<<<4096,256,0,stream>>>(adjb,swx,adjs,whs);
  tr_k<<<dim3(10,2,BB),256,0,stream>>>(ginb,gint);
  wgemm_k<4,0,1><<<dim3(2,4,BB),256,0,stream>>>(adjs,gint,nullptr,axb, DM,DMP,DMP, 16384,(long long)DMP*NN_,(long long)NN_*DMP);
  wgemm_k<19,1,1><<<dim3(128,8,1),256,0,stream>>>(axb,wwp,bw,g1b, DM,DMP,DMP, 0,0,0);
  // 7. layer-2 adjacency collapsed (sg via coalesced MFMA GEMV, N=2)
  wgemm_k<19,0,0><<<dim3(128,1,1),256,0,stream>>>(g1b,w12,nullptr,sgi, 2,2,2, 0,0,0);
  adjsum2_k<<<4096,256,0,stream>>>(whs,sgi,sbx,adjs);
  // 8. GCN layer 2
  tr_k<<<dim3(10,2,BB),256,0,stream>>>(g1b,g1t);
  wgemm_k<4,0,1><<<dim3(2,4,BB),256,0,stream>>>(adjs,g1t,nullptr,ax2b, DM,DMP,DMP, 16384,(long long)DMP*NN_,(long long)NN_*DMP);
  wgemm_k<19,1,1><<<dim3(128,8,1),256,0,stream>>>(ax2b,wwp,bw,g2b, DM,DMP,DMP, 0,0,0);
  // 9. head
  wgemm_k<19,2,0><<<dim3(128,4,1),256,0,stream>>>(g2b,wxxp,bxx,hnb, RHID,RHID,RHID, 0,0,0);
  pooled_k<<<BB,320,0,stream>>>(hnb,mask,Wc,bc,out);
}

// Round 10
// 1270.019 us; speedup vs baseline: 2.0987x; 1.0107x over previous
//
#include <hip/hip_runtime.h>
#include <math.h>

// ---- problem constants ----
#define BB    64
#define NN_   128
#define NH    6
#define DM    600     // d_model
#define RHID  300     // rnn hidden
#define DKH   100     // per-head dim
#define INDIM 360
#define G4    1200    // 4*RHID
#define WXROW 1206    // NH + 2*DM
#define DMP   608     // DM padded to mult of 32
#define INP   384     // INDIM padded
#define QKL   1536    // 2 * NH * 128 (head-padded q||k row length)
#define XGW   2400    // merged xg row width (fwd 0:1200, bwd 1200:2400)

// ---- LSTM cluster config ----
#define S_CL  25
#define NSU   12
#define NSR   48
#define KPAD  320
#define HSLOT (BB*KPAD)          // 20480 bf16 per history slot
#define DSTR  (129*HSLOT)        // per-dir history stride (bf16)

// ---- workspace layout (float offsets). Peak ~ 26.35M fl = 105.4 MB ----
#define OFF_GINB   0ull                 // bf16 [8192][608] = 2,490,368 fl
#define OFF_ASPECT 2490368ull
#define OFF_ASCB   2573568ull
#define OFF_W1SUM  2622720ull
#define OFF_W2SUM  2623360ull
#define OFF_SWX    2624000ull
#define OFF_SBX    2624016ull
#define OFF_SGI    2624032ull           // fp32 [8192][2] interleaved (sg1,sg2)
#define OFF_WHS    2640416ull           // fp32 [64][128][128]
#define OFF_WQKP   3688992ull           // bf16 [1536][608] = 466,944 fl
#define OFF_BQK    4155936ull           // fp32 1536
#define OFF_WWP    4157472ull           // bf16 [600][608] = 182,400 fl
#define OFF_WXXP   4339872ull           // bf16 [300][608] = 91,200 fl
#define OFF_WIHP   4431072ull           // bf16 [2400][384] = 460,800 fl
#define OFF_BP     4891872ull           // fp32 [2400]
#define OFF_WTB    4894272ull           // bf16 [2][1200][320] = 384,000 fl
#define OFF_EMBS   5278272ull           // bf16 [8192][384] = 1,572,864 fl
#define ARENA      6851136ull
#define OFF_XG     (ARENA)                      // bf16 [8192][2400] = 9,830,400 fl
#define OFF_HIST   (ARENA + 9830400ull)         // bf16 [2][129][64][320] = 2,641,920 fl
#define OFF_FLAGS  (ARENA + 12472320ull)        // flags (50, 128B apart)
// post-lstm reuse (xg dead after lstm; hist/flags dead after reshape):
#define OFF_QKH    (ARENA)                      // bf16 [8192][1536] = 6,291,456 fl (over xg)
#define OFF_ADJ    (ARENA + 6291456ull)         // bf16 [64][6][128][128] = 3,145,728 fl
#define OFF_ADJS   (ARENA + 16121856ull)        // bf16 [64][128][128] = 524,288 fl
#define OFF_GINT   (ARENA + 16646144ull)        // bf16 [64][608][128] = 2,490,368 fl
#define OFF_W12    (ARENA + 19136512ull)        // bf16 [2][608] = 608 fl
#define OFF_WDM    (ARENA + 19137152ull)        // fp32 [6][600][100] = 360,000 fl
#define OFF_BDM    (ARENA + 19497152ull)        // fp32 600
#define OFF_AXB    (ARENA)                      // bf16 (over qkh, dead after attn2/ascf)
#define OFF_G1B    (ARENA + 2490368ull)
#define OFF_G1T    (OFF_GINT)
#define OFF_AX2B   (ARENA + 4980736ull)
#define OFF_G2B    (ARENA + 7471104ull)         // over adj (dead after adjsum)
#define OFF_HNB    (ARENA + 9961472ull)         // fp32 [8192][300] (over hist, dead)

// ---- pack_k segmented index space ----
#define PK0 (XGW*INP + XGW)                 //   924,000 wihp + bias
#define PK1 (PK0 + QKL*DMP + QKL)           // 1,859,424 wqkhp + bias
#define PK2 (PK1 + DM*DMP)                  // 2,224,224 Ww pack
#define PK3 (PK2 + RHID*DMP)                // 2,406,624 Wxx pack
#define PK4 (PK3 + 2*G4*KPAD)               // 3,174,624 Whh both dirs
#define PK5 (PK4 + 22528)                   // 3,197,152 hist slot0 + flags init

typedef __bf16 bf16x8 __attribute__((ext_vector_type(8)));
typedef __bf16 bf16x4 __attribute__((ext_vector_type(4)));
typedef __bf16 bf16x2 __attribute__((ext_vector_type(2)));
typedef float  f32x4  __attribute__((ext_vector_type(4)));

__device__ __forceinline__ float sigm(float x){ return 1.f/(1.f+__expf(-x)); }
__device__ __forceinline__ float selu_f(float x){
  const float sc=1.0507009873554805f, al=1.6732632423543772f;
  return x>0.f ? sc*x : sc*al*(__expf(x)-1.f);
}
__device__ __forceinline__ bf16x8 bzero8(){
  bf16x8 z;
#pragma unroll
  for (int j=0;j<8;++j) z[j]=(__bf16)0.f;
  return z;
}

// ---------------- embedding concat -> bf16 [8192][384], pads written zero ----------------
__global__ __launch_bounds__(384) void embed_k(
    const int* __restrict__ tok, const int* __restrict__ pos_ids, const int* __restrict__ post_ids,
    const float* __restrict__ emb_w, const float* __restrict__ pos_w, const float* __restrict__ post_w,
    __bf16* __restrict__ embs)
{
  int bn = blockIdx.x, t = threadIdx.x;
  float v = 0.f;
  if      (t < 300) v = emb_w [(size_t)tok     [bn]*300 + t];
  else if (t < 330) v = pos_w [(size_t)pos_ids [bn]*30  + (t-300)];
  else if (t < 360) v = post_w[(size_t)post_ids[bn]*30  + (t-330)];
  embs[(size_t)bn*INP + t] = (__bf16)v;
}

// ---------------- Wx folded constants (+ bf16 w12 for the sg GEMV) ----------------
__global__ __launch_bounds__(640) void consts_k(
    const float* __restrict__ Wx, const float* __restrict__ bx,
    float* __restrict__ w1sum, float* __restrict__ w2sum,
    float* __restrict__ swx, float* __restrict__ sbx, __bf16* __restrict__ w12)
{
  int t = threadIdx.x;
  if (t < DM){
    float s1=0.f, s2=0.f;
    for (int k=0;k<NH;++k){ s1 += Wx[k*WXROW + NH + t]; s2 += Wx[k*WXROW + NH + DM + t]; }
    w1sum[t]=s1; w2sum[t]=s2;
    w12[t]=(__bf16)s1; w12[DMP+t]=(__bf16)s2;
  } else if (t < DM+NH){
    int h=t-DM; float s=0.f;
    for (int k=0;k<NH;++k) s += Wx[k*WXROW + h];
    swx[h]=s;
  } else if (t == DM+NH){
    float s=0.f; for (int k=0;k<NH;++k) s += bx[k];
    sbx[0]=s;
  }
  if (t >= DM && t < DMP){ w12[t]=(__bf16)0.f; w12[DMP+t]=(__bf16)0.f; }
}

// ---------------- WdM[h][D][e] = sum_d Wd[d][D]*wm[h][d][e]; bdM[h][e] = bd·wm[h][:,e] ----------------
__global__ __launch_bounds__(128) void wdm_k(
    const float* __restrict__ Wd, const float* __restrict__ bd, const float* __restrict__ wm,
    float* __restrict__ WdM, float* __restrict__ bdM)
{
  int D = blockIdx.x, h = blockIdx.y, e = threadIdx.x;
  if (e >= DKH) return;
  float s = 0.f;
  for (int d=0; d<DKH; ++d)
    s += Wd[d*DM + D] * wm[(h*DKH+d)*DKH + e];
  WdM[((size_t)h*DM + D)*DKH + e] = s;
  if (D == 0){
    float sb = 0.f;
    for (int d=0; d<DKH; ++d) sb += bd[d]*wm[(h*DKH+d)*DKH + e];
    bdM[h*DKH + e] = sb;
  }
}

// ---------------- fused packing/init (segmented): wihp|wqkhp|Ww|Wxx|Whh|init ----------------
__global__ __launch_bounds__(256) void pack_k(
    const float* __restrict__ Wih_f, const float* __restrict__ b_f,
    const float* __restrict__ Wih_b, const float* __restrict__ b_b,
    const float* __restrict__ Wq, const float* __restrict__ bq,
    const float* __restrict__ Wk, const float* __restrict__ bk,
    const float* __restrict__ Ww, const float* __restrict__ Wxx,
    const float* __restrict__ Whh_f, const float* __restrict__ Whh_b,
    __bf16* __restrict__ wihp, float* __restrict__ bp,
    __bf16* __restrict__ wqkp, float* __restrict__ bqk,
    __bf16* __restrict__ wwp, __bf16* __restrict__ wxxp,
    __bf16* __restrict__ wtb, float* __restrict__ ws)
{
  int idx = blockIdx.x*256 + threadIdx.x;
  if (idx < PK0){
    // Wih both dirs, gate-interleaved rows p=4u+g -> [2400][384]
    if (idx < XGW*INP){
      int r = idx / INP, k = idx - r*INP;
      int dir = r >= G4; int p = r - dir*G4;
      const float* W = dir ? Wih_b : Wih_f;
      int srow = (p&3)*RHID + (p>>2);
      wihp[idx] = (k<INDIM) ? (__bf16)W[(size_t)srow*INDIM + k] : (__bf16)0.f;
    } else {
      int n = idx - XGW*INP;
      int dir = n >= G4; int p = n - dir*G4;
      const float* b = dir ? b_b : b_f;
      bp[n] = b[(p&3)*RHID + (p>>2)];
    }
  } else if (idx < PK1){
    // Wq||Wk head-padded -> [1536][608]; e>=100 rows zero
    int id = idx - PK0;
    if (id < QKL*DMP){
      int n = id / DMP, k = id - n*DMP;
      int nl = (n < 768) ? n : n - 768;
      int h = nl >> 7, e = nl & 127;
      float v = 0.f;
      if (k < DM && e < DKH)
        v = (n < 768) ? Wq[(size_t)(h*DKH+e)*DM + k] : Wk[(size_t)(h*DKH+e)*DM + k];
      wqkp[id] = (__bf16)v;
    } else {
      int n = id - QKL*DMP;
      int nl = (n < 768) ? n : n - 768;
      int h = nl >> 7, e = nl & 127;
      bqk[n] = (e < DKH) ? ((n < 768) ? bq[h*DKH+e] : bk[h*DKH+e]) : 0.f;
    }
  } else if (idx < PK2){
    int id = idx - PK1;
    int n = id / DMP, k = id - n*DMP;
    wwp[id] = (k < DM) ? (__bf16)Ww[(size_t)n*DM + k] : (__bf16)0.f;
  } else if (idx < PK3){
    int id = idx - PK2;
    int n = id / DMP, k = id - n*DMP;
    wxxp[id] = (k < DM) ? (__bf16)Wxx[(size_t)n*DM + k] : (__bf16)0.f;
  } else if (idx < PK4){
    int id = idx - PK3;
    int dir = id >= G4*KPAD; int id2 = id - dir*G4*KPAD;
    int p = id2 / KPAD, k = id2 - p*KPAD;
    const float* Whh = dir ? Whh_b : Whh_f;
    wtb[id] = (k < RHID) ? (__bf16)Whh[((size_t)((p&3)*RHID + (p>>2)))*RHID + k] : (__bf16)0.f;
  } else if (idx < PK5){
    int id = idx - PK4;
    if (id < 10240)      ws[OFF_HIST + id] = 0.f;                        // dir0 slot0
    else if (id < 20480) ws[OFF_HIST + 1320960ull + (id-10240)] = 0.f;   // dir1 slot0
    else                 ws[OFF_FLAGS + (id-20480)] = 0.f;               // flags
  }
}

// ---------------- LDS-free bf16 MFMA GEMM: C = act(A @ B^T + bias) ----------------
// Dual accumulator chains (even/odd kt) double per-wave MFMA ILP.
template<int KT, int ACT, int OBF>
__global__ __launch_bounds__(256) void wgemm_k(
    const __bf16* __restrict__ A, const __bf16* __restrict__ B,
    const float* __restrict__ bias, void* __restrict__ Cout,
    int Nn, int Npad, int ldc,
    long long sA, long long sB, long long sC)
{
  const int tid = threadIdx.x, lane = tid & 63, wave = tid >> 6;
  const int fn = lane & 15, fq = lane >> 4;
  const int K = KT*32;
  const __bf16* Ab = A + (size_t)blockIdx.z * (size_t)sA;
  const __bf16* Bb = B + (size_t)blockIdx.z * (size_t)sB;
  float*  Cf = (float*) Cout + (size_t)blockIdx.z * (size_t)sC;
  __bf16* Ch = (__bf16*)Cout + (size_t)blockIdx.z * (size_t)sC;

  const int m0 = (blockIdx.x*4 + wave)*16;

  bf16x8 Af[KT];
#pragma unroll
  for (int kt=0; kt<KT; ++kt)
    Af[kt] = *(const bf16x8*)(Ab + (size_t)(m0 + fn)*K + kt*32 + fq*8);

  for (int n0 = blockIdx.y*16; n0 < Nn; n0 += 16*gridDim.y){
    const int gn = n0 + fn;
    const int gnc = (gn < Nn) ? gn : 0;
    f32x4 acc0 = {0.f,0.f,0.f,0.f};
    f32x4 acc1 = {0.f,0.f,0.f,0.f};
#pragma unroll
    for (int kt=0; kt<KT; ++kt){
      bf16x8 Bf = *(const bf16x8*)(Bb + (size_t)gnc*K + kt*32 + fq*8);
      if (gn >= Nn) Bf = bzero8();
      if (kt & 1) acc1 = __builtin_amdgcn_mfma_f32_16x16x32_bf16(Af[kt], Bf, acc1, 0, 0, 0);
      else        acc0 = __builtin_amdgcn_mfma_f32_16x16x32_bf16(Af[kt], Bf, acc0, 0, 0, 0);
    }
    float bv = (bias && gn < Nn) ? bias[gn] : 0.f;
#pragma unroll
    for (int r=0; r<4; ++r){
      int gm = m0 + fq*4 + r;
      float v = acc0[r] + acc1[r] + bv;
      if (ACT==1) v = selu_f(v);
      else if (ACT==2) v = fmaxf(v, 0.f);
      if (gn < Nn){
        if (OBF) Ch[(size_t)gm*ldc + gn] = (__bf16)v;
        else     Cf[(size_t)gm*ldc + gn] = v;
      } else if (gn < Npad){
        if (OBF) Ch[(size_t)gm*ldc + gn] = (__bf16)0.f;
        else     Cf[(size_t)gm*ldc + gn] = 0.f;
      }
    }
  }
}

// ---------------- bf16 per-batch transpose [64][128][608] -> [64][608][128] ----------------
__global__ __launch_bounds__(256) void tr_k(
    const __bf16* __restrict__ in, __bf16* __restrict__ out)
{
  const int b = blockIdx.z, m0 = blockIdx.y*64, d0 = blockIdx.x*64;
  const int tid = threadIdx.x;
  __shared__ __align__(16) __bf16 T[64][72];
  const __bf16* ib = in + (size_t)b*NN_*DMP;
  __bf16* ob = out + (size_t)b*DMP*NN_;
#pragma unroll
  for (int r=0;r<2;++r){
    int idx = tid + 256*r;
    int mi = idx>>3, ch = idx&7;
    int d = d0 + ch*8;
    bf16x8 v = bzero8();
    if (d < DMP) v = *(const bf16x8*)(ib + (size_t)(m0+mi)*DMP + d);
    *(bf16x8*)&T[mi][ch*8] = v;
  }
  __syncthreads();
#pragma unroll
  for (int r=0;r<2;++r){
    int idx = tid + 256*r;
    int di = idx>>3, mch = idx&7;
    int d = d0 + di;
    if (d >= DMP) continue;
    bf16x8 v;
#pragma unroll
    for (int j=0;j<8;++j) v[j] = T[mch*8+j][di];
    *(bf16x8*)(ob + (size_t)d*NN_ + m0 + mch*8) = v;
  }
}

// ---------------- cooperative-cluster MFMA LSTM — fence-free system-coherent sync ----------------
// xg merged: row stride 2400, dir offset 1200.
__global__ __launch_bounds__(256, 1) void lstm_mfma_k(
    const __bf16* __restrict__ xg,
    const __bf16* __restrict__ wtb,
    __bf16* hist, int* flags)
{
  const int blk = blockIdx.x;
  const int dir = blk / S_CL, sl = blk - dir*S_CL;
  const int tid = threadIdx.x, lane = tid & 63, wave = tid >> 6;
  const int p0 = sl * NSR;
  const __bf16* W = wtb + (size_t)dir * G4 * KPAD;
  __bf16* hb = hist + (size_t)dir * DSTR;

  __shared__ __align__(16) float accS[NSR][68];

  const int fn = lane & 15;
  const int fk = (lane >> 4) * 8;
  const int m0 = wave * 16;

  bf16x8 Bf[3][10];
#pragma unroll
  for (int nt = 0; nt < 3; ++nt)
#pragma unroll
    for (int kt = 0; kt < 10; ++kt)
      Bf[nt][kt] = *(const bf16x8*)(W + (size_t)(p0 + nt*16 + fn)*KPAD + kt*32 + fk);

  const int b_ep = tid / 3;
  const int q_ep = tid - b_ep*3;
  const int u0 = q_ep*4;
  const bool ep = (tid < 192);
  float cst[4] = {0.f,0.f,0.f,0.f};
  const __bf16* xp = xg + (size_t)b_ep*NN_*XGW + dir*G4 + p0 + u0*4;

  for (int s = 0; s < NN_; ++s){
    const int n_t = dir ? (NN_-1-s) : s;
    const __bf16* hbr = hb + (size_t)s*HSLOT;
    __bf16*       hbw = hb + (size_t)(s+1)*HSLOT;

    bf16x8 xv0, xv1;
    if (ep){
      xv0 = *(const bf16x8*)(xp + (size_t)n_t*XGW);
      xv1 = *(const bf16x8*)(xp + (size_t)n_t*XGW + 8);
    }

    bf16x8 Af[10];
#pragma unroll
    for (int kt = 0; kt < 10; ++kt){
      const unsigned long long* hp =
          (const unsigned long long*)(hbr + (size_t)(m0 + fn)*KPAD + kt*32 + fk);
      union { unsigned long long u[2]; bf16x8 v; } cv;
      cv.u[0] = __hip_atomic_load(hp,   __ATOMIC_RELAXED, __HIP_MEMORY_SCOPE_SYSTEM);
      cv.u[1] = __hip_atomic_load(hp+1, __ATOMIC_RELAXED, __HIP_MEMORY_SCOPE_SYSTEM);
      Af[kt] = cv.v;
    }

    f32x4 acc[3] = { {0.f,0.f,0.f,0.f}, {0.f,0.f,0.f,0.f}, {0.f,0.f,0.f,0.f} };
#pragma unroll
    for (int kt = 0; kt < 10; ++kt)
#pragma unroll
      for (int nt = 0; nt < 3; ++nt)
        acc[nt] = __builtin_amdgcn_mfma_f32_16x16x32_bf16(Af[kt], Bf[nt][kt], acc[nt], 0, 0, 0);

#pragma unroll
    for (int nt = 0; nt < 3; ++nt)
      *(f32x4*)&accS[nt*16 + fn][m0 + (lane>>4)*4] = acc[nt];
    __syncthreads();

    if (ep){
      union { unsigned long long u; __bf16 h[4]; } pk;
      float xgv[16];
#pragma unroll
      for (int j=0;j<8;++j){ xgv[j]=(float)xv0[j]; xgv[8+j]=(float)xv1[j]; }
#pragma unroll
      for (int du = 0; du < 4; ++du){
        int u = u0 + du;
        float p_i = accS[u*4+0][b_ep] + xgv[du*4+0];
        float p_f = accS[u*4+1][b_ep] + xgv[du*4+1];
        float p_g = accS[u*4+2][b_ep] + xgv[du*4+2];
        float p_o = accS[u*4+3][b_ep] + xgv[du*4+3];
        float ig = sigm(p_i), fg = sigm(p_f), gg = tanhf(p_g), og = sigm(p_o);
        float c = fg*cst[du] + ig*gg; cst[du] = c;
        pk.h[du] = (__bf16)(og * tanhf(c));
      }
      __hip_atomic_store(
          (unsigned long long*)(hbw + (size_t)b_ep*KPAD + sl*NSU + u0),
          pk.u, __ATOMIC_RELAXED, __HIP_MEMORY_SCOPE_SYSTEM);
    }
    __syncthreads();
    if (tid == 0)
      __hip_atomic_store(&flags[(dir*S_CL + sl)*32], s+1, __ATOMIC_RELAXED, __HIP_MEMORY_SCOPE_SYSTEM);
    if (wave == 0 && lane < S_CL){
      int* fp = &flags[(dir*S_CL + lane)*32];
      while (__hip_atomic_load(fp, __ATOMIC_RELAXED, __HIP_MEMORY_SCOPE_SYSTEM) < s+1) { }
    }
    __syncthreads();
  }
}

// ---------------- hist -> ginb [8192][608] (pads zeroed) ----------------
__global__ __launch_bounds__(320) void reshape_k(
    const __bf16* __restrict__ hist, __bf16* __restrict__ ginb)
{
  int row = blockIdx.x;                 // b*128 + n
  int b = row >> 7, n = row & 127;
  int t = threadIdx.x;
  if (t < 150){
    int u = 2*t;
    bf16x2 v = *(const bf16x2*)(hist + (size_t)(n+1)*HSLOT + (size_t)b*KPAD + u);
    *(bf16x2*)(ginb + (size_t)row*DMP + u) = v;
  } else if (t >= 160 && t < 310){
    int u = 2*(t-160);
    bf16x2 v = *(const bf16x2*)(hist + (size_t)DSTR + (size_t)(NN_-n)*HSLOT + (size_t)b*KPAD + u);
    *(bf16x2*)(ginb + (size_t)row*DMP + RHID + u) = v;
  } else if (t >= 312 && t < 316){
    int c = DM + 2*(t-312);
    bf16x2 z; z[0]=(__bf16)0.f; z[1]=(__bf16)0.f;
    *(bf16x2*)(ginb + (size_t)row*DMP + c) = z;
  }
}

// ---------------- masked mean over sequence -> aspect[B,DM] (bf16 in, 2 col-halves) ----------------
__global__ __launch_bounds__(320) void aspect_k(
    const __bf16* __restrict__ ginb, const float* __restrict__ mask, float* __restrict__ aspect)
{
  int b = blockIdx.x, t = threadIdx.x;
  int col = blockIdx.y*300 + t;
  __shared__ float msk[NN_];
  __shared__ float wn;
  if (t < NN_) msk[t] = mask[b*NN_+t];
  __syncthreads();
  if (t==0){ float s=0.f; for (int n=0;n<NN_;++n) s+=msk[n]; wn=s; }
  __syncthreads();
  if (t < 300){
    float s=0.f;
    for (int n=0;n<NN_;++n) s += (float)ginb[((size_t)(b*NN_+n))*DMP + col]*msk[n];
    aspect[b*DM+col] = s/wn;
  }
}

// ---------------- fused: aw = aspect@WdM + bdM ; asc = tanh(aw·k + bias_m) ----------------
__global__ __launch_bounds__(128) void ascf_k(
    const float* __restrict__ aspect, const float* __restrict__ WdM, const float* __restrict__ bdM,
    const __bf16* __restrict__ qkh, const float* __restrict__ bias_m, float* __restrict__ asc)
{
  int b = blockIdx.x, h = blockIdx.y, t = threadIdx.x;
  __shared__ __align__(16) float asp[DM];
  __shared__ __align__(16) float awl[DKH];
  for (int i = t; i < DM; i += 128) asp[i] = aspect[b*DM + i];
  __syncthreads();
  if (t < DKH){
    const float* wrow = WdM + (size_t)h*DM*DKH + t;
    float s0=0.f,s1=0.f,s2=0.f,s3=0.f;
    for (int D=0; D<DM; D+=4){
      s0 += asp[D+0]*wrow[(size_t)(D+0)*DKH];
      s1 += asp[D+1]*wrow[(size_t)(D+1)*DKH];
      s2 += asp[D+2]*wrow[(size_t)(D+2)*DKH];
      s3 += asp[D+3]*wrow[(size_t)(D+3)*DKH];
    }
    awl[t] = s0+s1+s2+s3 + bdM[h*DKH + t];
  }
  __syncthreads();
  const __bf16* kr = qkh + (size_t)(b*NN_ + t)*QKL + 768 + h*128;
  float s=0.f;
#pragma unroll
  for (int e=0;e<DKH;e+=2){
    bf16x2 kv = *(const bf16x2*)(kr + e);
    s += awl[e]*(float)kv[0] + awl[e+1]*(float)kv[1];
  }
  asc[(b*NH+h)*NN_ + t] = tanhf(s + bias_m[0]);
}

// ---------------- MFMA attention (split x2): scores + mask + short + softmax -> adj bf16 ----------------
__global__ __launch_bounds__(256) void attn2_k(
    const __bf16* __restrict__ qkh, const float* __restrict__ asc,
    const float* __restrict__ shortm, const int* __restrict__ tok,
    __bf16* __restrict__ adj)
{
  const int bx = blockIdx.x;
  const int bh = bx >> 1, half = bx & 1;
  const int b = bh / NH, h = bh - b*NH;
  const int tid = threadIdx.x, lane = tid & 63, wave = tid >> 6;
  const int fn = lane & 15, fq = lane >> 4;
  const __bf16* qb = qkh + (size_t)(b*NN_)*QKL + h*128;
  const __bf16* kb = qkh + (size_t)(b*NN_)*QKL + 768 + h*128;

  const int m0 = half*64 + wave*16;
  bf16x8 Af[4];
#pragma unroll
  for (int kt=0;kt<4;++kt)
    Af[kt] = *(const bf16x8*)(qb + (size_t)(m0+fn)*QKL + kt*32 + fq*8);

  f32x4 acc[8];
#pragma unroll
  for (int j=0;j<8;++j) acc[j] = (f32x4){0.f,0.f,0.f,0.f};

#pragma unroll
  for (int j=0;j<8;++j){
    bf16x8 Bf[4];
#pragma unroll
    for (int kt=0;kt<4;++kt)
      Bf[kt] = *(const bf16x8*)(kb + (size_t)(j*16+fn)*QKL + kt*32 + fq*8);
#pragma unroll
    for (int kt=0;kt<4;++kt)
      acc[j] = __builtin_amdgcn_mfma_f32_16x16x32_bf16(Af[kt], Bf[kt], acc[j], 0,0,0);
  }

  float ascv[8]; int msk[8];
#pragma unroll
  for (int j=0;j<8;++j){
    int c = j*16 + fn;
    ascv[j] = asc[(b*NH+h)*NN_ + c];
    msk [j] = tok[b*NN_ + c];
  }

#pragma unroll
  for (int r=0;r<4;++r){
    int m = m0 + fq*4 + r;
    float sv[8];
#pragma unroll
    for (int j=0;j<8;++j){
      int c = j*16 + fn;
      float s = acc[j][r]*0.1f + ascv[j];
      if (msk[j]==0) s = -1e9f;
      s += shortm[((size_t)(b*NN_+m))*NN_ + c];
      sv[j]=s;
    }
    float mx = sv[0];
#pragma unroll
    for (int j=1;j<8;++j) mx = fmaxf(mx, sv[j]);
#pragma unroll
    for (int o=1;o<16;o<<=1) mx = fmaxf(mx, __shfl_xor(mx, o, 64));
    float sum = 0.f, ev[8];
#pragma unroll
    for (int j=0;j<8;++j){ ev[j]=__expf(sv[j]-mx); sum+=ev[j]; }
#pragma unroll
    for (int o=1;o<16;o<<=1) sum += __shfl_xor(sum, o, 64);
    float inv = 1.f/sum;
#pragma unroll
    for (int j=0;j<8;++j)
      adj[(((size_t)(b*NH+h))*NN_ + m)*NN_ + j*16 + fn] = (__bf16)(ev[j]*inv);
  }
}

// ---------------- adjsum (bf16 in) -> bf16 adjs (/H) + fp32 whs ----------------
__global__ __launch_bounds__(256) void adjsum_k(
    const __bf16* __restrict__ adj, const float* __restrict__ swx,
    __bf16* __restrict__ adjs, float* __restrict__ whs)
{
  int idx = blockIdx.x*256 + threadIdx.x;
  int b = idx >> 14, rem = idx & 16383;
  float s=0.f, w=0.f;
  for (int h=0;h<NH;++h){
    float v = (float)adj[(((size_t)b*NH+h)<<14) + rem];
    s += v; w += v*swx[h];
  }
  adjs[idx] = (__bf16)(s*(1.f/NH));
  whs [idx] = w*(1.f/NH);
}

// ---------------- adjs2[b,i,j] = whs + (sg1[b,j]+sg2[b,i]+sbx)/H -> bf16 ----------------
__global__ __launch_bounds__(256) void adjsum2_k(
    const float* __restrict__ whs, const float* __restrict__ sgi,
    const float* __restrict__ sbx, __bf16* __restrict__ adjs)
{
  int idx = blockIdx.x*256 + threadIdx.x;
  int b = idx >> 14, rem = idx & 16383;
  int i = rem >> 7, j = rem & 127;
  adjs[idx] = (__bf16)(whs[idx] + (sgi[(b*NN_+j)*2] + sgi[(b*NN_+i)*2+1] + sbx[0])*(1.f/NH));
}

// ---------------- pooled mean + logits ----------------
__global__ __launch_bounds__(320) void pooled_k(
    const float* __restrict__ hn, const float* __restrict__ mask,
    const float* __restrict__ Wc, const float* __restrict__ bc, float* __restrict__ out)
{
  int b=blockIdx.x, t=threadIdx.x;
  __shared__ float msk[NN_];
  __shared__ float pl[RHID];
  __shared__ float wn;
  if (t<NN_) msk[t]=mask[b*NN_+t];
  __syncthreads();
  if (t==0){ float s=0.f; for (int n=0;n<NN_;++n) s+=msk[n]; wn=s; }
  __syncthreads();
  if (t<RHID){
    float s=0.f;
    for (int n=0;n<NN_;++n) s += hn[((size_t)(b*NN_+n))*RHID+t]*msk[n];
    pl[t]=s/wn;
  }
  __syncthreads();
  if (t<3){
    float s=bc[t];
    for (int d=0;d<RHID;++d) s += pl[d]*Wc[t*RHID+d];
    out[b*3+t]=s;
  }
}

extern "C" void kernel_launch(void* const* d_in, const int* in_sizes, int n_in,
                              void* d_out, int out_size, void* d_ws, size_t ws_size,
                              hipStream_t stream)
{
  (void)in_sizes; (void)n_in; (void)out_size; (void)ws_size;
  const int*   tok      = (const int*)  d_in[0];
  const int*   pos_ids  = (const int*)  d_in[2];
  const int*   post_ids = (const int*)  d_in[5];
  const float* mask     = (const float*)d_in[6];
  const float* shortm   = (const float*)d_in[8];
  const float* emb_w    = (const float*)d_in[9];
  const float* pos_w    = (const float*)d_in[10];
  const float* post_w   = (const float*)d_in[11];
  const float* Wih_f    = (const float*)d_in[12];
  const float* Whh_f    = (const float*)d_in[13];
  const float* b_f      = (const float*)d_in[14];
  const float* Wih_b    = (const float*)d_in[15];
  const float* Whh_b    = (const float*)d_in[16];
  const float* b_b      = (const float*)d_in[17];
  const float* Wq       = (const float*)d_in[18];
  const float* bq       = (const float*)d_in[19];
  const float* Wk       = (const float*)d_in[20];
  const float* bk       = (const float*)d_in[21];
  const float* Wd       = (const float*)d_in[22];
  const float* bd       = (const float*)d_in[23];
  const float* weight_m = (const float*)d_in[24];
  const float* bias_m   = (const float*)d_in[25];
  const float* Ww       = (const float*)d_in[26];
  const float* bw       = (const float*)d_in[27];
  const float* Wx       = (const float*)d_in[28];
  const float* bx       = (const float*)d_in[29];
  const float* Wxx      = (const float*)d_in[30];
  const float* bxx      = (const float*)d_in[31];
  const float* Wc       = (const float*)d_in[32];
  const float* bc       = (const float*)d_in[33];

  float* ws  = (float*)d_ws;
  float* out = (float*)d_out;

  __bf16* ginb  = (__bf16*)(ws + OFF_GINB);
  float* aspect = ws + OFF_ASPECT;
  float* ascb   = ws + OFF_ASCB;
  float* w1sum  = ws + OFF_W1SUM;
  float* w2sum  = ws + OFF_W2SUM;
  float* swx    = ws + OFF_SWX;
  float* sbx    = ws + OFF_SBX;
  float* sgi    = ws + OFF_SGI;
  float* whs    = ws + OFF_WHS;
  __bf16* wqkp  = (__bf16*)(ws + OFF_WQKP);
  float* bqk    = ws + OFF_BQK;
  __bf16* wwp   = (__bf16*)(ws + OFF_WWP);
  __bf16* wxxp  = (__bf16*)(ws + OFF_WXXP);
  __bf16* wihp  = (__bf16*)(ws + OFF_WIHP);
  float* bp     = ws + OFF_BP;
  __bf16* wtb   = (__bf16*)(ws + OFF_WTB);
  __bf16* embs  = (__bf16*)(ws + OFF_EMBS);
  __bf16* xg    = (__bf16*)(ws + OFF_XG);
  __bf16* hist  = (__bf16*)(ws + OFF_HIST);
  int*   flags  = (int*)(ws + OFF_FLAGS);
  __bf16* qkh   = (__bf16*)(ws + OFF_QKH);
  __bf16* adjb  = (__bf16*)(ws + OFF_ADJ);
  __bf16* adjs  = (__bf16*)(ws + OFF_ADJS);
  __bf16* gint  = (__bf16*)(ws + OFF_GINT);
  __bf16* w12   = (__bf16*)(ws + OFF_W12);
  float* wdm    = ws + OFF_WDM;
  float* bdm    = ws + OFF_BDM;
  __bf16* axb   = (__bf16*)(ws + OFF_AXB);
  __bf16* g1b   = (__bf16*)(ws + OFF_G1B);
  __bf16* g1t   = (__bf16*)(ws + OFF_G1T);
  __bf16* ax2b  = (__bf16*)(ws + OFF_AX2B);
  __bf16* g2b   = (__bf16*)(ws + OFF_G2B);
  float* hnb    = ws + OFF_HNB;

  // 1. embeddings, constants, fused packing/init
  embed_k<<<dim3(BB*NN_),384,0,stream>>>(tok,pos_ids,post_ids,emb_w,pos_w,post_w,embs);
  consts_k<<<1,640,0,stream>>>(Wx,bx,w1sum,w2sum,swx,sbx,w12);
  wdm_k<<<dim3(DM,NH),128,0,stream>>>(Wd,bd,weight_m,wdm,bdm);
  pack_k<<<dim3((PK5+255)/256),256,0,stream>>>(Wih_f,b_f,Wih_b,b_b,Wq,bq,Wk,bk,Ww,Wxx,
                                               Whh_f,Whh_b,wihp,bp,wqkp,bqk,wwp,wxxp,wtb,ws);
  // 2. merged LSTM input projection (both dirs), bf16 out [8192][2400]
  wgemm_k<12,0,1><<<dim3(128,8,1),256,0,stream>>>(embs,wihp,bp,xg, XGW,XGW,XGW, 0,0,0);
  // 3. recurrence (fence-free system-coherent cluster sync)
  lstm_mfma_k<<<dim3(2*S_CL),256,0,stream>>>(xg,wtb,hist,flags);
  reshape_k<<<dim3(BB*NN_),320,0,stream>>>(hist,ginb);
  // 4. fused Q||K projection (bf16 head-padded), aspect path
  wgemm_k<19,0,1><<<dim3(128,12,1),256,0,stream>>>(ginb,wqkp,bqk,qkh, QKL,QKL,QKL, 0,0,0);
  aspect_k<<<dim3(BB,2),320,0,stream>>>(ginb,mask,aspect);
  ascf_k<<<dim3(BB,NH),128,0,stream>>>(aspect,wdm,bdm,qkh,bias_m,ascb);
  // 5. MFMA scores + softmax -> adj bf16
  attn2_k<<<dim3(BB*NH*2),256,0,stream>>>(qkh,ascb,shortm,tok,adjb);
  // 6. GCN layer 1 (bf16 MFMA)
  adjsum_k<<<4096,256,0,stream>>>(adjb,swx,adjs,whs);
  tr_k<<<dim3(10,2,BB),256,0,stream>>>(ginb,gint);
  wgemm_k<4,0,1><<<dim3(2,4,BB),256,0,stream>>>(adjs,gint,nullptr,axb, DM,DMP,DMP, 16384,(long long)DMP*NN_,(long long)NN_*DMP);
  wgemm_k<19,1,1><<<dim3(128,8,1),256,0,stream>>>(axb,wwp,bw,g1b, DM,DMP,DMP, 0,0,0);
  // 7. layer-2 adjacency collapsed (sg via coalesced MFMA GEMV, N=2)
  wgemm_k<19,0,0><<<dim3(128,1,1),256,0,stream>>>(g1b,w12,nullptr,sgi, 2,2,2, 0,0,0);
  adjsum2_k<<<4096,256,0,stream>>>(whs,sgi,sbx,adjs);
  // 8. GCN layer 2
  tr_k<<<dim3(10,2,BB),256,0,stream>>>(g1b,g1t);
  wgemm_k<4,0,1><<<dim3(2,4,BB),256,0,stream>>>(adjs,g1t,nullptr,ax2b, DM,DMP,DMP, 16384,(long long)DMP*NN_,(long long)NN_*DMP);
  wgemm_k<19,1,1><<<dim3(128,8,1),256,0,stream>>>(ax2b,wwp,bw,g2b, DM,DMP,DMP, 0,0,0);
  // 9. head
  wgemm_k<19,2,0><<<dim3(128,4,1),256,0,stream>>>(g2b,wxxp,bxx,hnb, RHID,RHID,RHID, 0,0,0);
  pooled_k<<<BB,320,0,stream>>>(hnb,mask,Wc,bc,out);
}

// Round 13
// 1265.901 us; speedup vs baseline: 2.1055x; 1.0033x over previous
//
#include <hip/hip_runtime.h>
#include <math.h>

// ---- problem constants ----
#define BB    64
#define NN_   128
#define NH    6
#define DM    600     // d_model
#define RHID  300     // rnn hidden
#define DKH   100     // per-head dim
#define INDIM 360
#define G4    1200    // 4*RHID
#define WXROW 1206    // NH + 2*DM
#define DMP   608     // DM padded to mult of 32
#define INP   384     // INDIM padded
#define QKL   1536    // 2 * NH * 128 (head-padded q||k row length)
#define XGW   2400    // merged xg row width (fwd 0:1200, bwd 1200:2400)

// ---- LSTM cluster config ----
#define S_CL  25
#define NSU   12
#define NSR   48
#define KPAD  320
#define HSLOT (BB*KPAD)          // 20480 bf16 per history slot
#define DSTR  (129*HSLOT)        // per-dir history stride (bf16)

// ---- workspace layout (float offsets). Peak ~ 26.35M fl = 105.4 MB ----
#define OFF_GINB   0ull                 // bf16 [8192][608] = 2,490,368 fl
#define OFF_ASPECT 2490368ull
#define OFF_ASCB   2573568ull
#define OFF_W1SUM  2622720ull
#define OFF_W2SUM  2623360ull
#define OFF_SWX    2624000ull
#define OFF_SBX    2624016ull
#define OFF_SGI    2624032ull           // fp32 [8192][2] interleaved (sg1,sg2)
#define OFF_WHS    2640416ull           // fp32 [64][128][128]
#define OFF_WQKP   3688992ull           // bf16 [1536][608] = 466,944 fl
#define OFF_BQK    4155936ull           // fp32 1536
#define OFF_WWP    4157472ull           // bf16 [600][608] = 182,400 fl
#define OFF_WXXP   4339872ull           // bf16 [300][608] = 91,200 fl
#define OFF_WIHP   4431072ull           // bf16 [2400][384] = 460,800 fl
#define OFF_BP     4891872ull           // fp32 [2400]
#define OFF_WTB    4894272ull           // bf16 [2][1200][320] = 384,000 fl
#define OFF_EMBS   5278272ull           // bf16 [8192][384] = 1,572,864 fl
#define ARENA      6851136ull
#define OFF_XG     (ARENA)                      // bf16 [8192][2400] = 9,830,400 fl
#define OFF_HIST   (ARENA + 9830400ull)         // bf16 [2][129][64][320] = 2,641,920 fl
#define OFF_FLAGS  (ARENA + 12472320ull)        // flags (50, 128B apart)
// post-lstm reuse (xg dead after lstm; hist/flags dead after reshape):
#define OFF_QKH    (ARENA)                      // bf16 [8192][1536] = 6,291,456 fl (over xg)
#define OFF_ADJ    (ARENA + 6291456ull)         // bf16 [64][6][128][128] = 3,145,728 fl
#define OFF_ADJS   (ARENA + 16121856ull)        // bf16 [64][128][128] = 524,288 fl
#define OFF_GINT   (ARENA + 16646144ull)        // bf16 [64][608][128] = 2,490,368 fl
#define OFF_W12    (ARENA + 19136512ull)        // bf16 [2][608] = 608 fl
#define OFF_WDM    (ARENA + 19137152ull)        // fp32 [6][600][100] = 360,000 fl
#define OFF_BDM    (ARENA + 19497152ull)        // fp32 600
#define OFF_AXB    (ARENA)                      // bf16 (over qkh, dead after attn2/ascf)
#define OFF_G1B    (ARENA + 2490368ull)
#define OFF_G1T    (OFF_GINT)
#define OFF_AX2B   (ARENA + 4980736ull)
#define OFF_G2B    (ARENA + 7471104ull)         // over adj (dead after adjsum)
#define OFF_HNB    (ARENA + 9961472ull)         // bf16 [8192][300] (over hist, dead)

// ---- pack_k segmented index space ----
#define PK0 (XGW*INP + XGW)                 //   924,000 wihp + bias
#define PK1 (PK0 + QKL*DMP + QKL)           // 1,859,424 wqkhp + bias
#define PK2 (PK1 + DM*DMP)                  // 2,224,224 Ww pack
#define PK3 (PK2 + RHID*DMP)                // 2,406,624 Wxx pack
#define PK4 (PK3 + 2*G4*KPAD)               // 3,174,624 Whh both dirs
#define PK5 (PK4 + 22528)                   // 3,197,152 hist slot0 + flags init

typedef __bf16 bf16x8 __attribute__((ext_vector_type(8)));
typedef __bf16 bf16x4 __attribute__((ext_vector_type(4)));
typedef __bf16 bf16x2 __attribute__((ext_vector_type(2)));
typedef float  f32x4  __attribute__((ext_vector_type(4)));

__device__ __forceinline__ float sigm(float x){ return 1.f/(1.f+__expf(-x)); }
__device__ __forceinline__ float selu_f(float x){
  const float sc=1.0507009873554805f, al=1.6732632423543772f;
  return x>0.f ? sc*x : sc*al*(__expf(x)-1.f);
}
__device__ __forceinline__ bf16x8 bzero8(){
  bf16x8 z;
#pragma unroll
  for (int j=0;j<8;++j) z[j]=(__bf16)0.f;
  return z;
}

// ---------------- embedding concat -> bf16 [8192][384], pads written zero ----------------
__global__ __launch_bounds__(384) void embed_k(
    const int* __restrict__ tok, const int* __restrict__ pos_ids, const int* __restrict__ post_ids,
    const float* __restrict__ emb_w, const float* __restrict__ pos_w, const float* __restrict__ post_w,
    __bf16* __restrict__ embs)
{
  int bn = blockIdx.x, t = threadIdx.x;
  float v = 0.f;
  if      (t < 300) v = emb_w [(size_t)tok     [bn]*300 + t];
  else if (t < 330) v = pos_w [(size_t)pos_ids [bn]*30  + (t-300)];
  else if (t < 360) v = post_w[(size_t)post_ids[bn]*30  + (t-330)];
  embs[(size_t)bn*INP + t] = (__bf16)v;
}

// ---------------- Wx folded constants (+ bf16 w12 for the sg GEMV) ----------------
__global__ __launch_bounds__(640) void consts_k(
    const float* __restrict__ Wx, const float* __restrict__ bx,
    float* __restrict__ w1sum, float* __restrict__ w2sum,
    float* __restrict__ swx, float* __restrict__ sbx, __bf16* __restrict__ w12)
{
  int t = threadIdx.x;
  if (t < DM){
    float s1=0.f, s2=0.f;
    for (int k=0;k<NH;++k){ s1 += Wx[k*WXROW + NH + t]; s2 += Wx[k*WXROW + NH + DM + t]; }
    w1sum[t]=s1; w2sum[t]=s2;
    w12[t]=(__bf16)s1; w12[DMP+t]=(__bf16)s2;
  } else if (t < DM+NH){
    int h=t-DM; float s=0.f;
    for (int k=0;k<NH;++k) s += Wx[k*WXROW + h];
    swx[h]=s;
  } else if (t == DM+NH){
    float s=0.f; for (int k=0;k<NH;++k) s += bx[k];
    sbx[0]=s;
  }
  if (t >= DM && t < DMP){ w12[t]=(__bf16)0.f; w12[DMP+t]=(__bf16)0.f; }
}

// ---------------- WdM[h][D][e] = sum_d Wd[d][D]*wm[h][d][e]; bdM[h][e] = bd·wm[h][:,e] ----------------
__global__ __launch_bounds__(128) void wdm_k(
    const float* __restrict__ Wd, const float* __restrict__ bd, const float* __restrict__ wm,
    float* __restrict__ WdM, float* __restrict__ bdM)
{
  int D = blockIdx.x, h = blockIdx.y, e = threadIdx.x;
  if (e >= DKH) return;
  float s = 0.f;
  for (int d=0; d<DKH; ++d)
    s += Wd[d*DM + D] * wm[(h*DKH+d)*DKH + e];
  WdM[((size_t)h*DM + D)*DKH + e] = s;
  if (D == 0){
    float sb = 0.f;
    for (int d=0; d<DKH; ++d) sb += bd[d]*wm[(h*DKH+d)*DKH + e];
    bdM[h*DKH + e] = sb;
  }
}

// ---------------- fused packing/init (segmented): wihp|wqkhp|Ww|Wxx|Whh|init ----------------
__global__ __launch_bounds__(256) void pack_k(
    const float* __restrict__ Wih_f, const float* __restrict__ b_f,
    const float* __restrict__ Wih_b, const float* __restrict__ b_b,
    const float* __restrict__ Wq, const float* __restrict__ bq,
    const float* __restrict__ Wk, const float* __restrict__ bk,
    const float* __restrict__ Ww, const float* __restrict__ Wxx,
    const float* __restrict__ Whh_f, const float* __restrict__ Whh_b,
    __bf16* __restrict__ wihp, float* __restrict__ bp,
    __bf16* __restrict__ wqkp, float* __restrict__ bqk,
    __bf16* __restrict__ wwp, __bf16* __restrict__ wxxp,
    __bf16* __restrict__ wtb, float* __restrict__ ws)
{
  int idx = blockIdx.x*256 + threadIdx.x;
  if (idx < PK0){
    if (idx < XGW*INP){
      int r = idx / INP, k = idx - r*INP;
      int dir = r >= G4; int p = r - dir*G4;
      const float* W = dir ? Wih_b : Wih_f;
      int srow = (p&3)*RHID + (p>>2);
      wihp[idx] = (k<INDIM) ? (__bf16)W[(size_t)srow*INDIM + k] : (__bf16)0.f;
    } else {
      int n = idx - XGW*INP;
      int dir = n >= G4; int p = n - dir*G4;
      const float* b = dir ? b_b : b_f;
      bp[n] = b[(p&3)*RHID + (p>>2)];
    }
  } else if (idx < PK1){
    int id = idx - PK0;
    if (id < QKL*DMP){
      int n = id / DMP, k = id - n*DMP;
      int nl = (n < 768) ? n : n - 768;
      int h = nl >> 7, e = nl & 127;
      float v = 0.f;
      if (k < DM && e < DKH)
        v = (n < 768) ? Wq[(size_t)(h*DKH+e)*DM + k] : Wk[(size_t)(h*DKH+e)*DM + k];
      wqkp[id] = (__bf16)v;
    } else {
      int n = id - QKL*DMP;
      int nl = (n < 768) ? n : n - 768;
      int h = nl >> 7, e = nl & 127;
      bqk[n] = (e < DKH) ? ((n < 768) ? bq[h*DKH+e] : bk[h*DKH+e]) : 0.f;
    }
  } else if (idx < PK2){
    int id = idx - PK1;
    int n = id / DMP, k = id - n*DMP;
    wwp[id] = (k < DM) ? (__bf16)Ww[(size_t)n*DM + k] : (__bf16)0.f;
  } else if (idx < PK3){
    int id = idx - PK2;
    int n = id / DMP, k = id - n*DMP;
    wxxp[id] = (k < DM) ? (__bf16)Wxx[(size_t)n*DM + k] : (__bf16)0.f;
  } else if (idx < PK4){
    int id = idx - PK3;
    int dir = id >= G4*KPAD; int id2 = id - dir*G4*KPAD;
    int p = id2 / KPAD, k = id2 - p*KPAD;
    const float* Whh = dir ? Whh_b : Whh_f;
    wtb[id] = (k < RHID) ? (__bf16)Whh[((size_t)((p&3)*RHID + (p>>2)))*RHID + k] : (__bf16)0.f;
  } else if (idx < PK5){
    int id = idx - PK4;
    if (id < 10240)      ws[OFF_HIST + id] = 0.f;                        // dir0 slot0
    else if (id < 20480) ws[OFF_HIST + 1320960ull + (id-10240)] = 0.f;   // dir1 slot0
    else                 ws[OFF_FLAGS + (id-20480)] = 0.f;               // flags
  }
}

// ---------------- LDS-free bf16 MFMA GEMM: C = act(A @ B^T + bias) ----------------
// Dual accumulator chains (even/odd kt) double per-wave MFMA ILP.
template<int KT, int ACT, int OBF>
__global__ __launch_bounds__(256) void wgemm_k(
    const __bf16* __restrict__ A, const __bf16* __restrict__ B,
    const float* __restrict__ bias, void* __restrict__ Cout,
    int Nn, int Npad, int ldc,
    long long sA, long long sB, long long sC)
{
  const int tid = threadIdx.x, lane = tid & 63, wave = tid >> 6;
  const int fn = lane & 15, fq = lane >> 4;
  const int K = KT*32;
  const __bf16* Ab = A + (size_t)blockIdx.z * (size_t)sA;
  const __bf16* Bb = B + (size_t)blockIdx.z * (size_t)sB;
  float*  Cf = (float*) Cout + (size_t)blockIdx.z * (size_t)sC;
  __bf16* Ch = (__bf16*)Cout + (size_t)blockIdx.z * (size_t)sC;

  const int m0 = (blockIdx.x*4 + wave)*16;

  bf16x8 Af[KT];
#pragma unroll
  for (int kt=0; kt<KT; ++kt)
    Af[kt] = *(const bf16x8*)(Ab + (size_t)(m0 + fn)*K + kt*32 + fq*8);

  for (int n0 = blockIdx.y*16; n0 < Nn; n0 += 16*gridDim.y){
    const int gn = n0 + fn;
    const int gnc = (gn < Nn) ? gn : 0;
    f32x4 acc0 = {0.f,0.f,0.f,0.f};
    f32x4 acc1 = {0.f,0.f,0.f,0.f};
#pragma unroll
    for (int kt=0; kt<KT; ++kt){
      bf16x8 Bf = *(const bf16x8*)(Bb + (size_t)gnc*K + kt*32 + fq*8);
      if (gn >= Nn) Bf = bzero8();
      if (kt & 1) acc1 = __builtin_amdgcn_mfma_f32_16x16x32_bf16(Af[kt], Bf, acc1, 0, 0, 0);
      else        acc0 = __builtin_amdgcn_mfma_f32_16x16x32_bf16(Af[kt], Bf, acc0, 0, 0, 0);
    }
    float bv = (bias && gn < Nn) ? bias[gn] : 0.f;
#pragma unroll
    for (int r=0; r<4; ++r){
      int gm = m0 + fq*4 + r;
      float v = acc0[r] + acc1[r] + bv;
      if (ACT==1) v = selu_f(v);
      else if (ACT==2) v = fmaxf(v, 0.f);
      if (gn < Nn){
        if (OBF) Ch[(size_t)gm*ldc + gn] = (__bf16)v;
        else     Cf[(size_t)gm*ldc + gn] = v;
      } else if (gn < Npad){
        if (OBF) Ch[(size_t)gm*ldc + gn] = (__bf16)0.f;
        else     Cf[(size_t)gm*ldc + gn] = 0.f;
      }
    }
  }
}

// ---------------- bf16 per-batch transpose [64][128][608] -> [64][608][128] ----------------
__global__ __launch_bounds__(256) void tr_k(
    const __bf16* __restrict__ in, __bf16* __restrict__ out)
{
  const int b = blockIdx.z, m0 = blockIdx.y*64, d0 = blockIdx.x*64;
  const int tid = threadIdx.x;
  __shared__ __align__(16) __bf16 T[64][72];
  const __bf16* ib = in + (size_t)b*NN_*DMP;
  __bf16* ob = out + (size_t)b*DMP*NN_;
#pragma unroll
  for (int r=0;r<2;++r){
    int idx = tid + 256*r;
    int mi = idx>>3, ch = idx&7;
    int d = d0 + ch*8;
    bf16x8 v = bzero8();
    if (d < DMP) v = *(const bf16x8*)(ib + (size_t)(m0+mi)*DMP + d);
    *(bf16x8*)&T[mi][ch*8] = v;
  }
  __syncthreads();
#pragma unroll
  for (int r=0;r<2;++r){
    int idx = tid + 256*r;
    int di = idx>>3, mch = idx&7;
    int d = d0 + di;
    if (d >= DMP) continue;
    bf16x8 v;
#pragma unroll
    for (int j=0;j<8;++j) v[j] = T[mch*8+j][di];
    *(bf16x8*)(ob + (size_t)d*NN_ + m0 + mch*8) = v;
  }
}

// ---------------- cooperative-cluster MFMA LSTM — fence-free system-coherent sync ----------------
// (R10-proven structure: system-scope RELAXED atomics serialize at L3; no fences in loop.)
__global__ __launch_bounds__(256, 1) void lstm_mfma_k(
    const __bf16* __restrict__ xg,
    const __bf16* __restrict__ wtb,
    __bf16* hist, int* flags)
{
  const int blk = blockIdx.x;
  const int dir = blk / S_CL, sl = blk - dir*S_CL;
  const int tid = threadIdx.x, lane = tid & 63, wave = tid >> 6;
  const int p0 = sl * NSR;
  const __bf16* W = wtb + (size_t)dir * G4 * KPAD;
  __bf16* hb = hist + (size_t)dir * DSTR;

  __shared__ __align__(16) float accS[NSR][68];

  const int fn = lane & 15;
  const int fk = (lane >> 4) * 8;
  const int m0 = wave * 16;

  bf16x8 Bf[3][10];
#pragma unroll
  for (int nt = 0; nt < 3; ++nt)
#pragma unroll
    for (int kt = 0; kt < 10; ++kt)
      Bf[nt][kt] = *(const bf16x8*)(W + (size_t)(p0 + nt*16 + fn)*KPAD + kt*32 + fk);

  const int b_ep = tid / 3;
  const int q_ep = tid - b_ep*3;
  const int u0 = q_ep*4;
  const bool ep = (tid < 192);
  float cst[4] = {0.f,0.f,0.f,0.f};
  const __bf16* xp = xg + (size_t)b_ep*NN_*XGW + dir*G4 + p0 + u0*4;

  for (int s = 0; s < NN_; ++s){
    const int n_t = dir ? (NN_-1-s) : s;
    const __bf16* hbr = hb + (size_t)s*HSLOT;
    __bf16*       hbw = hb + (size_t)(s+1)*HSLOT;

    bf16x8 xv0, xv1;
    if (ep){
      xv0 = *(const bf16x8*)(xp + (size_t)n_t*XGW);
      xv1 = *(const bf16x8*)(xp + (size_t)n_t*XGW + 8);
    }

    bf16x8 Af[10];
#pragma unroll
    for (int kt = 0; kt < 10; ++kt){
      const unsigned long long* hp =
          (const unsigned long long*)(hbr + (size_t)(m0 + fn)*KPAD + kt*32 + fk);
      union { unsigned long long u[2]; bf16x8 v; } cv;
      cv.u[0] = __hip_atomic_load(hp,   __ATOMIC_RELAXED, __HIP_MEMORY_SCOPE_SYSTEM);
      cv.u[1] = __hip_atomic_load(hp+1, __ATOMIC_RELAXED, __HIP_MEMORY_SCOPE_SYSTEM);
      Af[kt] = cv.v;
    }

    f32x4 acc[3] = { {0.f,0.f,0.f,0.f}, {0.f,0.f,0.f,0.f}, {0.f,0.f,0.f,0.f} };
#pragma unroll
    for (int kt = 0; kt < 10; ++kt)
#pragma unroll
      for (int nt = 0; nt < 3; ++nt)
        acc[nt] = __builtin_amdgcn_mfma_f32_16x16x32_bf16(Af[kt], Bf[nt][kt], acc[nt], 0, 0, 0);

#pragma unroll
    for (int nt = 0; nt < 3; ++nt)
      *(f32x4*)&accS[nt*16 + fn][m0 + (lane>>4)*4] = acc[nt];
    __syncthreads();

    if (ep){
      union { unsigned long long u; __bf16 h[4]; } pk;
      float xgv[16];
#pragma unroll
      for (int j=0;j<8;++j){ xgv[j]=(float)xv0[j]; xgv[8+j]=(float)xv1[j]; }
#pragma unroll
      for (int du = 0; du < 4; ++du){
        int u = u0 + du;
        float p_i = accS[u*4+0][b_ep] + xgv[du*4+0];
        float p_f = accS[u*4+1][b_ep] + xgv[du*4+1];
        float p_g = accS[u*4+2][b_ep] + xgv[du*4+2];
        float p_o = accS[u*4+3][b_ep] + xgv[du*4+3];
        float ig = sigm(p_i), fg = sigm(p_f), gg = tanhf(p_g), og = sigm(p_o);
        float c = fg*cst[du] + ig*gg; cst[du] = c;
        pk.h[du] = (__bf16)(og * tanhf(c));
      }
      __hip_atomic_store(
          (unsigned long long*)(hbw + (size_t)b_ep*KPAD + sl*NSU + u0),
          pk.u, __ATOMIC_RELAXED, __HIP_MEMORY_SCOPE_SYSTEM);
    }
    __syncthreads();
    if (tid == 0)
      __hip_atomic_store(&flags[(dir*S_CL + sl)*32], s+1, __ATOMIC_RELAXED, __HIP_MEMORY_SCOPE_SYSTEM);
    if (wave == 0 && lane < S_CL){
      int* fp = &flags[(dir*S_CL + lane)*32];
      while (__hip_atomic_load(fp, __ATOMIC_RELAXED, __HIP_MEMORY_SCOPE_SYSTEM) < s+1) { }
    }
    __syncthreads();
  }
}

// ---------------- hist -> ginb [8192][608] (pads zeroed) ----------------
__global__ __launch_bounds__(320) void reshape_k(
    const __bf16* __restrict__ hist, __bf16* __restrict__ ginb)
{
  int row = blockIdx.x;                 // b*128 + n
  int b = row >> 7, n = row & 127;
  int t = threadIdx.x;
  if (t < 150){
    int u = 2*t;
    bf16x2 v = *(const bf16x2*)(hist + (size_t)(n+1)*HSLOT + (size_t)b*KPAD + u);
    *(bf16x2*)(ginb + (size_t)row*DMP + u) = v;
  } else if (t >= 160 && t < 310){
    int u = 2*(t-160);
    bf16x2 v = *(const bf16x2*)(hist + (size_t)DSTR + (size_t)(NN_-n)*HSLOT + (size_t)b*KPAD + u);
    *(bf16x2*)(ginb + (size_t)row*DMP + RHID + u) = v;
  } else if (t >= 312 && t < 316){
    int c = DM + 2*(t-312);
    bf16x2 z; z[0]=(__bf16)0.f; z[1]=(__bf16)0.f;
    *(bf16x2*)(ginb + (size_t)row*DMP + c) = z;
  }
}

// ---------------- masked mean over sequence -> aspect[B,DM] (bf16 in, 2 col-halves) ----------------
__global__ __launch_bounds__(320) void aspect_k(
    const __bf16* __restrict__ ginb, const float* __restrict__ mask, float* __restrict__ aspect)
{
  int b = blockIdx.x, t = threadIdx.x;
  int col = blockIdx.y*300 + t;
  __shared__ float msk[NN_];
  __shared__ float wn;
  if (t < NN_) msk[t] = mask[b*NN_+t];
  __syncthreads();
  if (t==0){ float s=0.f; for (int n=0;n<NN_;++n) s+=msk[n]; wn=s; }
  __syncthreads();
  if (t < 300){
    float s=0.f;
    for (int n=0;n<NN_;++n) s += (float)ginb[((size_t)(b*NN_+n))*DMP + col]*msk[n];
    aspect[b*DM+col] = s/wn;
  }
}

// ---------------- fused: aw = aspect@WdM + bdM ; asc = tanh(aw·k + bias_m) ----------------
__global__ __launch_bounds__(128) void ascf_k(
    const float* __restrict__ aspect, const float* __restrict__ WdM, const float* __restrict__ bdM,
    const __bf16* __restrict__ qkh, const float* __restrict__ bias_m, float* __restrict__ asc)
{
  int b = blockIdx.x, h = blockIdx.y, t = threadIdx.x;
  __shared__ __align__(16) float asp[DM];
  __shared__ __align__(16) float awl[DKH];
  for (int i = t; i < DM; i += 128) asp[i] = aspect[b*DM + i];
  __syncthreads();
  if (t < DKH){
    const float* wrow = WdM + (size_t)h*DM*DKH + t;
    float s0=0.f,s1=0.f,s2=0.f,s3=0.f;
    for (int D=0; D<DM; D+=4){
      s0 += asp[D+0]*wrow[(size_t)(D+0)*DKH];
      s1 += asp[D+1]*wrow[(size_t)(D+1)*DKH];
      s2 += asp[D+2]*wrow[(size_t)(D+2)*DKH];
      s3 += asp[D+3]*wrow[(size_t)(D+3)*DKH];
    }
    awl[t] = s0+s1+s2+s3 + bdM[h*DKH + t];
  }
  __syncthreads();
  const __bf16* kr = qkh + (size_t)(b*NN_ + t)*QKL + 768 + h*128;
  float s=0.f;
#pragma unroll
  for (int e=0;e<DKH;e+=2){
    bf16x2 kv = *(const bf16x2*)(kr + e);
    s += awl[e]*(float)kv[0] + awl[e+1]*(float)kv[1];
  }
  asc[(b*NH+h)*NN_ + t] = tanhf(s + bias_m[0]);
}

// ---------------- MFMA attention (split x2): scores + mask + short + softmax -> adj bf16 ----------------
__global__ __launch_bounds__(256) void attn2_k(
    const __bf16* __restrict__ qkh, const float* __restrict__ asc,
    const float* __restrict__ shortm, const int* __restrict__ tok,
    __bf16* __restrict__ adj)
{
  const int bx = blockIdx.x;
  const int bh = bx >> 1, half = bx & 1;
  const int b = bh / NH, h = bh - b*NH;
  const int tid = threadIdx.x, lane = tid & 63, wave = tid >> 6;
  const int fn = lane & 15, fq = lane >> 4;
  const __bf16* qb = qkh + (size_t)(b*NN_)*QKL + h*128;
  const __bf16* kb = qkh + (size_t)(b*NN_)*QKL + 768 + h*128;

  const int m0 = half*64 + wave*16;
  bf16x8 Af[4];
#pragma unroll
  for (int kt=0;kt<4;++kt)
    Af[kt] = *(const bf16x8*)(qb + (size_t)(m0+fn)*QKL + kt*32 + fq*8);

  f32x4 acc[8];
#pragma unroll
  for (int j=0;j<8;++j) acc[j] = (f32x4){0.f,0.f,0.f,0.f};

#pragma unroll
  for (int j=0;j<8;++j){
    bf16x8 Bf[4];
#pragma unroll
    for (int kt=0;kt<4;++kt)
      Bf[kt] = *(const bf16x8*)(kb + (size_t)(j*16+fn)*QKL + kt*32 + fq*8);
#pragma unroll
    for (int kt=0;kt<4;++kt)
      acc[j] = __builtin_amdgcn_mfma_f32_16x16x32_bf16(Af[kt], Bf[kt], acc[j], 0,0,0);
  }

  float ascv[8]; int msk[8];
#pragma unroll
  for (int j=0;j<8;++j){
    int c = j*16 + fn;
    ascv[j] = asc[(b*NH+h)*NN_ + c];
    msk [j] = tok[b*NN_ + c];
  }

#pragma unroll
  for (int r=0;r<4;++r){
    int m = m0 + fq*4 + r;
    float sv[8];
#pragma unroll
    for (int j=0;j<8;++j){
      int c = j*16 + fn;
      float s = acc[j][r]*0.1f + ascv[j];
      if (msk[j]==0) s = -1e9f;
      s += shortm[((size_t)(b*NN_+m))*NN_ + c];
      sv[j]=s;
    }
    float mx = sv[0];
#pragma unroll
    for (int j=1;j<8;++j) mx = fmaxf(mx, sv[j]);
#pragma unroll
    for (int o=1;o<16;o<<=1) mx = fmaxf(mx, __shfl_xor(mx, o, 64));
    float sum = 0.f, ev[8];
#pragma unroll
    for (int j=0;j<8;++j){ ev[j]=__expf(sv[j]-mx); sum+=ev[j]; }
#pragma unroll
    for (int o=1;o<16;o<<=1) sum += __shfl_xor(sum, o, 64);
    float inv = 1.f/sum;
#pragma unroll
    for (int j=0;j<8;++j)
      adj[(((size_t)(b*NH+h))*NN_ + m)*NN_ + j*16 + fn] = (__bf16)(ev[j]*inv);
  }
}

// ---------------- adjsum (bf16 in) -> bf16 adjs (/H) + fp32 whs ----------------
__global__ __launch_bounds__(256) void adjsum_k(
    const __bf16* __restrict__ adj, const float* __restrict__ swx,
    __bf16* __restrict__ adjs, float* __restrict__ whs)
{
  int idx = blockIdx.x*256 + threadIdx.x;
  int b = idx >> 14, rem = idx & 16383;
  float s=0.f, w=0.f;
  for (int h=0;h<NH;++h){
    float v = (float)adj[(((size_t)b*NH+h)<<14) + rem];
    s += v; w += v*swx[h];
  }
  adjs[idx] = (__bf16)(s*(1.f/NH));
  whs [idx] = w*(1.f/NH);
}

// ---------------- adjs2[b,i,j] = whs + (sg1[b,j]+sg2[b,i]+sbx)/H -> bf16 ----------------
__global__ __launch_bounds__(256) void adjsum2_k(
    const float* __restrict__ whs, const float* __restrict__ sgi,
    const float* __restrict__ sbx, __bf16* __restrict__ adjs)
{
  int idx = blockIdx.x*256 + threadIdx.x;
  int b = idx >> 14, rem = idx & 16383;
  int i = rem >> 7, j = rem & 127;
  adjs[idx] = (__bf16)(whs[idx] + (sgi[(b*NN_+j)*2] + sgi[(b*NN_+i)*2+1] + sbx[0])*(1.f/NH));
}

// ---------------- pooled mean + logits (bf16 hn) ----------------
__global__ __launch_bounds__(320) void pooled_k(
    const __bf16* __restrict__ hn, const float* __restrict__ mask,
    const float* __restrict__ Wc, const float* __restrict__ bc, float* __restrict__ out)
{
  int b=blockIdx.x, t=threadIdx.x;
  __shared__ float msk[NN_];
  __shared__ float pl[RHID];
  __shared__ float wn;
  if (t<NN_) msk[t]=mask[b*NN_+t];
  __syncthreads();
  if (t==0){ float s=0.f; for (int n=0;n<NN_;++n) s+=msk[n]; wn=s; }
  __syncthreads();
  if (t<RHID){
    float s=0.f;
    for (int n=0;n<NN_;++n) s += (float)hn[((size_t)(b*NN_+n))*RHID+t]*msk[n];
    pl[t]=s/wn;
  }
  __syncthreads();
  if (t<3){
    float s=bc[t];
    for (int d=0;d<RHID;++d) s += pl[d]*Wc[t*RHID+d];
    out[b*3+t]=s;
  }
}

extern "C" void kernel_launch(void* const* d_in, const int* in_sizes, int n_in,
                              void* d_out, int out_size, void* d_ws, size_t ws_size,
                              hipStream_t stream)
{
  (void)in_sizes; (void)n_in; (void)out_size; (void)ws_size;
  const int*   tok      = (const int*)  d_in[0];
  const int*   pos_ids  = (const int*)  d_in[2];
  const int*   post_ids = (const int*)  d_in[5];
  const float* mask     = (const float*)d_in[6];
  const float* shortm   = (const float*)d_in[8];
  const float* emb_w    = (const float*)d_in[9];
  const float* pos_w    = (const float*)d_in[10];
  const float* post_w   = (const float*)d_in[11];
  const float* Wih_f    = (const float*)d_in[12];
  const float* Whh_f    = (const float*)d_in[13];
  const float* b_f      = (const float*)d_in[14];
  const float* Wih_b    = (const float*)d_in[15];
  const float* Whh_b    = (const float*)d_in[16];
  const float* b_b      = (const float*)d_in[17];
  const float* Wq       = (const float*)d_in[18];
  const float* bq       = (const float*)d_in[19];
  const float* Wk       = (const float*)d_in[20];
  const float* bk       = (const float*)d_in[21];
  const float* Wd       = (const float*)d_in[22];
  const float* bd       = (const float*)d_in[23];
  const float* weight_m = (const float*)d_in[24];
  const float* bias_m   = (const float*)d_in[25];
  const float* Ww       = (const float*)d_in[26];
  const float* bw       = (const float*)d_in[27];
  const float* Wx       = (const float*)d_in[28];
  const float* bx       = (const float*)d_in[29];
  const float* Wxx      = (const float*)d_in[30];
  const float* bxx      = (const float*)d_in[31];
  const float* Wc       = (const float*)d_in[32];
  const float* bc       = (const float*)d_in[33];

  float* ws  = (float*)d_ws;
  float* out = (float*)d_out;

  __bf16* ginb  = (__bf16*)(ws + OFF_GINB);
  float* aspect = ws + OFF_ASPECT;
  float* ascb   = ws + OFF_ASCB;
  float* w1sum  = ws + OFF_W1SUM;
  float* w2sum  = ws + OFF_W2SUM;
  float* swx    = ws + OFF_SWX;
  float* sbx    = ws + OFF_SBX;
  float* sgi    = ws + OFF_SGI;
  float* whs    = ws + OFF_WHS;
  __bf16* wqkp  = (__bf16*)(ws + OFF_WQKP);
  float* bqk    = ws + OFF_BQK;
  __bf16* wwp   = (__bf16*)(ws + OFF_WWP);
  __bf16* wxxp  = (__bf16*)(ws + OFF_WXXP);
  __bf16* wihp  = (__bf16*)(ws + OFF_WIHP);
  float* bp     = ws + OFF_BP;
  __bf16* wtb   = (__bf16*)(ws + OFF_WTB);
  __bf16* embs  = (__bf16*)(ws + OFF_EMBS);
  __bf16* xg    = (__bf16*)(ws + OFF_XG);
  __bf16* hist  = (__bf16*)(ws + OFF_HIST);
  int*   flags  = (int*)(ws + OFF_FLAGS);
  __bf16* qkh   = (__bf16*)(ws + OFF_QKH);
  __bf16* adjb  = (__bf16*)(ws + OFF_ADJ);
  __bf16* adjs  = (__bf16*)(ws + OFF_ADJS);
  __bf16* gint  = (__bf16*)(ws + OFF_GINT);
  __bf16* w12   = (__bf16*)(ws + OFF_W12);
  float* wdm    = ws + OFF_WDM;
  float* bdm    = ws + OFF_BDM;
  __bf16* axb   = (__bf16*)(ws + OFF_AXB);
  __bf16* g1b   = (__bf16*)(ws + OFF_G1B);
  __bf16* g1t   = (__bf16*)(ws + OFF_G1T);
  __bf16* ax2b  = (__bf16*)(ws + OFF_AX2B);
  __bf16* g2b   = (__bf16*)(ws + OFF_G2B);
  __bf16* hnb   = (__bf16*)(ws + OFF_HNB);

  // 1. embeddings, constants, fused packing/init
  embed_k<<<dim3(BB*NN_),384,0,stream>>>(tok,pos_ids,post_ids,emb_w,pos_w,post_w,embs);
  consts_k<<<1,640,0,stream>>>(Wx,bx,w1sum,w2sum,swx,sbx,w12);
  wdm_k<<<dim3(DM,NH),128,0,stream>>>(Wd,bd,weight_m,wdm,bdm);
  pack_k<<<dim3((PK5+255)/256),256,0,stream>>>(Wih_f,b_f,Wih_b,b_b,Wq,bq,Wk,bk,Ww,Wxx,
                                               Whh_f,Whh_b,wihp,bp,wqkp,bqk,wwp,wxxp,wtb,ws);
  // 2. merged LSTM input projection (both dirs), bf16 out [8192][2400]
  wgemm_k<12,0,1><<<dim3(128,8,1),256,0,stream>>>(embs,wihp,bp,xg, XGW,XGW,XGW, 0,0,0);
  // 3. recurrence (fence-free system-coherent cluster sync — R10-proven)
  lstm_mfma_k<<<dim3(2*S_CL),256,0,stream>>>(xg,wtb,hist,flags);
  reshape_k<<<dim3(BB*NN_),320,0,stream>>>(hist,ginb);
  // 4. fused Q||K projection (bf16 head-padded), aspect path
  wgemm_k<19,0,1><<<dim3(128,12,1),256,0,stream>>>(ginb,wqkp,bqk,qkh, QKL,QKL,QKL, 0,0,0);
  aspect_k<<<dim3(BB,2),320,0,stream>>>(ginb,mask,aspect);
  ascf_k<<<dim3(BB,NH),128,0,stream>>>(aspect,wdm,bdm,qkh,bias_m,ascb);
  // 5. MFMA scores + softmax -> adj bf16
  attn2_k<<<dim3(BB*NH*2),256,0,stream>>>(qkh,ascb,shortm,tok,adjb);
  // 6. GCN layer 1 (bf16 MFMA)
  adjsum_k<<<4096,256,0,stream>>>(adjb,swx,adjs,whs);
  tr_k<<<dim3(10,2,BB),256,0,stream>>>(ginb,gint);
  wgemm_k<4,0,1><<<dim3(2,4,BB),256,0,stream>>>(adjs,gint,nullptr,axb, DM,DMP,DMP, 16384,(long long)DMP*NN_,(long long)NN_*DMP);
  wgemm_k<19,1,1><<<dim3(128,8,1),256,0,stream>>>(axb,wwp,bw,g1b, DM,DMP,DMP, 0,0,0);
  // 7. layer-2 adjacency collapsed (sg via coalesced MFMA GEMV, N=2)
  wgemm_k<19,0,0><<<dim3(128,1,1),256,0,stream>>>(g1b,w12,nullptr,sgi, 2,2,2, 0,0,0);
  adjsum2_k<<<4096,256,0,stream>>>(whs,sgi,sbx,adjs);
  // 8. GCN layer 2
  tr_k<<<dim3(10,2,BB),256,0,stream>>>(g1b,g1t);
  wgemm_k<4,0,1><<<dim3(2,4,BB),256,0,stream>>>(adjs,g1t,nullptr,ax2b, DM,DMP,DMP, 16384,(long long)DMP*NN_,(long long)NN_*DMP);
  wgemm_k<19,1,1><<<dim3(128,8,1),256,0,stream>>>(ax2b,wwp,bw,g2b, DM,DMP,DMP, 0,0,0);
  // 9. head (bf16 hnode out)
  wgemm_k<19,2,1><<<dim3(128,4,1),256,0,stream>>>(g2b,wxxp,bxx,hnb, RHID,RHID,RHID, 0,0,0);
  pooled_k<<<BB,320,0,stream>>>(hnb,mask,Wc,bc,out);
}